// Round 1
// baseline (803.828 us; speedup 1.0000x reference)
//
#include <hip/hip_runtime.h>

// ---------------------------------------------------------------------------
// multihead_attention_87454124081549 — round 1
// B=128, S=256, NU=256, NH=32, heads n = c*128+b (c in [0,8)), M = B*S = 32768
// softmax is over axis 0 (the 1024-head axis) -> denominator D[q,k] per attn.
// ---------------------------------------------------------------------------

typedef __attribute__((ext_vector_type(4))) float f32x4;
typedef __attribute__((ext_vector_type(8))) short bf16x8;

#define LOG2E 1.4426950408889634f
#define SM_SCALE (1.4426950408889634f / 5.656854249492381f)  // log2(e)/sqrt(32)

__device__ __forceinline__ unsigned short f2bf(float x) {
    union { float f; unsigned u; } v; v.f = x;
    unsigned r = v.u + 0x7FFFu + ((v.u >> 16) & 1u);   // RNE
    return (unsigned short)(r >> 16);
}

__device__ __forceinline__ float fast_tanh(float x) {
    float e = __builtin_amdgcn_exp2f(x * (2.0f * LOG2E));   // exp(2x)
    return 1.0f - 2.0f * __builtin_amdgcn_rcpf(e + 1.0f);
}

__device__ __forceinline__ f32x4 mfma_bf16(bf16x8 a, bf16x8 b, f32x4 c) {
    return __builtin_amdgcn_mfma_f32_16x16x32_bf16(a, b, c, 0, 0, 0);
}

// ---------------------------------------------------------------------------
// Weight conversion: 7 x (256x256) + W5 (256x1024) fp32 -> bf16, concatenated.
// ---------------------------------------------------------------------------
__global__ __launch_bounds__(256) void k_convert_w(
    const float* w0, const float* w1, const float* w2, const float* w3,
    const float* w4, const float* w5, const float* w6, const float* w7,
    unsigned short* out)
{
    int i = blockIdx.x * 256 + threadIdx.x;
    if (i >= 720896) return;
    float v;
    if (i < 458752) {
        int r = i >> 16, j = i & 65535;
        const float* s =
            (r == 0) ? w0 : (r == 1) ? w1 : (r == 2) ? w2 :
            (r == 3) ? w3 : (r == 4) ? w4 : (r == 5) ? w5 : w6;
        v = s[j];
    } else {
        v = w7[i - 458752];
    }
    out[i] = (short)f2bf(v);
}

// ---------------------------------------------------------------------------
// Linear + tanh:  Y(bf16, 32768x256) = tanh(X(f32) @ W^T + bias)
// optional batch gather (adj) on input rows.  BM=128, BN=128, BK=32.
// grid = (2, 256), block = 256 (4 waves, 2x2 of 64x64).
// ---------------------------------------------------------------------------
__global__ __launch_bounds__(256) void k_linear(
    const float* __restrict__ X, const int* __restrict__ adj,
    const unsigned short* __restrict__ Wb, const float* __restrict__ bias,
    unsigned short* __restrict__ Y)
{
    __shared__ __align__(16) short Bs[128 * 264];  // 128 rows(n) x 256(k), pad 264
    __shared__ __align__(16) short As[128 * 40];   // 128 rows(m) x 32(k),  pad 40
    const int tid = threadIdx.x;
    const int w = tid >> 6, l = tid & 63;
    const int n0 = blockIdx.x * 128, m0 = blockIdx.y * 128;
    const int lr = l & 15, lk = (l >> 4) * 8, lq = (l >> 4) * 4;
    const int wr = (w >> 1) * 64, wc = (w & 1) * 64;

    // stage whole B block (bf16 -> LDS, padded)
    for (int ci = tid; ci < 4096; ci += 256) {
        int r = ci >> 5, ch = ci & 31;
        *(bf16x8*)&Bs[r * 264 + ch * 8] =
            *(const bf16x8*)(Wb + (size_t)(n0 + r) * 256 + ch * 8);
    }

    f32x4 acc[4][4] = {};
    for (int step = 0; step < 8; ++step) {
        const int k0 = step * 32;
        __syncthreads();
        // stage A 128x32 fp32 -> bf16 (chunks of 8)
        for (int ci = tid; ci < 512; ci += 256) {
            int r = ci >> 2, ch = ci & 3;
            int gm = m0 + r;
            int sm = adj ? (adj[gm >> 8] * 256 + (gm & 255)) : gm;
            const float* src = X + (size_t)sm * 256 + k0 + ch * 8;
            float4 f0 = *(const float4*)src;
            float4 f1 = *(const float4*)(src + 4);
            bf16x8 v;
            v[0]=(short)f2bf(f0.x); v[1]=(short)f2bf(f0.y);
            v[2]=(short)f2bf(f0.z); v[3]=(short)f2bf(f0.w);
            v[4]=(short)f2bf(f1.x); v[5]=(short)f2bf(f1.y);
            v[6]=(short)f2bf(f1.z); v[7]=(short)f2bf(f1.w);
            *(bf16x8*)&As[r * 40 + ch * 8] = v;
        }
        __syncthreads();
        bf16x8 af[4], bfr[4];
        #pragma unroll
        for (int i = 0; i < 4; ++i)
            af[i] = *(const bf16x8*)&As[(wr + i * 16 + lr) * 40 + lk];
        #pragma unroll
        for (int j = 0; j < 4; ++j)
            bfr[j] = *(const bf16x8*)&Bs[(wc + j * 16 + lr) * 264 + k0 + lk];
        #pragma unroll
        for (int i = 0; i < 4; ++i)
            #pragma unroll
            for (int j = 0; j < 4; ++j)
                acc[i][j] = mfma_bf16(af[i], bfr[j], acc[i][j]);
    }
    // epilogue: tanh(acc + bias) -> bf16
    #pragma unroll
    for (int j = 0; j < 4; ++j) {
        int col = n0 + wc + j * 16 + lr;
        float bv = bias[col];
        #pragma unroll
        for (int i = 0; i < 4; ++i) {
            int rowb = m0 + wr + i * 16 + lq;
            #pragma unroll
            for (int r = 0; r < 4; ++r)
                Y[(size_t)(rowb + r) * 256 + col] =
                    (short)f2bf(fast_tanh(acc[i][j][r] + bv));
        }
    }
}

// ---------------------------------------------------------------------------
// Denominator partials: for attention a, qk-tile (128x128), head group g (32
// heads): partial[g][q][k] = sum_n exp(Q_n K_n^T / sqrt(32)).
// grid = (4 tiles, 32 groups, 4 attn), block = 256.
// ---------------------------------------------------------------------------
__global__ __launch_bounds__(256) void k_denom(
    const unsigned short* __restrict__ Qa, const unsigned short* __restrict__ Qb2,
    const unsigned short* __restrict__ Qc, const unsigned short* __restrict__ Qd,
    const unsigned short* __restrict__ Kb, float* __restrict__ partialBase)
{
    __shared__ __align__(16) short Qs[128 * 40];
    __shared__ __align__(16) short Ks[128 * 40];
    const int tid = threadIdx.x, w = tid >> 6, l = tid & 63;
    const int q0 = (blockIdx.x >> 1) * 128, k0 = (blockIdx.x & 1) * 128;
    const int g = blockIdx.y, a = blockIdx.z;
    const unsigned short* Qb = (a == 0) ? Qa : (a == 1) ? Qb2 : (a == 2) ? Qc : Qd;
    float* partial = partialBase + ((size_t)a * 32 + g) * 65536;
    const int lr = l & 15, lk = (l >> 4) * 8, lq = (l >> 4) * 4;

    f32x4 eacc[2][8] = {};
    for (int n = g * 32; n < g * 32 + 32; ++n) {
        const int c = n >> 7, b = n & 127;
        const size_t base = (size_t)b * 65536 + (size_t)c * 32;
        __syncthreads();
        for (int ci = tid; ci < 512; ci += 256) {
            int r = ci >> 2, ch = ci & 3;
            *(bf16x8*)&Qs[r * 40 + ch * 8] =
                *(const bf16x8*)(Qb + base + (size_t)(q0 + r) * 256 + ch * 8);
            *(bf16x8*)&Ks[r * 40 + ch * 8] =
                *(const bf16x8*)(Kb + base + (size_t)(k0 + r) * 256 + ch * 8);
        }
        __syncthreads();
        bf16x8 aq[2], bk[8];
        #pragma unroll
        for (int i = 0; i < 2; ++i)
            aq[i] = *(const bf16x8*)&Qs[(w * 32 + i * 16 + lr) * 40 + lk];
        #pragma unroll
        for (int j = 0; j < 8; ++j)
            bk[j] = *(const bf16x8*)&Ks[(j * 16 + lr) * 40 + lk];
        #pragma unroll
        for (int i = 0; i < 2; ++i)
            #pragma unroll
            for (int j = 0; j < 8; ++j) {
                f32x4 s = mfma_bf16(aq[i], bk[j], (f32x4){0.f, 0.f, 0.f, 0.f});
                #pragma unroll
                for (int r = 0; r < 4; ++r)
                    eacc[i][j][r] += __builtin_amdgcn_exp2f(s[r] * SM_SCALE);
            }
    }
    #pragma unroll
    for (int i = 0; i < 2; ++i)
        #pragma unroll
        for (int j = 0; j < 8; ++j)
            #pragma unroll
            for (int r = 0; r < 4; ++r) {
                int q = q0 + w * 32 + i * 16 + lq + r;
                int k = k0 + j * 16 + lr;
                partial[(size_t)q * 256 + k] = eacc[i][j][r];
            }
}

// Reduce 32 partials -> Dinv = 1/sum.  grid = (256, 4)
__global__ __launch_bounds__(256) void k_reduce(
    const float* __restrict__ partial, float* __restrict__ dinv)
{
    int a = blockIdx.y;
    int i = blockIdx.x * 256 + threadIdx.x;
    const float* p = partial + (size_t)a * 32 * 65536 + i;
    float s = 0.f;
    #pragma unroll
    for (int g = 0; g < 32; ++g) s += p[(size_t)g * 65536];
    dinv[(size_t)a * 65536 + i] = 1.0f / s;
}

// ---------------------------------------------------------------------------
// Attention output for one head: o = (exp(QK^T/sqrt32) * Dinv) @ V.
// grid = 1024 (one head per block), block = 256 (4 waves x 64 q-rows).
// k processed in 4 chunks of 64; P round-trips LDS; V^T staged in LDS.
// ---------------------------------------------------------------------------
__global__ __launch_bounds__(256) void k_attn(
    const unsigned short* __restrict__ Qb, const unsigned short* __restrict__ Kb,
    const unsigned short* __restrict__ Vb, const float* __restrict__ dinv,
    float* __restrict__ outp)
{
    __shared__ __align__(16) short Vt[32 * 264];      // V^T: [d=32][k=256] pad 264
    __shared__ __align__(16) short Pb[4][64 * 72];    // per-wave P: [64 q][64 k] pad 72
    const int tid = threadIdx.x, w = tid >> 6, l = tid & 63;
    const int n = blockIdx.x, c = n >> 7, b = n & 127;
    const int lr = l & 15, lk = (l >> 4) * 8, lq = (l >> 4) * 4;
    const size_t base = (size_t)b * 65536 + (size_t)c * 32;

    // stage V^T (thread t owns V row t = k index)
    {
        const unsigned short* vp = Vb + base + (size_t)tid * 256;
        bf16x8 v0 = *(const bf16x8*)(vp);
        bf16x8 v1 = *(const bf16x8*)(vp + 8);
        bf16x8 v2 = *(const bf16x8*)(vp + 16);
        bf16x8 v3 = *(const bf16x8*)(vp + 24);
        #pragma unroll
        for (int e = 0; e < 8; ++e) {
            Vt[(0  + e) * 264 + tid] = v0[e];
            Vt[(8  + e) * 264 + tid] = v1[e];
            Vt[(16 + e) * 264 + tid] = v2[e];
            Vt[(24 + e) * 264 + tid] = v3[e];
        }
    }
    __syncthreads();

    const int q0 = w * 64;
    bf16x8 aq[4];
    #pragma unroll
    for (int i = 0; i < 4; ++i)
        aq[i] = *(const bf16x8*)(Qb + base + (size_t)(q0 + i * 16 + lr) * 256 + lk);

    f32x4 oacc[4][2] = {};
    for (int kp = 0; kp < 4; ++kp) {
        const int k0 = kp * 64;
        bf16x8 bk[4];
        #pragma unroll
        for (int j = 0; j < 4; ++j)
            bk[j] = *(const bf16x8*)(Kb + base + (size_t)(k0 + j * 16 + lr) * 256 + lk);
        #pragma unroll
        for (int i = 0; i < 4; ++i)
            #pragma unroll
            for (int j = 0; j < 4; ++j) {
                f32x4 s = mfma_bf16(aq[i], bk[j], (f32x4){0.f, 0.f, 0.f, 0.f});
                #pragma unroll
                for (int r = 0; r < 4; ++r) {
                    int q = q0 + i * 16 + lq + r;
                    int k = k0 + j * 16 + lr;
                    float p = __builtin_amdgcn_exp2f(s[r] * SM_SCALE) *
                              dinv[(size_t)q * 256 + k];
                    Pb[w][(i * 16 + lq + r) * 72 + (j * 16 + lr)] = (short)f2bf(p);
                }
            }
        __syncthreads();
        // PV: o += P(64 x 64chunk) @ V(64chunk x 32)
        #pragma unroll
        for (int ks = 0; ks < 2; ++ks) {
            bf16x8 vb0 = *(const bf16x8*)&Vt[(0  + lr) * 264 + k0 + ks * 32 + lk];
            bf16x8 vb1 = *(const bf16x8*)&Vt[(16 + lr) * 264 + k0 + ks * 32 + lk];
            #pragma unroll
            for (int i = 0; i < 4; ++i) {
                bf16x8 pa = *(const bf16x8*)&Pb[w][(i * 16 + lr) * 72 + ks * 32 + lk];
                oacc[i][0] = mfma_bf16(pa, vb0, oacc[i][0]);
                oacc[i][1] = mfma_bf16(pa, vb1, oacc[i][1]);
            }
        }
        __syncthreads();
    }
    // store merged: out[b][q][c*32+d], fp32
    #pragma unroll
    for (int i = 0; i < 4; ++i)
        #pragma unroll
        for (int d = 0; d < 2; ++d)
            #pragma unroll
            for (int r = 0; r < 4; ++r) {
                int q = q0 + i * 16 + lq + r;
                int dc = d * 16 + lr;
                outp[(size_t)b * 65536 + (size_t)q * 256 + c * 32 + dc] =
                    oacc[i][d][r];
            }
}

// ---------------------------------------------------------------------------
// Final: o5 = tanh(concat(o1..o4) @ W5^T + b5).  M=32768, N=256, K=1024.
// A comes from 4 fp32 planes.  BM=128, BN=128, BK=64.  grid = (2, 256).
// ---------------------------------------------------------------------------
__global__ __launch_bounds__(256) void k_final(
    const float* __restrict__ p0, const float* __restrict__ p1,
    const float* __restrict__ p2, const float* __restrict__ p3,
    const unsigned short* __restrict__ W5b, const float* __restrict__ b5,
    float* __restrict__ out)
{
    __shared__ __align__(16) short As[128 * 72];
    __shared__ __align__(16) short Bs[128 * 72];
    const int tid = threadIdx.x, w = tid >> 6, l = tid & 63;
    const int n0 = blockIdx.x * 128, m0 = blockIdx.y * 128;
    const int lr = l & 15, lk = (l >> 4) * 8, lq = (l >> 4) * 4;
    const int wr = (w >> 1) * 64, wc = (w & 1) * 64;
    f32x4 acc[4][4] = {};
    for (int step = 0; step < 16; ++step) {
        const int k0 = step * 64;
        const float* P = (step < 4) ? p0 : (step < 8) ? p1 : (step < 12) ? p2 : p3;
        const int kc = k0 & 255;
        __syncthreads();
        for (int ci = tid; ci < 1024; ci += 256) {
            int r = ci >> 3, ch = ci & 7;
            const float* src = P + (size_t)(m0 + r) * 256 + kc + ch * 8;
            float4 f0 = *(const float4*)src;
            float4 f1 = *(const float4*)(src + 4);
            bf16x8 v;
            v[0]=(short)f2bf(f0.x); v[1]=(short)f2bf(f0.y);
            v[2]=(short)f2bf(f0.z); v[3]=(short)f2bf(f0.w);
            v[4]=(short)f2bf(f1.x); v[5]=(short)f2bf(f1.y);
            v[6]=(short)f2bf(f1.z); v[7]=(short)f2bf(f1.w);
            *(bf16x8*)&As[r * 72 + ch * 8] = v;
            *(bf16x8*)&Bs[r * 72 + ch * 8] =
                *(const bf16x8*)(W5b + (size_t)(n0 + r) * 1024 + k0 + ch * 8);
        }
        __syncthreads();
        #pragma unroll
        for (int kk = 0; kk < 2; ++kk) {
            bf16x8 af[4], bfr[4];
            #pragma unroll
            for (int i = 0; i < 4; ++i)
                af[i] = *(const bf16x8*)&As[(wr + i * 16 + lr) * 72 + kk * 32 + lk];
            #pragma unroll
            for (int j = 0; j < 4; ++j)
                bfr[j] = *(const bf16x8*)&Bs[(wc + j * 16 + lr) * 72 + kk * 32 + lk];
            #pragma unroll
            for (int i = 0; i < 4; ++i)
                #pragma unroll
                for (int j = 0; j < 4; ++j)
                    acc[i][j] = mfma_bf16(af[i], bfr[j], acc[i][j]);
        }
    }
    #pragma unroll
    for (int j = 0; j < 4; ++j) {
        int col = n0 + wc + j * 16 + lr;
        float bv = b5[col];
        #pragma unroll
        for (int i = 0; i < 4; ++i) {
            int rowb = m0 + wr + i * 16 + lq;
            #pragma unroll
            for (int r = 0; r < 4; ++r)
                out[(size_t)(rowb + r) * 256 + col] =
                    fast_tanh(acc[i][j][r] + bv);
        }
    }
}

// ---------------------------------------------------------------------------
extern "C" void kernel_launch(void* const* d_in, const int* in_sizes, int n_in,
                              void* d_out, int out_size, void* d_ws, size_t ws_size,
                              hipStream_t stream)
{
    const float* q1  = (const float*)d_in[0];
    const float* q2  = (const float*)d_in[1];
    const float* q3  = (const float*)d_in[2];
    const int*   adj = (const int*)d_in[3];
    const float* WQ  = (const float*)d_in[4];  const float* bQ  = (const float*)d_in[5];
    const float* WV  = (const float*)d_in[6];  const float* bV  = (const float*)d_in[7];
    const float* WQ3 = (const float*)d_in[8];  const float* bQ3 = (const float*)d_in[9];
    const float* WK3 = (const float*)d_in[10]; const float* bK3 = (const float*)d_in[11];
    const float* WV3 = (const float*)d_in[12]; const float* bV3 = (const float*)d_in[13];
    const float* WQ4 = (const float*)d_in[14]; const float* bQ4 = (const float*)d_in[15];
    const float* WV4 = (const float*)d_in[16]; const float* bV4 = (const float*)d_in[17];
    const float* W5  = (const float*)d_in[18]; const float* b5  = (const float*)d_in[19];

    char* ws = (char*)d_ws;
    unsigned short* wb   = (unsigned short*)ws;          // 720896 bf16 weights
    unsigned short* WQb  = wb;
    unsigned short* WVb  = wb + 65536;
    unsigned short* WQ3b = wb + 131072;
    unsigned short* WK3b = wb + 196608;
    unsigned short* WV3b = wb + 262144;
    unsigned short* WQ4b = wb + 327680;
    unsigned short* WV4b = wb + 393216;
    unsigned short* W5b  = wb + 458752;
    unsigned short* lin = (unsigned short*)(ws + 1441792);   // 9 x 32768x256 bf16
    unsigned short* Q1 = lin + 0ull * 8388608;
    unsigned short* Q2 = lin + 1ull * 8388608;
    unsigned short* Q3 = lin + 2ull * 8388608;
    unsigned short* Q4 = lin + 3ull * 8388608;
    unsigned short* K3 = lin + 4ull * 8388608;
    unsigned short* V1 = lin + 5ull * 8388608;
    unsigned short* V2 = lin + 6ull * 8388608;
    unsigned short* V3 = lin + 7ull * 8388608;
    unsigned short* V4 = lin + 8ull * 8388608;
    float* partial = (float*)(ws + 152436736);   // 4*32*65536 f32
    float* dinv    = (float*)(ws + 185991168);   // 4*65536 f32
    float* o4      = (float*)(ws + 152436736);   // overlaps partial (dead by then)

    float* outf = (float*)d_out;
    float* o1p = outf;
    float* o2p = outf + 8388608ull;
    float* o5p = outf + 2ull * 8388608;
    float* o3p = outf + 3ull * 8388608;

    dim3 blk(256);

    hipLaunchKernelGGL(k_convert_w, dim3(2816), blk, 0, stream,
                       WQ, WV, WQ3, WK3, WV3, WQ4, WV4, W5, wb);

    dim3 lgrid(2, 256);
    hipLaunchKernelGGL(k_linear, lgrid, blk, 0, stream, q1, (const int*)nullptr, WQb,  bQ,  Q1);
    hipLaunchKernelGGL(k_linear, lgrid, blk, 0, stream, q2, (const int*)nullptr, WQb,  bQ,  Q2);
    hipLaunchKernelGGL(k_linear, lgrid, blk, 0, stream, q3, (const int*)nullptr, WQ3b, bQ3, Q3);
    hipLaunchKernelGGL(k_linear, lgrid, blk, 0, stream, q3, adj,                 WQ4b, bQ4, Q4);
    hipLaunchKernelGGL(k_linear, lgrid, blk, 0, stream, q3, (const int*)nullptr, WK3b, bK3, K3);
    hipLaunchKernelGGL(k_linear, lgrid, blk, 0, stream, q1, (const int*)nullptr, WVb,  bV,  V1);
    hipLaunchKernelGGL(k_linear, lgrid, blk, 0, stream, q2, (const int*)nullptr, WVb,  bV,  V2);
    hipLaunchKernelGGL(k_linear, lgrid, blk, 0, stream, q3, (const int*)nullptr, WV3b, bV3, V3);
    hipLaunchKernelGGL(k_linear, lgrid, blk, 0, stream, q3, adj,                 WV4b, bV4, V4);

    hipLaunchKernelGGL(k_denom, dim3(4, 32, 4), blk, 0, stream,
                       Q1, Q2, Q3, Q4, K3, partial);
    hipLaunchKernelGGL(k_reduce, dim3(256, 4), blk, 0, stream, partial, dinv);

    hipLaunchKernelGGL(k_attn, dim3(1024), blk, 0, stream, Q1, K3, V1, dinv + 0ull * 65536, o1p);
    hipLaunchKernelGGL(k_attn, dim3(1024), blk, 0, stream, Q2, K3, V2, dinv + 1ull * 65536, o2p);
    hipLaunchKernelGGL(k_attn, dim3(1024), blk, 0, stream, Q3, K3, V3, dinv + 2ull * 65536, o3p);
    hipLaunchKernelGGL(k_attn, dim3(1024), blk, 0, stream, Q4, K3, V4, dinv + 3ull * 65536, o4);

    hipLaunchKernelGGL(k_final, dim3(2, 256), blk, 0, stream,
                       o1p, o2p, o3p, o4, W5b, b5, o5p);
}

// Round 2
// 536.622 us; speedup vs baseline: 1.4979x; 1.4979x over previous
//
#include <hip/hip_runtime.h>

// ---------------------------------------------------------------------------
// multihead_attention_87454124081549 — round 2
// B=128, S=256, NU=256, NH=32, heads n = c*128+b (c in [0,8)), M = B*S = 32768
// softmax is over axis 0 (the 1024-head axis) -> denominator D[q,k] per attn.
// Round-2 change: k_attn rewritten with swapped-operand QK^T (lane holds 4
// consecutive k at fixed q) -> float4 dinv loads, b64 packed P writes,
// zero barriers in the main loop, 32-k chunks (LDS 37 KB -> 4 blocks/CU),
// 4 attentions merged into one dispatch.
// ---------------------------------------------------------------------------

typedef __attribute__((ext_vector_type(4))) float f32x4;
typedef __attribute__((ext_vector_type(8))) short bf16x8;

#define LOG2E 1.4426950408889634f
#define SM_SCALE (1.4426950408889634f / 5.656854249492381f)  // log2(e)/sqrt(32)

__device__ __forceinline__ unsigned short f2bf(float x) {
    union { float f; unsigned u; } v; v.f = x;
    unsigned r = v.u + 0x7FFFu + ((v.u >> 16) & 1u);   // RNE
    return (unsigned short)(r >> 16);
}

__device__ __forceinline__ float fast_tanh(float x) {
    float e = __builtin_amdgcn_exp2f(x * (2.0f * LOG2E));   // exp(2x)
    return 1.0f - 2.0f * __builtin_amdgcn_rcpf(e + 1.0f);
}

__device__ __forceinline__ f32x4 mfma_bf16(bf16x8 a, bf16x8 b, f32x4 c) {
    return __builtin_amdgcn_mfma_f32_16x16x32_bf16(a, b, c, 0, 0, 0);
}

// ---------------------------------------------------------------------------
// Weight conversion: 7 x (256x256) + W5 (256x1024) fp32 -> bf16, concatenated.
// ---------------------------------------------------------------------------
__global__ __launch_bounds__(256) void k_convert_w(
    const float* w0, const float* w1, const float* w2, const float* w3,
    const float* w4, const float* w5, const float* w6, const float* w7,
    unsigned short* out)
{
    int i = blockIdx.x * 256 + threadIdx.x;
    if (i >= 720896) return;
    float v;
    if (i < 458752) {
        int r = i >> 16, j = i & 65535;
        const float* s =
            (r == 0) ? w0 : (r == 1) ? w1 : (r == 2) ? w2 :
            (r == 3) ? w3 : (r == 4) ? w4 : (r == 5) ? w5 : w6;
        v = s[j];
    } else {
        v = w7[i - 458752];
    }
    out[i] = (short)f2bf(v);
}

// ---------------------------------------------------------------------------
// Linear + tanh:  Y(bf16, 32768x256) = tanh(X(f32) @ W^T + bias)
// ---------------------------------------------------------------------------
__global__ __launch_bounds__(256) void k_linear(
    const float* __restrict__ X, const int* __restrict__ adj,
    const unsigned short* __restrict__ Wb, const float* __restrict__ bias,
    unsigned short* __restrict__ Y)
{
    __shared__ __align__(16) short Bs[128 * 264];  // 128 rows(n) x 256(k), pad 264
    __shared__ __align__(16) short As[128 * 40];   // 128 rows(m) x 32(k),  pad 40
    const int tid = threadIdx.x;
    const int w = tid >> 6, l = tid & 63;
    const int n0 = blockIdx.x * 128, m0 = blockIdx.y * 128;
    const int lr = l & 15, lk = (l >> 4) * 8, lq = (l >> 4) * 4;
    const int wr = (w >> 1) * 64, wc = (w & 1) * 64;

    for (int ci = tid; ci < 4096; ci += 256) {
        int r = ci >> 5, ch = ci & 31;
        *(bf16x8*)&Bs[r * 264 + ch * 8] =
            *(const bf16x8*)(Wb + (size_t)(n0 + r) * 256 + ch * 8);
    }

    f32x4 acc[4][4] = {};
    for (int step = 0; step < 8; ++step) {
        const int k0 = step * 32;
        __syncthreads();
        for (int ci = tid; ci < 512; ci += 256) {
            int r = ci >> 2, ch = ci & 3;
            int gm = m0 + r;
            int sm = adj ? (adj[gm >> 8] * 256 + (gm & 255)) : gm;
            const float* src = X + (size_t)sm * 256 + k0 + ch * 8;
            float4 f0 = *(const float4*)src;
            float4 f1 = *(const float4*)(src + 4);
            bf16x8 v;
            v[0]=(short)f2bf(f0.x); v[1]=(short)f2bf(f0.y);
            v[2]=(short)f2bf(f0.z); v[3]=(short)f2bf(f0.w);
            v[4]=(short)f2bf(f1.x); v[5]=(short)f2bf(f1.y);
            v[6]=(short)f2bf(f1.z); v[7]=(short)f2bf(f1.w);
            *(bf16x8*)&As[r * 40 + ch * 8] = v;
        }
        __syncthreads();
        bf16x8 af[4], bfr[4];
        #pragma unroll
        for (int i = 0; i < 4; ++i)
            af[i] = *(const bf16x8*)&As[(wr + i * 16 + lr) * 40 + lk];
        #pragma unroll
        for (int j = 0; j < 4; ++j)
            bfr[j] = *(const bf16x8*)&Bs[(wc + j * 16 + lr) * 264 + k0 + lk];
        #pragma unroll
        for (int i = 0; i < 4; ++i)
            #pragma unroll
            for (int j = 0; j < 4; ++j)
                acc[i][j] = mfma_bf16(af[i], bfr[j], acc[i][j]);
    }
    #pragma unroll
    for (int j = 0; j < 4; ++j) {
        int col = n0 + wc + j * 16 + lr;
        float bv = bias[col];
        #pragma unroll
        for (int i = 0; i < 4; ++i) {
            int rowb = m0 + wr + i * 16 + lq;
            #pragma unroll
            for (int r = 0; r < 4; ++r)
                Y[(size_t)(rowb + r) * 256 + col] =
                    (short)f2bf(fast_tanh(acc[i][j][r] + bv));
        }
    }
}

// ---------------------------------------------------------------------------
// Denominator partials.
// ---------------------------------------------------------------------------
__global__ __launch_bounds__(256) void k_denom(
    const unsigned short* __restrict__ Qa, const unsigned short* __restrict__ Qb2,
    const unsigned short* __restrict__ Qc, const unsigned short* __restrict__ Qd,
    const unsigned short* __restrict__ Kb, float* __restrict__ partialBase)
{
    __shared__ __align__(16) short Qs[128 * 40];
    __shared__ __align__(16) short Ks[128 * 40];
    const int tid = threadIdx.x, w = tid >> 6, l = tid & 63;
    const int q0 = (blockIdx.x >> 1) * 128, k0 = (blockIdx.x & 1) * 128;
    const int g = blockIdx.y, a = blockIdx.z;
    const unsigned short* Qb = (a == 0) ? Qa : (a == 1) ? Qb2 : (a == 2) ? Qc : Qd;
    float* partial = partialBase + ((size_t)a * 32 + g) * 65536;
    const int lr = l & 15, lk = (l >> 4) * 8, lq = (l >> 4) * 4;

    f32x4 eacc[2][8] = {};
    for (int n = g * 32; n < g * 32 + 32; ++n) {
        const int c = n >> 7, b = n & 127;
        const size_t base = (size_t)b * 65536 + (size_t)c * 32;
        __syncthreads();
        for (int ci = tid; ci < 512; ci += 256) {
            int r = ci >> 2, ch = ci & 3;
            *(bf16x8*)&Qs[r * 40 + ch * 8] =
                *(const bf16x8*)(Qb + base + (size_t)(q0 + r) * 256 + ch * 8);
            *(bf16x8*)&Ks[r * 40 + ch * 8] =
                *(const bf16x8*)(Kb + base + (size_t)(k0 + r) * 256 + ch * 8);
        }
        __syncthreads();
        bf16x8 aq[2], bk[8];
        #pragma unroll
        for (int i = 0; i < 2; ++i)
            aq[i] = *(const bf16x8*)&Qs[(w * 32 + i * 16 + lr) * 40 + lk];
        #pragma unroll
        for (int j = 0; j < 8; ++j)
            bk[j] = *(const bf16x8*)&Ks[(j * 16 + lr) * 40 + lk];
        #pragma unroll
        for (int i = 0; i < 2; ++i)
            #pragma unroll
            for (int j = 0; j < 8; ++j) {
                f32x4 s = mfma_bf16(aq[i], bk[j], (f32x4){0.f, 0.f, 0.f, 0.f});
                #pragma unroll
                for (int r = 0; r < 4; ++r)
                    eacc[i][j][r] += __builtin_amdgcn_exp2f(s[r] * SM_SCALE);
            }
    }
    #pragma unroll
    for (int i = 0; i < 2; ++i)
        #pragma unroll
        for (int j = 0; j < 8; ++j)
            #pragma unroll
            for (int r = 0; r < 4; ++r) {
                int q = q0 + w * 32 + i * 16 + lq + r;
                int k = k0 + j * 16 + lr;
                partial[(size_t)q * 256 + k] = eacc[i][j][r];
            }
}

// Reduce 32 partials -> Dinv = 1/sum.  grid = (256, 4)
__global__ __launch_bounds__(256) void k_reduce(
    const float* __restrict__ partial, float* __restrict__ dinv)
{
    int a = blockIdx.y;
    int i = blockIdx.x * 256 + threadIdx.x;
    const float* p = partial + (size_t)a * 32 * 65536 + i;
    float s = 0.f;
    #pragma unroll
    for (int g = 0; g < 32; ++g) s += p[(size_t)g * 65536];
    dinv[(size_t)a * 65536 + i] = 1.0f / s;
}

// ---------------------------------------------------------------------------
// Attention (all 4 merged): o = (exp(QK^T/sqrt32) * Dinv) @ V.
// grid = (1024 heads, 4 attn), block = 256 (4 waves x 64 q-rows).
// Swapped-operand QK^T: st = mfma(K_frag, Q_frag) -> lane holds 4 consecutive
// k at fixed q => float4 dinv loads + b64 P writes. No barriers in main loop
// (Pb is per-wave). k processed in 8 chunks of 32.
// ---------------------------------------------------------------------------
__global__ __launch_bounds__(256) void k_attn(
    const unsigned short* __restrict__ Q1, const unsigned short* __restrict__ Q2,
    const unsigned short* __restrict__ Q3, const unsigned short* __restrict__ Q4,
    const unsigned short* __restrict__ Kb,
    const unsigned short* __restrict__ V1, const unsigned short* __restrict__ V2,
    const unsigned short* __restrict__ V3, const unsigned short* __restrict__ V4,
    const float* __restrict__ dinvBase,
    float* __restrict__ o1, float* __restrict__ o2,
    float* __restrict__ o3, float* __restrict__ o4)
{
    __shared__ __align__(16) short Vt[32 * 264];      // V^T: [d=32][k=256] pad 264
    __shared__ __align__(16) short Pb[4][64 * 40];    // per-wave P: [64 q][32 k] pad 40
    const int tid = threadIdx.x, w = tid >> 6, l = tid & 63;
    const int n = blockIdx.x, c = n >> 7, b = n & 127;
    const int a = blockIdx.y;
    const int q16 = l & 15, h = l >> 4;
    const size_t base = (size_t)b * 65536 + (size_t)c * 32;

    const unsigned short* Qb = (a == 0) ? Q1 : (a == 1) ? Q2 : (a == 2) ? Q3 : Q4;
    const unsigned short* Vb = (a == 0) ? V1 : (a == 1) ? V2 : (a == 2) ? V3 : V4;
    float* outp               = (a == 0) ? o1 : (a == 1) ? o2 : (a == 2) ? o3 : o4;
    const float* dinv = dinvBase + (size_t)a * 65536;

    // stage V^T (thread t owns V row t = k index)
    {
        const unsigned short* vp = Vb + base + (size_t)tid * 256;
        bf16x8 v0 = *(const bf16x8*)(vp);
        bf16x8 v1 = *(const bf16x8*)(vp + 8);
        bf16x8 v2 = *(const bf16x8*)(vp + 16);
        bf16x8 v3 = *(const bf16x8*)(vp + 24);
        #pragma unroll
        for (int e = 0; e < 8; ++e) {
            Vt[(0  + e) * 264 + tid] = v0[e];
            Vt[(8  + e) * 264 + tid] = v1[e];
            Vt[(16 + e) * 264 + tid] = v2[e];
            Vt[(24 + e) * 264 + tid] = v3[e];
        }
    }
    __syncthreads();

    const int q0 = w * 64;
    short* Pw = Pb[w];
    bf16x8 bq[4];
    #pragma unroll
    for (int i = 0; i < 4; ++i)
        bq[i] = *(const bf16x8*)(Qb + base + (size_t)(q0 + i * 16 + q16) * 256 + h * 8);

    f32x4 oacc[4][2] = {};
    for (int kp = 0; kp < 8; ++kp) {
        const int kk0 = kp * 32;
        bf16x8 ak[2];
        #pragma unroll
        for (int j = 0; j < 2; ++j)
            ak[j] = *(const bf16x8*)(Kb + base + (size_t)(kk0 + j * 16 + q16) * 256 + h * 8);
        #pragma unroll
        for (int i = 0; i < 4; ++i)
            #pragma unroll
            for (int j = 0; j < 2; ++j) {
                // st[r] = S[q = q0+i*16+q16][k = kk0 + j*16 + h*4 + r]
                f32x4 st = mfma_bf16(ak[j], bq[i], (f32x4){0.f, 0.f, 0.f, 0.f});
                const float4 dv = *(const float4*)(dinv +
                    (size_t)(q0 + i * 16 + q16) * 256 + kk0 + j * 16 + h * 4);
                float p0 = __builtin_amdgcn_exp2f(st[0] * SM_SCALE) * dv.x;
                float p1 = __builtin_amdgcn_exp2f(st[1] * SM_SCALE) * dv.y;
                float p2 = __builtin_amdgcn_exp2f(st[2] * SM_SCALE) * dv.z;
                float p3 = __builtin_amdgcn_exp2f(st[3] * SM_SCALE) * dv.w;
                unsigned w0 = (unsigned)f2bf(p0) | ((unsigned)f2bf(p1) << 16);
                unsigned w1 = (unsigned)f2bf(p2) | ((unsigned)f2bf(p3) << 16);
                uint2 pk; pk.x = w0; pk.y = w1;
                *(uint2*)&Pw[(i * 16 + q16) * 40 + j * 16 + h * 4] = pk;
            }
        // PV: o += P(64 x 32) @ V(32 x 32)   (no barrier: per-wave buffer)
        bf16x8 vb0 = *(const bf16x8*)&Vt[(0  + q16) * 264 + kk0 + h * 8];
        bf16x8 vb1 = *(const bf16x8*)&Vt[(16 + q16) * 264 + kk0 + h * 8];
        #pragma unroll
        for (int i = 0; i < 4; ++i) {
            bf16x8 pa = *(const bf16x8*)&Pw[(i * 16 + q16) * 40 + h * 8];
            oacc[i][0] = mfma_bf16(pa, vb0, oacc[i][0]);
            oacc[i][1] = mfma_bf16(pa, vb1, oacc[i][1]);
        }
    }
    // store merged: out[b][q][c*32+d], fp32
    #pragma unroll
    for (int i = 0; i < 4; ++i)
        #pragma unroll
        for (int d = 0; d < 2; ++d)
            #pragma unroll
            for (int r = 0; r < 4; ++r) {
                int q = q0 + i * 16 + h * 4 + r;
                int dc = d * 16 + q16;
                outp[(size_t)b * 65536 + (size_t)q * 256 + c * 32 + dc] =
                    oacc[i][d][r];
            }
}

// ---------------------------------------------------------------------------
// Final: o5 = tanh(concat(o1..o4) @ W5^T + b5).  M=32768, N=256, K=1024.
// ---------------------------------------------------------------------------
__global__ __launch_bounds__(256) void k_final(
    const float* __restrict__ p0, const float* __restrict__ p1,
    const float* __restrict__ p2, const float* __restrict__ p3,
    const unsigned short* __restrict__ W5b, const float* __restrict__ b5,
    float* __restrict__ out)
{
    __shared__ __align__(16) short As[128 * 72];
    __shared__ __align__(16) short Bs[128 * 72];
    const int tid = threadIdx.x, w = tid >> 6, l = tid & 63;
    const int n0 = blockIdx.x * 128, m0 = blockIdx.y * 128;
    const int lr = l & 15, lk = (l >> 4) * 8, lq = (l >> 4) * 4;
    const int wr = (w >> 1) * 64, wc = (w & 1) * 64;
    f32x4 acc[4][4] = {};
    for (int step = 0; step < 16; ++step) {
        const int k0 = step * 64;
        const float* P = (step < 4) ? p0 : (step < 8) ? p1 : (step < 12) ? p2 : p3;
        const int kc = k0 & 255;
        __syncthreads();
        for (int ci = tid; ci < 1024; ci += 256) {
            int r = ci >> 3, ch = ci & 7;
            const float* src = P + (size_t)(m0 + r) * 256 + kc + ch * 8;
            float4 f0 = *(const float4*)src;
            float4 f1 = *(const float4*)(src + 4);
            bf16x8 v;
            v[0]=(short)f2bf(f0.x); v[1]=(short)f2bf(f0.y);
            v[2]=(short)f2bf(f0.z); v[3]=(short)f2bf(f0.w);
            v[4]=(short)f2bf(f1.x); v[5]=(short)f2bf(f1.y);
            v[6]=(short)f2bf(f1.z); v[7]=(short)f2bf(f1.w);
            *(bf16x8*)&As[r * 72 + ch * 8] = v;
            *(bf16x8*)&Bs[r * 72 + ch * 8] =
                *(const bf16x8*)(W5b + (size_t)(n0 + r) * 1024 + k0 + ch * 8);
        }
        __syncthreads();
        #pragma unroll
        for (int kk = 0; kk < 2; ++kk) {
            bf16x8 af[4], bfr[4];
            #pragma unroll
            for (int i = 0; i < 4; ++i)
                af[i] = *(const bf16x8*)&As[(wr + i * 16 + lr) * 72 + kk * 32 + lk];
            #pragma unroll
            for (int j = 0; j < 4; ++j)
                bfr[j] = *(const bf16x8*)&Bs[(wc + j * 16 + lr) * 72 + kk * 32 + lk];
            #pragma unroll
            for (int i = 0; i < 4; ++i)
                #pragma unroll
                for (int j = 0; j < 4; ++j)
                    acc[i][j] = mfma_bf16(af[i], bfr[j], acc[i][j]);
        }
    }
    #pragma unroll
    for (int j = 0; j < 4; ++j) {
        int col = n0 + wc + j * 16 + lr;
        float bv = b5[col];
        #pragma unroll
        for (int i = 0; i < 4; ++i) {
            int rowb = m0 + wr + i * 16 + lq;
            #pragma unroll
            for (int r = 0; r < 4; ++r)
                out[(size_t)(rowb + r) * 256 + col] =
                    fast_tanh(acc[i][j][r] + bv);
        }
    }
}

// ---------------------------------------------------------------------------
extern "C" void kernel_launch(void* const* d_in, const int* in_sizes, int n_in,
                              void* d_out, int out_size, void* d_ws, size_t ws_size,
                              hipStream_t stream)
{
    const float* q1  = (const float*)d_in[0];
    const float* q2  = (const float*)d_in[1];
    const float* q3  = (const float*)d_in[2];
    const int*   adj = (const int*)d_in[3];
    const float* WQ  = (const float*)d_in[4];  const float* bQ  = (const float*)d_in[5];
    const float* WV  = (const float*)d_in[6];  const float* bV  = (const float*)d_in[7];
    const float* WQ3 = (const float*)d_in[8];  const float* bQ3 = (const float*)d_in[9];
    const float* WK3 = (const float*)d_in[10]; const float* bK3 = (const float*)d_in[11];
    const float* WV3 = (const float*)d_in[12]; const float* bV3 = (const float*)d_in[13];
    const float* WQ4 = (const float*)d_in[14]; const float* bQ4 = (const float*)d_in[15];
    const float* WV4 = (const float*)d_in[16]; const float* bV4 = (const float*)d_in[17];
    const float* W5  = (const float*)d_in[18]; const float* b5  = (const float*)d_in[19];

    char* ws = (char*)d_ws;
    unsigned short* wb   = (unsigned short*)ws;          // 720896 bf16 weights
    unsigned short* WQb  = wb;
    unsigned short* WVb  = wb + 65536;
    unsigned short* WQ3b = wb + 131072;
    unsigned short* WK3b = wb + 196608;
    unsigned short* WV3b = wb + 262144;
    unsigned short* WQ4b = wb + 327680;
    unsigned short* WV4b = wb + 393216;
    unsigned short* W5b  = wb + 458752;
    unsigned short* lin = (unsigned short*)(ws + 1441792);   // 9 x 32768x256 bf16
    unsigned short* Q1 = lin + 0ull * 8388608;
    unsigned short* Q2 = lin + 1ull * 8388608;
    unsigned short* Q3 = lin + 2ull * 8388608;
    unsigned short* Q4 = lin + 3ull * 8388608;
    unsigned short* K3 = lin + 4ull * 8388608;
    unsigned short* V1 = lin + 5ull * 8388608;
    unsigned short* V2 = lin + 6ull * 8388608;
    unsigned short* V3 = lin + 7ull * 8388608;
    unsigned short* V4 = lin + 8ull * 8388608;
    float* partial = (float*)(ws + 152436736);   // 4*32*65536 f32
    float* dinv    = (float*)(ws + 185991168);   // 4*65536 f32
    float* o4      = (float*)(ws + 152436736);   // overlaps partial (dead by then)

    float* outf = (float*)d_out;
    float* o1p = outf;
    float* o2p = outf + 8388608ull;
    float* o5p = outf + 2ull * 8388608;
    float* o3p = outf + 3ull * 8388608;

    dim3 blk(256);

    hipLaunchKernelGGL(k_convert_w, dim3(2816), blk, 0, stream,
                       WQ, WV, WQ3, WK3, WV3, WQ4, WV4, W5, wb);

    dim3 lgrid(2, 256);
    hipLaunchKernelGGL(k_linear, lgrid, blk, 0, stream, q1, (const int*)nullptr, WQb,  bQ,  Q1);
    hipLaunchKernelGGL(k_linear, lgrid, blk, 0, stream, q2, (const int*)nullptr, WQb,  bQ,  Q2);
    hipLaunchKernelGGL(k_linear, lgrid, blk, 0, stream, q3, (const int*)nullptr, WQ3b, bQ3, Q3);
    hipLaunchKernelGGL(k_linear, lgrid, blk, 0, stream, q3, adj,                 WQ4b, bQ4, Q4);
    hipLaunchKernelGGL(k_linear, lgrid, blk, 0, stream, q3, (const int*)nullptr, WK3b, bK3, K3);
    hipLaunchKernelGGL(k_linear, lgrid, blk, 0, stream, q1, (const int*)nullptr, WVb,  bV,  V1);
    hipLaunchKernelGGL(k_linear, lgrid, blk, 0, stream, q2, (const int*)nullptr, WVb,  bV,  V2);
    hipLaunchKernelGGL(k_linear, lgrid, blk, 0, stream, q3, (const int*)nullptr, WV3b, bV3, V3);
    hipLaunchKernelGGL(k_linear, lgrid, blk, 0, stream, q3, adj,                 WV4b, bV4, V4);

    hipLaunchKernelGGL(k_denom, dim3(4, 32, 4), blk, 0, stream,
                       Q1, Q2, Q3, Q4, K3, partial);
    hipLaunchKernelGGL(k_reduce, dim3(256, 4), blk, 0, stream, partial, dinv);

    hipLaunchKernelGGL(k_attn, dim3(1024, 4), blk, 0, stream,
                       Q1, Q2, Q3, Q4, K3, V1, V2, V3, V4, dinv,
                       o1p, o2p, o3p, o4);

    hipLaunchKernelGGL(k_final, dim3(2, 256), blk, 0, stream,
                       o1p, o2p, o3p, o4, W5b, b5, o5p);
}

// Round 3
// 531.615 us; speedup vs baseline: 1.5120x; 1.0094x over previous
//
#include <hip/hip_runtime.h>

// ---------------------------------------------------------------------------
// multihead_attention_87454124081549 — round 3
// B=128, S=256, NU=256, NH=32, heads n = c*128+b (c in [0,8)), M = B*S = 32768
// softmax over axis 0 (1024-head axis) -> denominator D[q,k] per attn.
// Round-3: k_attn P stays in registers (cvt_pk_bf16 + permlane16/32_swap 4x4
// lane-row transpose replaces the LDS round trip); XCD-swizzled (a,n) grid;
// 9 linears merged into one grid.z=9 dispatch; o4 bf16-only (overlaps dead
// partial buffer), k_final reads it bf16.
// ---------------------------------------------------------------------------

typedef __attribute__((ext_vector_type(4))) float f32x4;
typedef __attribute__((ext_vector_type(8))) short bf16x8;

#define LOG2E 1.4426950408889634f
#define SM_SCALE (1.4426950408889634f / 5.656854249492381f)  // log2(e)/sqrt(32)

#define CVT_PK(d, lo, hi) \
    asm("v_cvt_pk_bf16_f32 %0, %1, %2" : "=v"(d) : "v"(lo), "v"(hi))
#define SWAP32(x, y) \
    asm("v_permlane32_swap_b32 %0, %1" : "+v"(x), "+v"(y))
#define SWAP16(x, y) \
    asm("v_permlane16_swap_b32 %0, %1" : "+v"(x), "+v"(y))

__device__ __forceinline__ unsigned short f2bf(float x) {
    union { float f; unsigned u; } v; v.f = x;
    unsigned r = v.u + 0x7FFFu + ((v.u >> 16) & 1u);   // RNE
    return (unsigned short)(r >> 16);
}

__device__ __forceinline__ float fast_tanh(float x) {
    float e = __builtin_amdgcn_exp2f(x * (2.0f * LOG2E));   // exp(2x)
    return 1.0f - 2.0f * __builtin_amdgcn_rcpf(e + 1.0f);
}

__device__ __forceinline__ f32x4 mfma_bf16(bf16x8 a, bf16x8 b, f32x4 c) {
    return __builtin_amdgcn_mfma_f32_16x16x32_bf16(a, b, c, 0, 0, 0);
}

// ---------------------------------------------------------------------------
// Weight conversion: 7 x (256x256) + W5 (256x1024) fp32 -> bf16, concatenated.
// Order: WQ(0) WV(1) WQ3(2) WK3(3) WV3(4) WQ4(5) WV4(6) W5(@458752)
// ---------------------------------------------------------------------------
__global__ __launch_bounds__(256) void k_convert_w(
    const float* w0, const float* w1, const float* w2, const float* w3,
    const float* w4, const float* w5, const float* w6, const float* w7,
    unsigned short* out)
{
    int i = blockIdx.x * 256 + threadIdx.x;
    if (i >= 720896) return;
    float v;
    if (i < 458752) {
        int r = i >> 16, j = i & 65535;
        const float* s =
            (r == 0) ? w0 : (r == 1) ? w1 : (r == 2) ? w2 :
            (r == 3) ? w3 : (r == 4) ? w4 : (r == 5) ? w5 : w6;
        v = s[j];
    } else {
        v = w7[i - 458752];
    }
    out[i] = (short)f2bf(v);
}

// ---------------------------------------------------------------------------
// Linear + tanh, all 9 in one dispatch:  Y(bf16) = tanh(X(f32) @ W^T + bias)
// grid = (2, 256, 9), block = 256.
// z: 0:Q1 1:Q2 2:Q3 3:Q4(gather) 4:K3 5:V1 6:V2 7:V3 8:V4(gather)
// ---------------------------------------------------------------------------
__global__ __launch_bounds__(256) void k_linear(
    const float* __restrict__ q1, const float* __restrict__ q2,
    const float* __restrict__ q3, const int* __restrict__ adj,
    const unsigned short* __restrict__ wb,
    const float* __restrict__ bQ, const float* __restrict__ bV,
    const float* __restrict__ bQ3, const float* __restrict__ bK3,
    const float* __restrict__ bV3, const float* __restrict__ bQ4,
    const float* __restrict__ bV4,
    unsigned short* __restrict__ lin)
{
    __shared__ __align__(16) short Bs[128 * 264];  // 128 n-rows x 256 k, pad 264
    __shared__ __align__(16) short As[128 * 40];   // 128 m-rows x 32 k, pad 40
    const int z = blockIdx.z;
    const float* X = (z == 0 || z == 5) ? q1 : (z == 1 || z == 6) ? q2 : q3;
    const bool gather = (z == 3 || z == 8);
    const int widx = (z == 0 || z == 1) ? 0 : (z == 2) ? 2 : (z == 3) ? 5 :
                     (z == 4) ? 3 : (z == 5 || z == 6) ? 1 : (z == 7) ? 4 : 6;
    const float* bias = (z == 0 || z == 1) ? bQ : (z == 2) ? bQ3 : (z == 3) ? bQ4 :
                        (z == 4) ? bK3 : (z == 5 || z == 6) ? bV : (z == 7) ? bV3 : bV4;
    const unsigned short* Wb = wb + (size_t)widx * 65536;
    unsigned short* Y = lin + (size_t)z * 8388608;

    const int tid = threadIdx.x;
    const int w = tid >> 6, l = tid & 63;
    const int n0 = blockIdx.x * 128, m0 = blockIdx.y * 128;
    const int lr = l & 15, lk = (l >> 4) * 8, lq = (l >> 4) * 4;
    const int wr = (w >> 1) * 64, wc = (w & 1) * 64;

    for (int ci = tid; ci < 4096; ci += 256) {
        int r = ci >> 5, ch = ci & 31;
        *(bf16x8*)&Bs[r * 264 + ch * 8] =
            *(const bf16x8*)(Wb + (size_t)(n0 + r) * 256 + ch * 8);
    }

    f32x4 acc[4][4] = {};
    for (int step = 0; step < 8; ++step) {
        const int k0 = step * 32;
        __syncthreads();
        for (int ci = tid; ci < 512; ci += 256) {
            int r = ci >> 2, ch = ci & 3;
            int gm = m0 + r;
            int sm = gather ? (adj[gm >> 8] * 256 + (gm & 255)) : gm;
            const float* src = X + (size_t)sm * 256 + k0 + ch * 8;
            float4 f0 = *(const float4*)src;
            float4 f1 = *(const float4*)(src + 4);
            bf16x8 v;
            v[0]=(short)f2bf(f0.x); v[1]=(short)f2bf(f0.y);
            v[2]=(short)f2bf(f0.z); v[3]=(short)f2bf(f0.w);
            v[4]=(short)f2bf(f1.x); v[5]=(short)f2bf(f1.y);
            v[6]=(short)f2bf(f1.z); v[7]=(short)f2bf(f1.w);
            *(bf16x8*)&As[r * 40 + ch * 8] = v;
        }
        __syncthreads();
        bf16x8 af[4], bfr[4];
        #pragma unroll
        for (int i = 0; i < 4; ++i)
            af[i] = *(const bf16x8*)&As[(wr + i * 16 + lr) * 40 + lk];
        #pragma unroll
        for (int j = 0; j < 4; ++j)
            bfr[j] = *(const bf16x8*)&Bs[(wc + j * 16 + lr) * 264 + k0 + lk];
        #pragma unroll
        for (int i = 0; i < 4; ++i)
            #pragma unroll
            for (int j = 0; j < 4; ++j)
                acc[i][j] = mfma_bf16(af[i], bfr[j], acc[i][j]);
    }
    #pragma unroll
    for (int j = 0; j < 4; ++j) {
        int col = n0 + wc + j * 16 + lr;
        float bv = bias[col];
        #pragma unroll
        for (int i = 0; i < 4; ++i) {
            int rowb = m0 + wr + i * 16 + lq;
            #pragma unroll
            for (int r = 0; r < 4; ++r)
                Y[(size_t)(rowb + r) * 256 + col] =
                    (short)f2bf(fast_tanh(acc[i][j][r] + bv));
        }
    }
}

// ---------------------------------------------------------------------------
// Denominator partials: partial[a][g][q][k] = sum_{n in g} exp(QK^T/sqrt32).
// grid = (4 tiles, 32 groups, 4 attn), block = 256.
// ---------------------------------------------------------------------------
__global__ __launch_bounds__(256) void k_denom(
    const unsigned short* __restrict__ Qa, const unsigned short* __restrict__ Qb2,
    const unsigned short* __restrict__ Qc, const unsigned short* __restrict__ Qd,
    const unsigned short* __restrict__ Kb, float* __restrict__ partialBase)
{
    __shared__ __align__(16) short Qs[128 * 40];
    __shared__ __align__(16) short Ks[128 * 40];
    const int tid = threadIdx.x, w = tid >> 6, l = tid & 63;
    const int q0 = (blockIdx.x >> 1) * 128, k0 = (blockIdx.x & 1) * 128;
    const int g = blockIdx.y, a = blockIdx.z;
    const unsigned short* Qb = (a == 0) ? Qa : (a == 1) ? Qb2 : (a == 2) ? Qc : Qd;
    float* partial = partialBase + ((size_t)a * 32 + g) * 65536;
    const int lr = l & 15, lk = (l >> 4) * 8, lq = (l >> 4) * 4;

    f32x4 eacc[2][8] = {};
    for (int n = g * 32; n < g * 32 + 32; ++n) {
        const int c = n >> 7, b = n & 127;
        const size_t base = (size_t)b * 65536 + (size_t)c * 32;
        __syncthreads();
        for (int ci = tid; ci < 512; ci += 256) {
            int r = ci >> 2, ch = ci & 3;
            *(bf16x8*)&Qs[r * 40 + ch * 8] =
                *(const bf16x8*)(Qb + base + (size_t)(q0 + r) * 256 + ch * 8);
            *(bf16x8*)&Ks[r * 40 + ch * 8] =
                *(const bf16x8*)(Kb + base + (size_t)(k0 + r) * 256 + ch * 8);
        }
        __syncthreads();
        bf16x8 aq[2], bk[8];
        #pragma unroll
        for (int i = 0; i < 2; ++i)
            aq[i] = *(const bf16x8*)&Qs[(w * 32 + i * 16 + lr) * 40 + lk];
        #pragma unroll
        for (int j = 0; j < 8; ++j)
            bk[j] = *(const bf16x8*)&Ks[(j * 16 + lr) * 40 + lk];
        #pragma unroll
        for (int i = 0; i < 2; ++i)
            #pragma unroll
            for (int j = 0; j < 8; ++j) {
                f32x4 s = mfma_bf16(aq[i], bk[j], (f32x4){0.f, 0.f, 0.f, 0.f});
                #pragma unroll
                for (int r = 0; r < 4; ++r)
                    eacc[i][j][r] += __builtin_amdgcn_exp2f(s[r] * SM_SCALE);
            }
    }
    #pragma unroll
    for (int i = 0; i < 2; ++i)
        #pragma unroll
        for (int j = 0; j < 8; ++j)
            #pragma unroll
            for (int r = 0; r < 4; ++r) {
                int q = q0 + w * 32 + i * 16 + lq + r;
                int k = k0 + j * 16 + lr;
                partial[(size_t)q * 256 + k] = eacc[i][j][r];
            }
}

// Reduce 32 partials -> Dinv = 1/sum.  grid = (256, 4)
__global__ __launch_bounds__(256) void k_reduce(
    const float* __restrict__ partial, float* __restrict__ dinv)
{
    int a = blockIdx.y;
    int i = blockIdx.x * 256 + threadIdx.x;
    const float* p = partial + (size_t)a * 32 * 65536 + i;
    float s = 0.f;
    #pragma unroll
    for (int g = 0; g < 32; ++g) s += p[(size_t)g * 65536];
    dinv[(size_t)a * 65536 + i] = 1.0f / s;
}

// ---------------------------------------------------------------------------
// Attention: o = (exp(QK^T/sqrt32) * Dinv) @ V.  grid = 4096 (XCD-swizzled
// over (head n, attn a)), block = 256 (4 waves x 64 q-rows).
// P never touches LDS: cvt_pk_bf16 pairs + permlane16/32 4x4 row transpose
// convert the QK C-layout directly into the PV A-fragment layout.
// a<3 writes fp32 to d_out plane; a==3 writes bf16 to ob4 (ws).
// ---------------------------------------------------------------------------
__global__ __launch_bounds__(256) void k_attn(
    const unsigned short* __restrict__ Q1, const unsigned short* __restrict__ Q2,
    const unsigned short* __restrict__ Q3, const unsigned short* __restrict__ Q4,
    const unsigned short* __restrict__ Kb,
    const unsigned short* __restrict__ V1, const unsigned short* __restrict__ V2,
    const unsigned short* __restrict__ V3, const unsigned short* __restrict__ V4,
    const float* __restrict__ dinvBase,
    float* __restrict__ outBase, unsigned short* __restrict__ ob4)
{
    __shared__ __align__(16) short Vt[32 * 264];      // V^T: [d=32][k=256] pad 264
    const int tid = threadIdx.x, w = tid >> 6, l = tid & 63;
    // XCD swizzle: 4096 blocks, 8 XCDs. bid = x + 8t -> swz = 512x + t:
    // same-XCD consecutive blocks share the K tile (4 attn per head n).
    const int bid = blockIdx.x;
    const int swz = (bid & 7) * 512 + (bid >> 3);
    const int a = swz & 3, n = swz >> 2;
    const int c = n >> 7, b = n & 127;
    const int q16 = l & 15, h = l >> 4;
    const size_t base = (size_t)b * 65536 + (size_t)c * 32;

    const unsigned short* Qb = (a == 0) ? Q1 : (a == 1) ? Q2 : (a == 2) ? Q3 : Q4;
    const unsigned short* Vb = (a == 0) ? V1 : (a == 1) ? V2 : (a == 2) ? V3 : V4;
    const float* dinv = dinvBase + (size_t)a * 65536;
    float* outp = outBase + (size_t)((a == 2) ? 3 : a) * 8388608;

    // stage V^T (thread t owns V row t = k index)
    {
        const unsigned short* vp = Vb + base + (size_t)tid * 256;
        bf16x8 v0 = *(const bf16x8*)(vp);
        bf16x8 v1 = *(const bf16x8*)(vp + 8);
        bf16x8 v2 = *(const bf16x8*)(vp + 16);
        bf16x8 v3 = *(const bf16x8*)(vp + 24);
        #pragma unroll
        for (int e = 0; e < 8; ++e) {
            Vt[(0  + e) * 264 + tid] = v0[e];
            Vt[(8  + e) * 264 + tid] = v1[e];
            Vt[(16 + e) * 264 + tid] = v2[e];
            Vt[(24 + e) * 264 + tid] = v3[e];
        }
    }
    __syncthreads();

    const int q0 = w * 64;
    bf16x8 bq[4];
    #pragma unroll
    for (int i = 0; i < 4; ++i)
        bq[i] = *(const bf16x8*)(Qb + base + (size_t)(q0 + i * 16 + q16) * 256 + h * 8);

    f32x4 oacc[4][2] = {};
    #pragma unroll 2
    for (int kp = 0; kp < 8; ++kp) {
        const int kk0 = kp * 32;
        bf16x8 ak0 = *(const bf16x8*)(Kb + base + (size_t)(kk0 + q16) * 256 + h * 8);
        bf16x8 ak1 = *(const bf16x8*)(Kb + base + (size_t)(kk0 + 16 + q16) * 256 + h * 8);
        bf16x8 vb0 = *(const bf16x8*)&Vt[(0  + q16) * 264 + kk0 + h * 8];
        bf16x8 vb1 = *(const bf16x8*)&Vt[(16 + q16) * 264 + kk0 + h * 8];
        #pragma unroll
        for (int i = 0; i < 4; ++i) {
            // st[r] = S[q=q0+16i+q16][k = kk0 + 16j + 4h + r]
            f32x4 s0 = mfma_bf16(ak0, bq[i], (f32x4){0.f, 0.f, 0.f, 0.f});
            f32x4 s1 = mfma_bf16(ak1, bq[i], (f32x4){0.f, 0.f, 0.f, 0.f});
            const float* dq = dinv + (size_t)(q0 + i * 16 + q16) * 256 + kk0 + h * 4;
            const float4 d0 = *(const float4*)(dq);
            const float4 d1 = *(const float4*)(dq + 16);
            float p0 = __builtin_amdgcn_exp2f(s0[0] * SM_SCALE) * d0.x;
            float p1 = __builtin_amdgcn_exp2f(s0[1] * SM_SCALE) * d0.y;
            float p2 = __builtin_amdgcn_exp2f(s0[2] * SM_SCALE) * d0.z;
            float p3 = __builtin_amdgcn_exp2f(s0[3] * SM_SCALE) * d0.w;
            float p4 = __builtin_amdgcn_exp2f(s1[0] * SM_SCALE) * d1.x;
            float p5 = __builtin_amdgcn_exp2f(s1[1] * SM_SCALE) * d1.y;
            float p6 = __builtin_amdgcn_exp2f(s1[2] * SM_SCALE) * d1.z;
            float p7 = __builtin_amdgcn_exp2f(s1[3] * SM_SCALE) * d1.w;
            // pack: r0=pairs(4h,4h+1) r1=(4h+2,4h+3) r2=(16+4h,..) r3=(16+4h+2,..)
            unsigned r0, r1, r2, r3;
            CVT_PK(r0, p0, p1);
            CVT_PK(r1, p2, p3);
            CVT_PK(r2, p4, p5);
            CVT_PK(r3, p6, p7);
            // 4x4 transpose across 16-lane rows: rows hold pair-slots
            // (2h, 2h+1, 8+2h, 9+2h) -> need (4h+m), m=0..3.
            SWAP32(r0, r2); SWAP16(r0, r2);   // r0 -> out0, r2 -> out2
            SWAP32(r1, r3); SWAP16(r1, r3);   // r1 -> out1, r3 -> out3
            union { unsigned u[4]; bf16x8 v; } F;
            F.u[0] = r0; F.u[1] = r1; F.u[2] = r2; F.u[3] = r3;
            oacc[i][0] = mfma_bf16(F.v, vb0, oacc[i][0]);
            oacc[i][1] = mfma_bf16(F.v, vb1, oacc[i][1]);
        }
    }
    // store merged layout out[b][q][c*32+dc]
    if (a == 3) {
        #pragma unroll
        for (int i = 0; i < 4; ++i)
            #pragma unroll
            for (int d = 0; d < 2; ++d)
                #pragma unroll
                for (int r = 0; r < 4; ++r) {
                    int q = q0 + i * 16 + h * 4 + r;
                    int dc = d * 16 + q16;
                    ob4[(size_t)b * 65536 + (size_t)q * 256 + c * 32 + dc] =
                        f2bf(oacc[i][d][r]);
                }
    } else {
        #pragma unroll
        for (int i = 0; i < 4; ++i)
            #pragma unroll
            for (int d = 0; d < 2; ++d)
                #pragma unroll
                for (int r = 0; r < 4; ++r) {
                    int q = q0 + i * 16 + h * 4 + r;
                    int dc = d * 16 + q16;
                    outp[(size_t)b * 65536 + (size_t)q * 256 + c * 32 + dc] =
                        oacc[i][d][r];
                }
    }
}

// ---------------------------------------------------------------------------
// Final: o5 = tanh(concat(o1..o4) @ W5^T + b5).  M=32768, N=256, K=1024.
// o1..o3 fp32 (d_out planes), o4 bf16 (ws).  BM=128, BN=128, BK=64.
// ---------------------------------------------------------------------------
__global__ __launch_bounds__(256) void k_final(
    const float* __restrict__ p0, const float* __restrict__ p1,
    const float* __restrict__ p2, const unsigned short* __restrict__ p3,
    const unsigned short* __restrict__ W5b, const float* __restrict__ b5,
    float* __restrict__ out)
{
    __shared__ __align__(16) short As[128 * 72];
    __shared__ __align__(16) short Bs[128 * 72];
    const int tid = threadIdx.x, w = tid >> 6, l = tid & 63;
    const int n0 = blockIdx.x * 128, m0 = blockIdx.y * 128;
    const int lr = l & 15, lk = (l >> 4) * 8, lq = (l >> 4) * 4;
    const int wr = (w >> 1) * 64, wc = (w & 1) * 64;
    f32x4 acc[4][4] = {};
    for (int step = 0; step < 16; ++step) {
        const int k0 = step * 64;
        const int kc = k0 & 255;
        __syncthreads();
        if (step < 12) {
            const float* P = (step < 4) ? p0 : (step < 8) ? p1 : p2;
            for (int ci = tid; ci < 1024; ci += 256) {
                int r = ci >> 3, ch = ci & 7;
                const float* src = P + (size_t)(m0 + r) * 256 + kc + ch * 8;
                float4 f0 = *(const float4*)src;
                float4 f1 = *(const float4*)(src + 4);
                bf16x8 v;
                v[0]=(short)f2bf(f0.x); v[1]=(short)f2bf(f0.y);
                v[2]=(short)f2bf(f0.z); v[3]=(short)f2bf(f0.w);
                v[4]=(short)f2bf(f1.x); v[5]=(short)f2bf(f1.y);
                v[6]=(short)f2bf(f1.z); v[7]=(short)f2bf(f1.w);
                *(bf16x8*)&As[r * 72 + ch * 8] = v;
                *(bf16x8*)&Bs[r * 72 + ch * 8] =
                    *(const bf16x8*)(W5b + (size_t)(n0 + r) * 1024 + k0 + ch * 8);
            }
        } else {
            for (int ci = tid; ci < 1024; ci += 256) {
                int r = ci >> 3, ch = ci & 7;
                *(bf16x8*)&As[r * 72 + ch * 8] =
                    *(const bf16x8*)(p3 + (size_t)(m0 + r) * 256 + kc + ch * 8);
                *(bf16x8*)&Bs[r * 72 + ch * 8] =
                    *(const bf16x8*)(W5b + (size_t)(n0 + r) * 1024 + k0 + ch * 8);
            }
        }
        __syncthreads();
        #pragma unroll
        for (int kk = 0; kk < 2; ++kk) {
            bf16x8 af[4], bfr[4];
            #pragma unroll
            for (int i = 0; i < 4; ++i)
                af[i] = *(const bf16x8*)&As[(wr + i * 16 + lr) * 72 + kk * 32 + lk];
            #pragma unroll
            for (int j = 0; j < 4; ++j)
                bfr[j] = *(const bf16x8*)&Bs[(wc + j * 16 + lr) * 72 + kk * 32 + lk];
            #pragma unroll
            for (int i = 0; i < 4; ++i)
                #pragma unroll
                for (int j = 0; j < 4; ++j)
                    acc[i][j] = mfma_bf16(af[i], bfr[j], acc[i][j]);
        }
    }
    #pragma unroll
    for (int j = 0; j < 4; ++j) {
        int col = n0 + wc + j * 16 + lr;
        float bv = b5[col];
        #pragma unroll
        for (int i = 0; i < 4; ++i) {
            int rowb = m0 + wr + i * 16 + lq;
            #pragma unroll
            for (int r = 0; r < 4; ++r)
                out[(size_t)(rowb + r) * 256 + col] =
                    fast_tanh(acc[i][j][r] + bv);
        }
    }
}

// ---------------------------------------------------------------------------
extern "C" void kernel_launch(void* const* d_in, const int* in_sizes, int n_in,
                              void* d_out, int out_size, void* d_ws, size_t ws_size,
                              hipStream_t stream)
{
    const float* q1  = (const float*)d_in[0];
    const float* q2  = (const float*)d_in[1];
    const float* q3  = (const float*)d_in[2];
    const int*   adj = (const int*)d_in[3];
    const float* WQ  = (const float*)d_in[4];  const float* bQ  = (const float*)d_in[5];
    const float* WV  = (const float*)d_in[6];  const float* bV  = (const float*)d_in[7];
    const float* WQ3 = (const float*)d_in[8];  const float* bQ3 = (const float*)d_in[9];
    const float* WK3 = (const float*)d_in[10]; const float* bK3 = (const float*)d_in[11];
    const float* WV3 = (const float*)d_in[12]; const float* bV3 = (const float*)d_in[13];
    const float* WQ4 = (const float*)d_in[14]; const float* bQ4 = (const float*)d_in[15];
    const float* WV4 = (const float*)d_in[16]; const float* bV4 = (const float*)d_in[17];
    const float* W5  = (const float*)d_in[18]; const float* b5  = (const float*)d_in[19];

    char* ws = (char*)d_ws;
    unsigned short* wb  = (unsigned short*)ws;               // 720896 bf16 weights
    unsigned short* W5b = wb + 458752;
    unsigned short* lin = (unsigned short*)(ws + 1441792);   // 9 x 32768x256 bf16
    unsigned short* Q1 = lin + 0ull * 8388608;
    unsigned short* Q2 = lin + 1ull * 8388608;
    unsigned short* Q3 = lin + 2ull * 8388608;
    unsigned short* Q4 = lin + 3ull * 8388608;
    unsigned short* K3 = lin + 4ull * 8388608;
    unsigned short* V1 = lin + 5ull * 8388608;
    unsigned short* V2 = lin + 6ull * 8388608;
    unsigned short* V3 = lin + 7ull * 8388608;
    unsigned short* V4 = lin + 8ull * 8388608;
    float* partial = (float*)(ws + 152436736);               // 4*32*65536 f32
    float* dinv    = (float*)(ws + 185991168);               // 4*65536 f32
    unsigned short* ob4 = (unsigned short*)(ws + 152436736); // o4 bf16, overlaps dead partial

    float* outf = (float*)d_out;   // planes: o1(0) o2(1) o5(2) o3(3)
    float* o5p = outf + 2ull * 8388608;

    dim3 blk(256);

    hipLaunchKernelGGL(k_convert_w, dim3(2816), blk, 0, stream,
                       WQ, WV, WQ3, WK3, WV3, WQ4, WV4, W5, wb);

    hipLaunchKernelGGL(k_linear, dim3(2, 256, 9), blk, 0, stream,
                       q1, q2, q3, adj, wb,
                       bQ, bV, bQ3, bK3, bV3, bQ4, bV4, lin);

    hipLaunchKernelGGL(k_denom, dim3(4, 32, 4), blk, 0, stream,
                       Q1, Q2, Q3, Q4, K3, partial);
    hipLaunchKernelGGL(k_reduce, dim3(256, 4), blk, 0, stream, partial, dinv);

    hipLaunchKernelGGL(k_attn, dim3(4096), blk, 0, stream,
                       Q1, Q2, Q3, Q4, K3, V1, V2, V3, V4, dinv,
                       outf, ob4);

    hipLaunchKernelGGL(k_final, dim3(2, 256), blk, 0, stream,
                       outf, outf + 8388608ull, outf + 3ull * 8388608, ob4,
                       W5b, b5, o5p);
}

// Round 4
// 517.105 us; speedup vs baseline: 1.5545x; 1.0281x over previous
//
#include <hip/hip_runtime.h>

// ---------------------------------------------------------------------------
// multihead_attention_87454124081549 — round 4
// Round-4: k_linear rewritten — streamed A+B K-steps (BK=64), LDS 37 KB ->
// 4 blocks/CU, v_cvt_pk_bf16_f32 for the fp32->bf16 A conversion, stride-72
// LDS rows (uniform bank groups). Everything else unchanged from round 3.
// ---------------------------------------------------------------------------

typedef __attribute__((ext_vector_type(4))) float f32x4;
typedef __attribute__((ext_vector_type(8))) short bf16x8;

#define LOG2E 1.4426950408889634f
#define SM_SCALE (1.4426950408889634f / 5.656854249492381f)  // log2(e)/sqrt(32)

#define CVT_PK(d, lo, hi) \
    asm("v_cvt_pk_bf16_f32 %0, %1, %2" : "=v"(d) : "v"(lo), "v"(hi))
#define SWAP32(x, y) \
    asm("v_permlane32_swap_b32 %0, %1" : "+v"(x), "+v"(y))
#define SWAP16(x, y) \
    asm("v_permlane16_swap_b32 %0, %1" : "+v"(x), "+v"(y))

__device__ __forceinline__ unsigned short f2bf(float x) {
    union { float f; unsigned u; } v; v.f = x;
    unsigned r = v.u + 0x7FFFu + ((v.u >> 16) & 1u);   // RNE
    return (unsigned short)(r >> 16);
}

__device__ __forceinline__ float fast_tanh(float x) {
    float e = __builtin_amdgcn_exp2f(x * (2.0f * LOG2E));   // exp(2x)
    return 1.0f - 2.0f * __builtin_amdgcn_rcpf(e + 1.0f);
}

__device__ __forceinline__ f32x4 mfma_bf16(bf16x8 a, bf16x8 b, f32x4 c) {
    return __builtin_amdgcn_mfma_f32_16x16x32_bf16(a, b, c, 0, 0, 0);
}

// ---------------------------------------------------------------------------
// Weight conversion: 7 x (256x256) + W5 (256x1024) fp32 -> bf16, concatenated.
// Order: WQ(0) WV(1) WQ3(2) WK3(3) WV3(4) WQ4(5) WV4(6) W5(@458752)
// ---------------------------------------------------------------------------
__global__ __launch_bounds__(256) void k_convert_w(
    const float* w0, const float* w1, const float* w2, const float* w3,
    const float* w4, const float* w5, const float* w6, const float* w7,
    unsigned short* out)
{
    int i = blockIdx.x * 256 + threadIdx.x;
    if (i >= 720896) return;
    float v;
    if (i < 458752) {
        int r = i >> 16, j = i & 65535;
        const float* s =
            (r == 0) ? w0 : (r == 1) ? w1 : (r == 2) ? w2 :
            (r == 3) ? w3 : (r == 4) ? w4 : (r == 5) ? w5 : w6;
        v = s[j];
    } else {
        v = w7[i - 458752];
    }
    out[i] = (short)f2bf(v);
}

// ---------------------------------------------------------------------------
// Linear + tanh, all 9 in one dispatch:  Y(bf16) = tanh(X(f32) @ W^T + bias)
// grid = (2, 256, 9), block = 256.  BM=128, BN=128, BK=64 (4 K-steps).
// A (fp32 X -> bf16 via cvt_pk) and B (bf16 weights) both streamed per step.
// LDS 2 x 128x72 bf16 = 37 KB -> 4 blocks/CU.
// z: 0:Q1 1:Q2 2:Q3 3:Q4(gather) 4:K3 5:V1 6:V2 7:V3 8:V4(gather)
// ---------------------------------------------------------------------------
__global__ __launch_bounds__(256, 4) void k_linear(
    const float* __restrict__ q1, const float* __restrict__ q2,
    const float* __restrict__ q3, const int* __restrict__ adj,
    const unsigned short* __restrict__ wb,
    const float* __restrict__ bQ, const float* __restrict__ bV,
    const float* __restrict__ bQ3, const float* __restrict__ bK3,
    const float* __restrict__ bV3, const float* __restrict__ bQ4,
    const float* __restrict__ bV4,
    unsigned short* __restrict__ lin)
{
    __shared__ __align__(16) short As[128 * 72];   // 128 m-rows x 64 k, pad 72
    __shared__ __align__(16) short Bs[128 * 72];   // 128 n-rows x 64 k, pad 72
    const int z = blockIdx.z;
    const float* X = (z == 0 || z == 5) ? q1 : (z == 1 || z == 6) ? q2 : q3;
    const bool gather = (z == 3 || z == 8);
    const int widx = (z == 0 || z == 1) ? 0 : (z == 2) ? 2 : (z == 3) ? 5 :
                     (z == 4) ? 3 : (z == 5 || z == 6) ? 1 : (z == 7) ? 4 : 6;
    const float* bias = (z == 0 || z == 1) ? bQ : (z == 2) ? bQ3 : (z == 3) ? bQ4 :
                        (z == 4) ? bK3 : (z == 5 || z == 6) ? bV : (z == 7) ? bV3 : bV4;
    const unsigned short* Wb = wb + (size_t)widx * 65536;
    unsigned short* Y = lin + (size_t)z * 8388608;

    const int tid = threadIdx.x;
    const int w = tid >> 6, l = tid & 63;
    const int n0 = blockIdx.x * 128, m0 = blockIdx.y * 128;
    const int lr = l & 15, lk = (l >> 4) * 8, lq = (l >> 4) * 4;
    const int wr = (w >> 1) * 64, wc = (w & 1) * 64;
    const int srow = tid >> 3, schunk = tid & 7;   // staging: 32 rows / 8 chunks

    f32x4 acc[4][4] = {};
    for (int step = 0; step < 4; ++step) {
        const int k0 = step * 64;
        __syncthreads();
        #pragma unroll
        for (int it = 0; it < 4; ++it) {
            const int row = srow + it * 32;
            const int gm = m0 + row;
            const int sm = gather ? (adj[gm >> 8] * 256 + (gm & 255)) : gm;
            const float* src = X + (size_t)sm * 256 + k0 + schunk * 8;
            float4 f0 = *(const float4*)src;
            float4 f1 = *(const float4*)(src + 4);
            unsigned a0, a1, a2, a3;
            CVT_PK(a0, f0.x, f0.y);
            CVT_PK(a1, f0.z, f0.w);
            CVT_PK(a2, f1.x, f1.y);
            CVT_PK(a3, f1.z, f1.w);
            uint4 pk; pk.x = a0; pk.y = a1; pk.z = a2; pk.w = a3;
            *(uint4*)&As[row * 72 + schunk * 8] = pk;
            *(bf16x8*)&Bs[row * 72 + schunk * 8] =
                *(const bf16x8*)(Wb + (size_t)(n0 + row) * 256 + k0 + schunk * 8);
        }
        __syncthreads();
        #pragma unroll
        for (int kk = 0; kk < 2; ++kk) {
            bf16x8 af[4], bfr[4];
            #pragma unroll
            for (int i = 0; i < 4; ++i)
                af[i] = *(const bf16x8*)&As[(wr + i * 16 + lr) * 72 + kk * 32 + lk];
            #pragma unroll
            for (int j = 0; j < 4; ++j)
                bfr[j] = *(const bf16x8*)&Bs[(wc + j * 16 + lr) * 72 + kk * 32 + lk];
            #pragma unroll
            for (int i = 0; i < 4; ++i)
                #pragma unroll
                for (int j = 0; j < 4; ++j)
                    acc[i][j] = mfma_bf16(af[i], bfr[j], acc[i][j]);
        }
    }
    #pragma unroll
    for (int j = 0; j < 4; ++j) {
        int col = n0 + wc + j * 16 + lr;
        float bv = bias[col];
        #pragma unroll
        for (int i = 0; i < 4; ++i) {
            int rowb = m0 + wr + i * 16 + lq;
            #pragma unroll
            for (int r = 0; r < 4; ++r)
                Y[(size_t)(rowb + r) * 256 + col] =
                    (short)f2bf(fast_tanh(acc[i][j][r] + bv));
        }
    }
}

// ---------------------------------------------------------------------------
// Denominator partials: partial[a][g][q][k] = sum_{n in g} exp(QK^T/sqrt32).
// grid = (4 tiles, 32 groups, 4 attn), block = 256.
// ---------------------------------------------------------------------------
__global__ __launch_bounds__(256) void k_denom(
    const unsigned short* __restrict__ Qa, const unsigned short* __restrict__ Qb2,
    const unsigned short* __restrict__ Qc, const unsigned short* __restrict__ Qd,
    const unsigned short* __restrict__ Kb, float* __restrict__ partialBase)
{
    __shared__ __align__(16) short Qs[128 * 40];
    __shared__ __align__(16) short Ks[128 * 40];
    const int tid = threadIdx.x, w = tid >> 6, l = tid & 63;
    const int q0 = (blockIdx.x >> 1) * 128, k0 = (blockIdx.x & 1) * 128;
    const int g = blockIdx.y, a = blockIdx.z;
    const unsigned short* Qb = (a == 0) ? Qa : (a == 1) ? Qb2 : (a == 2) ? Qc : Qd;
    float* partial = partialBase + ((size_t)a * 32 + g) * 65536;
    const int lr = l & 15, lk = (l >> 4) * 8, lq = (l >> 4) * 4;

    f32x4 eacc[2][8] = {};
    for (int n = g * 32; n < g * 32 + 32; ++n) {
        const int c = n >> 7, b = n & 127;
        const size_t base = (size_t)b * 65536 + (size_t)c * 32;
        __syncthreads();
        for (int ci = tid; ci < 512; ci += 256) {
            int r = ci >> 2, ch = ci & 3;
            *(bf16x8*)&Qs[r * 40 + ch * 8] =
                *(const bf16x8*)(Qb + base + (size_t)(q0 + r) * 256 + ch * 8);
            *(bf16x8*)&Ks[r * 40 + ch * 8] =
                *(const bf16x8*)(Kb + base + (size_t)(k0 + r) * 256 + ch * 8);
        }
        __syncthreads();
        bf16x8 aq[2], bk[8];
        #pragma unroll
        for (int i = 0; i < 2; ++i)
            aq[i] = *(const bf16x8*)&Qs[(w * 32 + i * 16 + lr) * 40 + lk];
        #pragma unroll
        for (int j = 0; j < 8; ++j)
            bk[j] = *(const bf16x8*)&Ks[(j * 16 + lr) * 40 + lk];
        #pragma unroll
        for (int i = 0; i < 2; ++i)
            #pragma unroll
            for (int j = 0; j < 8; ++j) {
                f32x4 s = mfma_bf16(aq[i], bk[j], (f32x4){0.f, 0.f, 0.f, 0.f});
                #pragma unroll
                for (int r = 0; r < 4; ++r)
                    eacc[i][j][r] += __builtin_amdgcn_exp2f(s[r] * SM_SCALE);
            }
    }
    #pragma unroll
    for (int i = 0; i < 2; ++i)
        #pragma unroll
        for (int j = 0; j < 8; ++j)
            #pragma unroll
            for (int r = 0; r < 4; ++r) {
                int q = q0 + w * 32 + i * 16 + lq + r;
                int k = k0 + j * 16 + lr;
                partial[(size_t)q * 256 + k] = eacc[i][j][r];
            }
}

// Reduce 32 partials -> Dinv = 1/sum.  grid = (256, 4)
__global__ __launch_bounds__(256) void k_reduce(
    const float* __restrict__ partial, float* __restrict__ dinv)
{
    int a = blockIdx.y;
    int i = blockIdx.x * 256 + threadIdx.x;
    const float* p = partial + (size_t)a * 32 * 65536 + i;
    float s = 0.f;
    #pragma unroll
    for (int g = 0; g < 32; ++g) s += p[(size_t)g * 65536];
    dinv[(size_t)a * 65536 + i] = 1.0f / s;
}

// ---------------------------------------------------------------------------
// Attention: o = (exp(QK^T/sqrt32) * Dinv) @ V.  grid = 4096 (XCD-swizzled
// over (head n, attn a)), block = 256 (4 waves x 64 q-rows).
// P never touches LDS: cvt_pk_bf16 pairs + permlane16/32 4x4 row transpose
// convert the QK C-layout directly into the PV A-fragment layout.
// ---------------------------------------------------------------------------
__global__ __launch_bounds__(256) void k_attn(
    const unsigned short* __restrict__ Q1, const unsigned short* __restrict__ Q2,
    const unsigned short* __restrict__ Q3, const unsigned short* __restrict__ Q4,
    const unsigned short* __restrict__ Kb,
    const unsigned short* __restrict__ V1, const unsigned short* __restrict__ V2,
    const unsigned short* __restrict__ V3, const unsigned short* __restrict__ V4,
    const float* __restrict__ dinvBase,
    float* __restrict__ outBase, unsigned short* __restrict__ ob4)
{
    __shared__ __align__(16) short Vt[32 * 264];      // V^T: [d=32][k=256] pad 264
    const int tid = threadIdx.x, w = tid >> 6, l = tid & 63;
    const int bid = blockIdx.x;
    const int swz = (bid & 7) * 512 + (bid >> 3);
    const int a = swz & 3, n = swz >> 2;
    const int c = n >> 7, b = n & 127;
    const int q16 = l & 15, h = l >> 4;
    const size_t base = (size_t)b * 65536 + (size_t)c * 32;

    const unsigned short* Qb = (a == 0) ? Q1 : (a == 1) ? Q2 : (a == 2) ? Q3 : Q4;
    const unsigned short* Vb = (a == 0) ? V1 : (a == 1) ? V2 : (a == 2) ? V3 : V4;
    const float* dinv = dinvBase + (size_t)a * 65536;
    float* outp = outBase + (size_t)((a == 2) ? 3 : a) * 8388608;

    {
        const unsigned short* vp = Vb + base + (size_t)tid * 256;
        bf16x8 v0 = *(const bf16x8*)(vp);
        bf16x8 v1 = *(const bf16x8*)(vp + 8);
        bf16x8 v2 = *(const bf16x8*)(vp + 16);
        bf16x8 v3 = *(const bf16x8*)(vp + 24);
        #pragma unroll
        for (int e = 0; e < 8; ++e) {
            Vt[(0  + e) * 264 + tid] = v0[e];
            Vt[(8  + e) * 264 + tid] = v1[e];
            Vt[(16 + e) * 264 + tid] = v2[e];
            Vt[(24 + e) * 264 + tid] = v3[e];
        }
    }
    __syncthreads();

    const int q0 = w * 64;
    bf16x8 bq[4];
    #pragma unroll
    for (int i = 0; i < 4; ++i)
        bq[i] = *(const bf16x8*)(Qb + base + (size_t)(q0 + i * 16 + q16) * 256 + h * 8);

    f32x4 oacc[4][2] = {};
    #pragma unroll 2
    for (int kp = 0; kp < 8; ++kp) {
        const int kk0 = kp * 32;
        bf16x8 ak0 = *(const bf16x8*)(Kb + base + (size_t)(kk0 + q16) * 256 + h * 8);
        bf16x8 ak1 = *(const bf16x8*)(Kb + base + (size_t)(kk0 + 16 + q16) * 256 + h * 8);
        bf16x8 vb0 = *(const bf16x8*)&Vt[(0  + q16) * 264 + kk0 + h * 8];
        bf16x8 vb1 = *(const bf16x8*)&Vt[(16 + q16) * 264 + kk0 + h * 8];
        #pragma unroll
        for (int i = 0; i < 4; ++i) {
            f32x4 s0 = mfma_bf16(ak0, bq[i], (f32x4){0.f, 0.f, 0.f, 0.f});
            f32x4 s1 = mfma_bf16(ak1, bq[i], (f32x4){0.f, 0.f, 0.f, 0.f});
            const float* dq = dinv + (size_t)(q0 + i * 16 + q16) * 256 + kk0 + h * 4;
            const float4 d0 = *(const float4*)(dq);
            const float4 d1 = *(const float4*)(dq + 16);
            float p0 = __builtin_amdgcn_exp2f(s0[0] * SM_SCALE) * d0.x;
            float p1 = __builtin_amdgcn_exp2f(s0[1] * SM_SCALE) * d0.y;
            float p2 = __builtin_amdgcn_exp2f(s0[2] * SM_SCALE) * d0.z;
            float p3 = __builtin_amdgcn_exp2f(s0[3] * SM_SCALE) * d0.w;
            float p4 = __builtin_amdgcn_exp2f(s1[0] * SM_SCALE) * d1.x;
            float p5 = __builtin_amdgcn_exp2f(s1[1] * SM_SCALE) * d1.y;
            float p6 = __builtin_amdgcn_exp2f(s1[2] * SM_SCALE) * d1.z;
            float p7 = __builtin_amdgcn_exp2f(s1[3] * SM_SCALE) * d1.w;
            unsigned r0, r1, r2, r3;
            CVT_PK(r0, p0, p1);
            CVT_PK(r1, p2, p3);
            CVT_PK(r2, p4, p5);
            CVT_PK(r3, p6, p7);
            SWAP32(r0, r2); SWAP16(r0, r2);
            SWAP32(r1, r3); SWAP16(r1, r3);
            union { unsigned u[4]; bf16x8 v; } F;
            F.u[0] = r0; F.u[1] = r1; F.u[2] = r2; F.u[3] = r3;
            oacc[i][0] = mfma_bf16(F.v, vb0, oacc[i][0]);
            oacc[i][1] = mfma_bf16(F.v, vb1, oacc[i][1]);
        }
    }
    if (a == 3) {
        #pragma unroll
        for (int i = 0; i < 4; ++i)
            #pragma unroll
            for (int d = 0; d < 2; ++d)
                #pragma unroll
                for (int r = 0; r < 4; ++r) {
                    int q = q0 + i * 16 + h * 4 + r;
                    int dc = d * 16 + q16;
                    ob4[(size_t)b * 65536 + (size_t)q * 256 + c * 32 + dc] =
                        f2bf(oacc[i][d][r]);
                }
    } else {
        #pragma unroll
        for (int i = 0; i < 4; ++i)
            #pragma unroll
            for (int d = 0; d < 2; ++d)
                #pragma unroll
                for (int r = 0; r < 4; ++r) {
                    int q = q0 + i * 16 + h * 4 + r;
                    int dc = d * 16 + q16;
                    outp[(size_t)b * 65536 + (size_t)q * 256 + c * 32 + dc] =
                        oacc[i][d][r];
                }
    }
}

// ---------------------------------------------------------------------------
// Final: o5 = tanh(concat(o1..o4) @ W5^T + b5).  M=32768, N=256, K=1024.
// o1..o3 fp32 (d_out planes), o4 bf16 (ws).  BM=128, BN=128, BK=64.
// ---------------------------------------------------------------------------
__global__ __launch_bounds__(256) void k_final(
    const float* __restrict__ p0, const float* __restrict__ p1,
    const float* __restrict__ p2, const unsigned short* __restrict__ p3,
    const unsigned short* __restrict__ W5b, const float* __restrict__ b5,
    float* __restrict__ out)
{
    __shared__ __align__(16) short As[128 * 72];
    __shared__ __align__(16) short Bs[128 * 72];
    const int tid = threadIdx.x, w = tid >> 6, l = tid & 63;
    const int n0 = blockIdx.x * 128, m0 = blockIdx.y * 128;
    const int lr = l & 15, lk = (l >> 4) * 8, lq = (l >> 4) * 4;
    const int wr = (w >> 1) * 64, wc = (w & 1) * 64;
    f32x4 acc[4][4] = {};
    for (int step = 0; step < 16; ++step) {
        const int k0 = step * 64;
        const int kc = k0 & 255;
        __syncthreads();
        if (step < 12) {
            const float* P = (step < 4) ? p0 : (step < 8) ? p1 : p2;
            for (int ci = tid; ci < 1024; ci += 256) {
                int r = ci >> 3, ch = ci & 7;
                const float* src = P + (size_t)(m0 + r) * 256 + kc + ch * 8;
                float4 f0 = *(const float4*)src;
                float4 f1 = *(const float4*)(src + 4);
                unsigned a0, a1, a2, a3;
                CVT_PK(a0, f0.x, f0.y);
                CVT_PK(a1, f0.z, f0.w);
                CVT_PK(a2, f1.x, f1.y);
                CVT_PK(a3, f1.z, f1.w);
                uint4 pk; pk.x = a0; pk.y = a1; pk.z = a2; pk.w = a3;
                *(uint4*)&As[r * 72 + ch * 8] = pk;
                *(bf16x8*)&Bs[r * 72 + ch * 8] =
                    *(const bf16x8*)(W5b + (size_t)(n0 + r) * 1024 + k0 + ch * 8);
            }
        } else {
            for (int ci = tid; ci < 1024; ci += 256) {
                int r = ci >> 3, ch = ci & 7;
                *(bf16x8*)&As[r * 72 + ch * 8] =
                    *(const bf16x8*)(p3 + (size_t)(m0 + r) * 256 + kc + ch * 8);
                *(bf16x8*)&Bs[r * 72 + ch * 8] =
                    *(const bf16x8*)(W5b + (size_t)(n0 + r) * 1024 + k0 + ch * 8);
            }
        }
        __syncthreads();
        #pragma unroll
        for (int kk = 0; kk < 2; ++kk) {
            bf16x8 af[4], bfr[4];
            #pragma unroll
            for (int i = 0; i < 4; ++i)
                af[i] = *(const bf16x8*)&As[(wr + i * 16 + lr) * 72 + kk * 32 + lk];
            #pragma unroll
            for (int j = 0; j < 4; ++j)
                bfr[j] = *(const bf16x8*)&Bs[(wc + j * 16 + lr) * 72 + kk * 32 + lk];
            #pragma unroll
            for (int i = 0; i < 4; ++i)
                #pragma unroll
                for (int j = 0; j < 4; ++j)
                    acc[i][j] = mfma_bf16(af[i], bfr[j], acc[i][j]);
        }
    }
    #pragma unroll
    for (int j = 0; j < 4; ++j) {
        int col = n0 + wc + j * 16 + lr;
        float bv = b5[col];
        #pragma unroll
        for (int i = 0; i < 4; ++i) {
            int rowb = m0 + wr + i * 16 + lq;
            #pragma unroll
            for (int r = 0; r < 4; ++r)
                out[(size_t)(rowb + r) * 256 + col] =
                    fast_tanh(acc[i][j][r] + bv);
        }
    }
}

// ---------------------------------------------------------------------------
extern "C" void kernel_launch(void* const* d_in, const int* in_sizes, int n_in,
                              void* d_out, int out_size, void* d_ws, size_t ws_size,
                              hipStream_t stream)
{
    const float* q1  = (const float*)d_in[0];
    const float* q2  = (const float*)d_in[1];
    const float* q3  = (const float*)d_in[2];
    const int*   adj = (const int*)d_in[3];
    const float* WQ  = (const float*)d_in[4];  const float* bQ  = (const float*)d_in[5];
    const float* WV  = (const float*)d_in[6];  const float* bV  = (const float*)d_in[7];
    const float* WQ3 = (const float*)d_in[8];  const float* bQ3 = (const float*)d_in[9];
    const float* WK3 = (const float*)d_in[10]; const float* bK3 = (const float*)d_in[11];
    const float* WV3 = (const float*)d_in[12]; const float* bV3 = (const float*)d_in[13];
    const float* WQ4 = (const float*)d_in[14]; const float* bQ4 = (const float*)d_in[15];
    const float* WV4 = (const float*)d_in[16]; const float* bV4 = (const float*)d_in[17];
    const float* W5  = (const float*)d_in[18]; const float* b5  = (const float*)d_in[19];

    char* ws = (char*)d_ws;
    unsigned short* wb  = (unsigned short*)ws;               // 720896 bf16 weights
    unsigned short* W5b = wb + 458752;
    unsigned short* lin = (unsigned short*)(ws + 1441792);   // 9 x 32768x256 bf16
    unsigned short* Q1 = lin + 0ull * 8388608;
    unsigned short* Q2 = lin + 1ull * 8388608;
    unsigned short* Q3 = lin + 2ull * 8388608;
    unsigned short* Q4 = lin + 3ull * 8388608;
    unsigned short* K3 = lin + 4ull * 8388608;
    unsigned short* V1 = lin + 5ull * 8388608;
    unsigned short* V2 = lin + 6ull * 8388608;
    unsigned short* V3 = lin + 7ull * 8388608;
    unsigned short* V4 = lin + 8ull * 8388608;
    float* partial = (float*)(ws + 152436736);               // 4*32*65536 f32
    float* dinv    = (float*)(ws + 185991168);               // 4*65536 f32
    unsigned short* ob4 = (unsigned short*)(ws + 152436736); // o4 bf16, overlaps dead partial

    float* outf = (float*)d_out;   // planes: o1(0) o2(1) o5(2) o3(3)
    float* o5p = outf + 2ull * 8388608;

    dim3 blk(256);

    hipLaunchKernelGGL(k_convert_w, dim3(2816), blk, 0, stream,
                       WQ, WV, WQ3, WK3, WV3, WQ4, WV4, W5, wb);

    hipLaunchKernelGGL(k_linear, dim3(2, 256, 9), blk, 0, stream,
                       q1, q2, q3, adj, wb,
                       bQ, bV, bQ3, bK3, bV3, bQ4, bV4, lin);

    hipLaunchKernelGGL(k_denom, dim3(4, 32, 4), blk, 0, stream,
                       Q1, Q2, Q3, Q4, K3, partial);
    hipLaunchKernelGGL(k_reduce, dim3(256, 4), blk, 0, stream, partial, dinv);

    hipLaunchKernelGGL(k_attn, dim3(4096), blk, 0, stream,
                       Q1, Q2, Q3, Q4, K3, V1, V2, V3, V4, dinv,
                       outf, ob4);

    hipLaunchKernelGGL(k_final, dim3(2, 256), blk, 0, stream,
                       outf, outf + 8388608ull, outf + 3ull * 8388608, ob4,
                       W5b, b5, o5p);
}

// Round 5
// 456.020 us; speedup vs baseline: 1.7627x; 1.1340x over previous
//
#include <hip/hip_runtime.h>

// ---------------------------------------------------------------------------
// multihead_attention_87454124081549 — round 5
// Round-5: k_linear regrouped by input (5 variants, up to 2 weight matrices
// per block sharing one staged A-tile) + coalesced bf16x8 stores via an LDS
// bounce (kills the 2.6x partial-sector write amplification seen in round 4).
// Everything else unchanged from round 4.
// ---------------------------------------------------------------------------

typedef __attribute__((ext_vector_type(4))) float f32x4;
typedef __attribute__((ext_vector_type(8))) short bf16x8;

#define LOG2E 1.4426950408889634f
#define SM_SCALE (1.4426950408889634f / 5.656854249492381f)  // log2(e)/sqrt(32)

#define CVT_PK(d, lo, hi) \
    asm("v_cvt_pk_bf16_f32 %0, %1, %2" : "=v"(d) : "v"(lo), "v"(hi))
#define SWAP32(x, y) \
    asm("v_permlane32_swap_b32 %0, %1" : "+v"(x), "+v"(y))
#define SWAP16(x, y) \
    asm("v_permlane16_swap_b32 %0, %1" : "+v"(x), "+v"(y))

__device__ __forceinline__ unsigned short f2bf(float x) {
    union { float f; unsigned u; } v; v.f = x;
    unsigned r = v.u + 0x7FFFu + ((v.u >> 16) & 1u);   // RNE
    return (unsigned short)(r >> 16);
}

__device__ __forceinline__ float fast_tanh(float x) {
    float e = __builtin_amdgcn_exp2f(x * (2.0f * LOG2E));   // exp(2x)
    return 1.0f - 2.0f * __builtin_amdgcn_rcpf(e + 1.0f);
}

__device__ __forceinline__ f32x4 mfma_bf16(bf16x8 a, bf16x8 b, f32x4 c) {
    return __builtin_amdgcn_mfma_f32_16x16x32_bf16(a, b, c, 0, 0, 0);
}

// ---------------------------------------------------------------------------
// Weight conversion: 7 x (256x256) + W5 (256x1024) fp32 -> bf16, concatenated.
// Order: WQ(0) WV(1) WQ3(2) WK3(3) WV3(4) WQ4(5) WV4(6) W5(@458752)
// ---------------------------------------------------------------------------
__global__ __launch_bounds__(256) void k_convert_w(
    const float* w0, const float* w1, const float* w2, const float* w3,
    const float* w4, const float* w5, const float* w6, const float* w7,
    unsigned short* out)
{
    int i = blockIdx.x * 256 + threadIdx.x;
    if (i >= 720896) return;
    float v;
    if (i < 458752) {
        int r = i >> 16, j = i & 65535;
        const float* s =
            (r == 0) ? w0 : (r == 1) ? w1 : (r == 2) ? w2 :
            (r == 3) ? w3 : (r == 4) ? w4 : (r == 5) ? w5 : w6;
        v = s[j];
    } else {
        v = w7[i - 458752];
    }
    out[i] = (short)f2bf(v);
}

// ---------------------------------------------------------------------------
// Linear + tanh, grouped by input:  Y(bf16) = tanh(X(f32) @ W^T + bias)
// grid = (2, 256, 5), block = 256.  BM=128, BN=128, BK=64 (4 K-steps).
// Variant -> (X, gather, outputs):
//  v0: q1       -> z0 (WQ,bQ),  z5 (WV,bV)
//  v1: q2       -> z1 (WQ,bQ),  z6 (WV,bV)
//  v2: q3       -> z2 (WQ3,bQ3), z4 (WK3,bK3)
//  v3: q3       -> z7 (WV3,bV3)
//  v4: q3[adj]  -> z3 (WQ4,bQ4), z8 (WV4,bV4)
// A staged once per K-step, shared by both weight streams; epilogue bounces
// the bf16 tile through LDS for fully-coalesced 256B row stores.
// ---------------------------------------------------------------------------
__global__ __launch_bounds__(256, 2) void k_linear(
    const float* __restrict__ q1, const float* __restrict__ q2,
    const float* __restrict__ q3, const int* __restrict__ adj,
    const unsigned short* __restrict__ wb,
    const float* __restrict__ bQ, const float* __restrict__ bV,
    const float* __restrict__ bQ3, const float* __restrict__ bK3,
    const float* __restrict__ bV3, const float* __restrict__ bQ4,
    const float* __restrict__ bV4,
    unsigned short* __restrict__ lin)
{
    __shared__ __align__(16) short lds[27648];   // As(9216) + Bs0(9216) + Bs1(9216)
    const int var = blockIdx.z;
    const float* X = (var == 0) ? q1 : (var == 1) ? q2 : q3;
    const bool gather = (var == 4);
    const int nout = (var == 3) ? 1 : 2;

    int widx[2] = {0, 0}, zidx[2] = {0, 0};
    const float* bptr[2] = {bQ, bQ};
    if (var == 0)      { widx[0]=0; widx[1]=1; zidx[0]=0; zidx[1]=5; bptr[0]=bQ;  bptr[1]=bV;  }
    else if (var == 1) { widx[0]=0; widx[1]=1; zidx[0]=1; zidx[1]=6; bptr[0]=bQ;  bptr[1]=bV;  }
    else if (var == 2) { widx[0]=2; widx[1]=3; zidx[0]=2; zidx[1]=4; bptr[0]=bQ3; bptr[1]=bK3; }
    else if (var == 3) { widx[0]=4;            zidx[0]=7;            bptr[0]=bV3;              }
    else               { widx[0]=5; widx[1]=6; zidx[0]=3; zidx[1]=8; bptr[0]=bQ4; bptr[1]=bV4; }

    const int tid = threadIdx.x;
    const int w = tid >> 6, l = tid & 63;
    const int n0 = blockIdx.x * 128, m0 = blockIdx.y * 128;
    const int lr = l & 15, lk = (l >> 4) * 8, lq = (l >> 4) * 4;
    const int wr = (w >> 1) * 64, wc = (w & 1) * 64;
    const int srow = tid >> 3, schunk = tid & 7;   // staging: 32 rows x 8 chunks

    f32x4 acc[2][4][4] = {};
    for (int step = 0; step < 4; ++step) {
        const int k0 = step * 64;
        __syncthreads();
        #pragma unroll
        for (int it = 0; it < 4; ++it) {
            const int row = srow + it * 32;
            const int gm = m0 + row;
            const int sm = gather ? (adj[gm >> 8] * 256 + (gm & 255)) : gm;
            const float* src = X + (size_t)sm * 256 + k0 + schunk * 8;
            float4 f0 = *(const float4*)src;
            float4 f1 = *(const float4*)(src + 4);
            unsigned a0, a1, a2, a3;
            CVT_PK(a0, f0.x, f0.y);
            CVT_PK(a1, f0.z, f0.w);
            CVT_PK(a2, f1.x, f1.y);
            CVT_PK(a3, f1.z, f1.w);
            uint4 pk; pk.x = a0; pk.y = a1; pk.z = a2; pk.w = a3;
            *(uint4*)&lds[row * 72 + schunk * 8] = pk;
            #pragma unroll
            for (int t = 0; t < 2; ++t)
                if (t < nout)
                    *(bf16x8*)&lds[9216 * (1 + t) + row * 72 + schunk * 8] =
                        *(const bf16x8*)(wb + (size_t)widx[t] * 65536 +
                                         (size_t)(n0 + row) * 256 + k0 + schunk * 8);
        }
        __syncthreads();
        #pragma unroll
        for (int kk = 0; kk < 2; ++kk) {
            bf16x8 af[4];
            #pragma unroll
            for (int i = 0; i < 4; ++i)
                af[i] = *(const bf16x8*)&lds[(wr + i * 16 + lr) * 72 + kk * 32 + lk];
            #pragma unroll
            for (int t = 0; t < 2; ++t)
                if (t < nout) {
                    bf16x8 bfr[4];
                    #pragma unroll
                    for (int j = 0; j < 4; ++j)
                        bfr[j] = *(const bf16x8*)&lds[9216 * (1 + t) +
                                                      (wc + j * 16 + lr) * 72 + kk * 32 + lk];
                    #pragma unroll
                    for (int i = 0; i < 4; ++i)
                        #pragma unroll
                        for (int j = 0; j < 4; ++j)
                            acc[t][i][j] = mfma_bf16(af[i], bfr[j], acc[t][i][j]);
                }
        }
    }

    // Epilogue: tanh -> bf16 -> LDS bounce -> coalesced 16B row stores.
    #pragma unroll
    for (int t = 0; t < 2; ++t)
        if (t < nout) {
            float bv[4];
            #pragma unroll
            for (int j = 0; j < 4; ++j)
                bv[j] = bptr[t][n0 + wc + j * 16 + lr];
            __syncthreads();
            #pragma unroll
            for (int i = 0; i < 4; ++i)
                #pragma unroll
                for (int j = 0; j < 4; ++j)
                    #pragma unroll
                    for (int r = 0; r < 4; ++r)
                        lds[(wr + i * 16 + lq + r) * 136 + wc + j * 16 + lr] =
                            (short)f2bf(fast_tanh(acc[t][i][j][r] + bv[j]));
            __syncthreads();
            unsigned short* Y = lin + (size_t)zidx[t] * 8388608;
            const int row0 = tid >> 4, chunk = tid & 15;
            #pragma unroll
            for (int it2 = 0; it2 < 8; ++it2) {
                int row = row0 + it2 * 16;
                *(bf16x8*)(Y + (size_t)(m0 + row) * 256 + n0 + chunk * 8) =
                    *(const bf16x8*)&lds[row * 136 + chunk * 8];
            }
        }
}

// ---------------------------------------------------------------------------
// Denominator partials: partial[a][g][q][k] = sum_{n in g} exp(QK^T/sqrt32).
// grid = (4 tiles, 32 groups, 4 attn), block = 256.
// ---------------------------------------------------------------------------
__global__ __launch_bounds__(256) void k_denom(
    const unsigned short* __restrict__ Qa, const unsigned short* __restrict__ Qb2,
    const unsigned short* __restrict__ Qc, const unsigned short* __restrict__ Qd,
    const unsigned short* __restrict__ Kb, float* __restrict__ partialBase)
{
    __shared__ __align__(16) short Qs[128 * 40];
    __shared__ __align__(16) short Ks[128 * 40];
    const int tid = threadIdx.x, w = tid >> 6, l = tid & 63;
    const int q0 = (blockIdx.x >> 1) * 128, k0 = (blockIdx.x & 1) * 128;
    const int g = blockIdx.y, a = blockIdx.z;
    const unsigned short* Qb = (a == 0) ? Qa : (a == 1) ? Qb2 : (a == 2) ? Qc : Qd;
    float* partial = partialBase + ((size_t)a * 32 + g) * 65536;
    const int lr = l & 15, lk = (l >> 4) * 8, lq = (l >> 4) * 4;

    f32x4 eacc[2][8] = {};
    for (int n = g * 32; n < g * 32 + 32; ++n) {
        const int c = n >> 7, b = n & 127;
        const size_t base = (size_t)b * 65536 + (size_t)c * 32;
        __syncthreads();
        for (int ci = tid; ci < 512; ci += 256) {
            int r = ci >> 2, ch = ci & 3;
            *(bf16x8*)&Qs[r * 40 + ch * 8] =
                *(const bf16x8*)(Qb + base + (size_t)(q0 + r) * 256 + ch * 8);
            *(bf16x8*)&Ks[r * 40 + ch * 8] =
                *(const bf16x8*)(Kb + base + (size_t)(k0 + r) * 256 + ch * 8);
        }
        __syncthreads();
        bf16x8 aq[2], bk[8];
        #pragma unroll
        for (int i = 0; i < 2; ++i)
            aq[i] = *(const bf16x8*)&Qs[(w * 32 + i * 16 + lr) * 40 + lk];
        #pragma unroll
        for (int j = 0; j < 8; ++j)
            bk[j] = *(const bf16x8*)&Ks[(j * 16 + lr) * 40 + lk];
        #pragma unroll
        for (int i = 0; i < 2; ++i)
            #pragma unroll
            for (int j = 0; j < 8; ++j) {
                f32x4 s = mfma_bf16(aq[i], bk[j], (f32x4){0.f, 0.f, 0.f, 0.f});
                #pragma unroll
                for (int r = 0; r < 4; ++r)
                    eacc[i][j][r] += __builtin_amdgcn_exp2f(s[r] * SM_SCALE);
            }
    }
    #pragma unroll
    for (int i = 0; i < 2; ++i)
        #pragma unroll
        for (int j = 0; j < 8; ++j)
            #pragma unroll
            for (int r = 0; r < 4; ++r) {
                int q = q0 + w * 32 + i * 16 + lq + r;
                int k = k0 + j * 16 + lr;
                partial[(size_t)q * 256 + k] = eacc[i][j][r];
            }
}

// Reduce 32 partials -> Dinv = 1/sum.  grid = (256, 4)
__global__ __launch_bounds__(256) void k_reduce(
    const float* __restrict__ partial, float* __restrict__ dinv)
{
    int a = blockIdx.y;
    int i = blockIdx.x * 256 + threadIdx.x;
    const float* p = partial + (size_t)a * 32 * 65536 + i;
    float s = 0.f;
    #pragma unroll
    for (int g = 0; g < 32; ++g) s += p[(size_t)g * 65536];
    dinv[(size_t)a * 65536 + i] = 1.0f / s;
}

// ---------------------------------------------------------------------------
// Attention: o = (exp(QK^T/sqrt32) * Dinv) @ V.  grid = 4096 (XCD-swizzled
// over (head n, attn a)), block = 256 (4 waves x 64 q-rows).
// P never touches LDS: cvt_pk_bf16 pairs + permlane16/32 4x4 row transpose
// convert the QK C-layout directly into the PV A-fragment layout.
// ---------------------------------------------------------------------------
__global__ __launch_bounds__(256) void k_attn(
    const unsigned short* __restrict__ Q1, const unsigned short* __restrict__ Q2,
    const unsigned short* __restrict__ Q3, const unsigned short* __restrict__ Q4,
    const unsigned short* __restrict__ Kb,
    const unsigned short* __restrict__ V1, const unsigned short* __restrict__ V2,
    const unsigned short* __restrict__ V3, const unsigned short* __restrict__ V4,
    const float* __restrict__ dinvBase,
    float* __restrict__ outBase, unsigned short* __restrict__ ob4)
{
    __shared__ __align__(16) short Vt[32 * 264];      // V^T: [d=32][k=256] pad 264
    const int tid = threadIdx.x, w = tid >> 6, l = tid & 63;
    const int bid = blockIdx.x;
    const int swz = (bid & 7) * 512 + (bid >> 3);
    const int a = swz & 3, n = swz >> 2;
    const int c = n >> 7, b = n & 127;
    const int q16 = l & 15, h = l >> 4;
    const size_t base = (size_t)b * 65536 + (size_t)c * 32;

    const unsigned short* Qb = (a == 0) ? Q1 : (a == 1) ? Q2 : (a == 2) ? Q3 : Q4;
    const unsigned short* Vb = (a == 0) ? V1 : (a == 1) ? V2 : (a == 2) ? V3 : V4;
    const float* dinv = dinvBase + (size_t)a * 65536;
    float* outp = outBase + (size_t)((a == 2) ? 3 : a) * 8388608;

    {
        const unsigned short* vp = Vb + base + (size_t)tid * 256;
        bf16x8 v0 = *(const bf16x8*)(vp);
        bf16x8 v1 = *(const bf16x8*)(vp + 8);
        bf16x8 v2 = *(const bf16x8*)(vp + 16);
        bf16x8 v3 = *(const bf16x8*)(vp + 24);
        #pragma unroll
        for (int e = 0; e < 8; ++e) {
            Vt[(0  + e) * 264 + tid] = v0[e];
            Vt[(8  + e) * 264 + tid] = v1[e];
            Vt[(16 + e) * 264 + tid] = v2[e];
            Vt[(24 + e) * 264 + tid] = v3[e];
        }
    }
    __syncthreads();

    const int q0 = w * 64;
    bf16x8 bq[4];
    #pragma unroll
    for (int i = 0; i < 4; ++i)
        bq[i] = *(const bf16x8*)(Qb + base + (size_t)(q0 + i * 16 + q16) * 256 + h * 8);

    f32x4 oacc[4][2] = {};
    #pragma unroll 2
    for (int kp = 0; kp < 8; ++kp) {
        const int kk0 = kp * 32;
        bf16x8 ak0 = *(const bf16x8*)(Kb + base + (size_t)(kk0 + q16) * 256 + h * 8);
        bf16x8 ak1 = *(const bf16x8*)(Kb + base + (size_t)(kk0 + 16 + q16) * 256 + h * 8);
        bf16x8 vb0 = *(const bf16x8*)&Vt[(0  + q16) * 264 + kk0 + h * 8];
        bf16x8 vb1 = *(const bf16x8*)&Vt[(16 + q16) * 264 + kk0 + h * 8];
        #pragma unroll
        for (int i = 0; i < 4; ++i) {
            f32x4 s0 = mfma_bf16(ak0, bq[i], (f32x4){0.f, 0.f, 0.f, 0.f});
            f32x4 s1 = mfma_bf16(ak1, bq[i], (f32x4){0.f, 0.f, 0.f, 0.f});
            const float* dq = dinv + (size_t)(q0 + i * 16 + q16) * 256 + kk0 + h * 4;
            const float4 d0 = *(const float4*)(dq);
            const float4 d1 = *(const float4*)(dq + 16);
            float p0 = __builtin_amdgcn_exp2f(s0[0] * SM_SCALE) * d0.x;
            float p1 = __builtin_amdgcn_exp2f(s0[1] * SM_SCALE) * d0.y;
            float p2 = __builtin_amdgcn_exp2f(s0[2] * SM_SCALE) * d0.z;
            float p3 = __builtin_amdgcn_exp2f(s0[3] * SM_SCALE) * d0.w;
            float p4 = __builtin_amdgcn_exp2f(s1[0] * SM_SCALE) * d1.x;
            float p5 = __builtin_amdgcn_exp2f(s1[1] * SM_SCALE) * d1.y;
            float p6 = __builtin_amdgcn_exp2f(s1[2] * SM_SCALE) * d1.z;
            float p7 = __builtin_amdgcn_exp2f(s1[3] * SM_SCALE) * d1.w;
            unsigned r0, r1, r2, r3;
            CVT_PK(r0, p0, p1);
            CVT_PK(r1, p2, p3);
            CVT_PK(r2, p4, p5);
            CVT_PK(r3, p6, p7);
            SWAP32(r0, r2); SWAP16(r0, r2);
            SWAP32(r1, r3); SWAP16(r1, r3);
            union { unsigned u[4]; bf16x8 v; } F;
            F.u[0] = r0; F.u[1] = r1; F.u[2] = r2; F.u[3] = r3;
            oacc[i][0] = mfma_bf16(F.v, vb0, oacc[i][0]);
            oacc[i][1] = mfma_bf16(F.v, vb1, oacc[i][1]);
        }
    }
    if (a == 3) {
        #pragma unroll
        for (int i = 0; i < 4; ++i)
            #pragma unroll
            for (int d = 0; d < 2; ++d)
                #pragma unroll
                for (int r = 0; r < 4; ++r) {
                    int q = q0 + i * 16 + h * 4 + r;
                    int dc = d * 16 + q16;
                    ob4[(size_t)b * 65536 + (size_t)q * 256 + c * 32 + dc] =
                        f2bf(oacc[i][d][r]);
                }
    } else {
        #pragma unroll
        for (int i = 0; i < 4; ++i)
            #pragma unroll
            for (int d = 0; d < 2; ++d)
                #pragma unroll
                for (int r = 0; r < 4; ++r) {
                    int q = q0 + i * 16 + h * 4 + r;
                    int dc = d * 16 + q16;
                    outp[(size_t)b * 65536 + (size_t)q * 256 + c * 32 + dc] =
                        oacc[i][d][r];
                }
    }
}

// ---------------------------------------------------------------------------
// Final: o5 = tanh(concat(o1..o4) @ W5^T + b5).  M=32768, N=256, K=1024.
// o1..o3 fp32 (d_out planes), o4 bf16 (ws).  BM=128, BN=128, BK=64.
// ---------------------------------------------------------------------------
__global__ __launch_bounds__(256) void k_final(
    const float* __restrict__ p0, const float* __restrict__ p1,
    const float* __restrict__ p2, const unsigned short* __restrict__ p3,
    const unsigned short* __restrict__ W5b, const float* __restrict__ b5,
    float* __restrict__ out)
{
    __shared__ __align__(16) short As[128 * 72];
    __shared__ __align__(16) short Bs[128 * 72];
    const int tid = threadIdx.x, w = tid >> 6, l = tid & 63;
    const int n0 = blockIdx.x * 128, m0 = blockIdx.y * 128;
    const int lr = l & 15, lk = (l >> 4) * 8, lq = (l >> 4) * 4;
    const int wr = (w >> 1) * 64, wc = (w & 1) * 64;
    f32x4 acc[4][4] = {};
    for (int step = 0; step < 16; ++step) {
        const int k0 = step * 64;
        const int kc = k0 & 255;
        __syncthreads();
        if (step < 12) {
            const float* P = (step < 4) ? p0 : (step < 8) ? p1 : p2;
            for (int ci = tid; ci < 1024; ci += 256) {
                int r = ci >> 3, ch = ci & 7;
                const float* src = P + (size_t)(m0 + r) * 256 + kc + ch * 8;
                float4 f0 = *(const float4*)src;
                float4 f1 = *(const float4*)(src + 4);
                unsigned a0, a1, a2, a3;
                CVT_PK(a0, f0.x, f0.y);
                CVT_PK(a1, f0.z, f0.w);
                CVT_PK(a2, f1.x, f1.y);
                CVT_PK(a3, f1.z, f1.w);
                uint4 pk; pk.x = a0; pk.y = a1; pk.z = a2; pk.w = a3;
                *(uint4*)&As[r * 72 + ch * 8] = pk;
                *(bf16x8*)&Bs[r * 72 + ch * 8] =
                    *(const bf16x8*)(W5b + (size_t)(n0 + r) * 1024 + k0 + ch * 8);
            }
        } else {
            for (int ci = tid; ci < 1024; ci += 256) {
                int r = ci >> 3, ch = ci & 7;
                *(bf16x8*)&As[r * 72 + ch * 8] =
                    *(const bf16x8*)(p3 + (size_t)(m0 + r) * 256 + kc + ch * 8);
                *(bf16x8*)&Bs[r * 72 + ch * 8] =
                    *(const bf16x8*)(W5b + (size_t)(n0 + r) * 1024 + k0 + ch * 8);
            }
        }
        __syncthreads();
        #pragma unroll
        for (int kk = 0; kk < 2; ++kk) {
            bf16x8 af[4], bfr[4];
            #pragma unroll
            for (int i = 0; i < 4; ++i)
                af[i] = *(const bf16x8*)&As[(wr + i * 16 + lr) * 72 + kk * 32 + lk];
            #pragma unroll
            for (int j = 0; j < 4; ++j)
                bfr[j] = *(const bf16x8*)&Bs[(wc + j * 16 + lr) * 72 + kk * 32 + lk];
            #pragma unroll
            for (int i = 0; i < 4; ++i)
                #pragma unroll
                for (int j = 0; j < 4; ++j)
                    acc[i][j] = mfma_bf16(af[i], bfr[j], acc[i][j]);
        }
    }
    #pragma unroll
    for (int j = 0; j < 4; ++j) {
        int col = n0 + wc + j * 16 + lr;
        float bv = b5[col];
        #pragma unroll
        for (int i = 0; i < 4; ++i) {
            int rowb = m0 + wr + i * 16 + lq;
            #pragma unroll
            for (int r = 0; r < 4; ++r)
                out[(size_t)(rowb + r) * 256 + col] =
                    fast_tanh(acc[i][j][r] + bv);
        }
    }
}

// ---------------------------------------------------------------------------
extern "C" void kernel_launch(void* const* d_in, const int* in_sizes, int n_in,
                              void* d_out, int out_size, void* d_ws, size_t ws_size,
                              hipStream_t stream)
{
    const float* q1  = (const float*)d_in[0];
    const float* q2  = (const float*)d_in[1];
    const float* q3  = (const float*)d_in[2];
    const int*   adj = (const int*)d_in[3];
    const float* WQ  = (const float*)d_in[4];  const float* bQ  = (const float*)d_in[5];
    const float* WV  = (const float*)d_in[6];  const float* bV  = (const float*)d_in[7];
    const float* WQ3 = (const float*)d_in[8];  const float* bQ3 = (const float*)d_in[9];
    const float* WK3 = (const float*)d_in[10]; const float* bK3 = (const float*)d_in[11];
    const float* WV3 = (const float*)d_in[12]; const float* bV3 = (const float*)d_in[13];
    const float* WQ4 = (const float*)d_in[14]; const float* bQ4 = (const float*)d_in[15];
    const float* WV4 = (const float*)d_in[16]; const float* bV4 = (const float*)d_in[17];
    const float* W5  = (const float*)d_in[18]; const float* b5  = (const float*)d_in[19];

    char* ws = (char*)d_ws;
    unsigned short* wb  = (unsigned short*)ws;               // 720896 bf16 weights
    unsigned short* W5b = wb + 458752;
    unsigned short* lin = (unsigned short*)(ws + 1441792);   // 9 x 32768x256 bf16
    unsigned short* Q1 = lin + 0ull * 8388608;
    unsigned short* Q2 = lin + 1ull * 8388608;
    unsigned short* Q3 = lin + 2ull * 8388608;
    unsigned short* Q4 = lin + 3ull * 8388608;
    unsigned short* K3 = lin + 4ull * 8388608;
    unsigned short* V1 = lin + 5ull * 8388608;
    unsigned short* V2 = lin + 6ull * 8388608;
    unsigned short* V3 = lin + 7ull * 8388608;
    unsigned short* V4 = lin + 8ull * 8388608;
    float* partial = (float*)(ws + 152436736);               // 4*32*65536 f32
    float* dinv    = (float*)(ws + 185991168);               // 4*65536 f32
    unsigned short* ob4 = (unsigned short*)(ws + 152436736); // o4 bf16, overlaps dead partial

    float* outf = (float*)d_out;   // planes: o1(0) o2(1) o5(2) o3(3)
    float* o5p = outf + 2ull * 8388608;

    dim3 blk(256);

    hipLaunchKernelGGL(k_convert_w, dim3(2816), blk, 0, stream,
                       WQ, WV, WQ3, WK3, WV3, WQ4, WV4, W5, wb);

    hipLaunchKernelGGL(k_linear, dim3(2, 256, 5), blk, 0, stream,
                       q1, q2, q3, adj, wb,
                       bQ, bV, bQ3, bK3, bV3, bQ4, bV4, lin);

    hipLaunchKernelGGL(k_denom, dim3(4, 32, 4), blk, 0, stream,
                       Q1, Q2, Q3, Q4, K3, partial);
    hipLaunchKernelGGL(k_reduce, dim3(256, 4), blk, 0, stream, partial, dinv);

    hipLaunchKernelGGL(k_attn, dim3(4096), blk, 0, stream,
                       Q1, Q2, Q3, Q4, K3, V1, V2, V3, V4, dinv,
                       outf, ob4);

    hipLaunchKernelGGL(k_final, dim3(2, 256), blk, 0, stream,
                       outf, outf + 8388608ull, outf + 3ull * 8388608, ob4,
                       W5b, b5, o5p);
}

// Round 6
// 388.657 us; speedup vs baseline: 2.0682x; 1.1733x over previous
//
#include <hip/hip_runtime.h>

// ---------------------------------------------------------------------------
// multihead_attention_87454124081549 — round 6
// Round-6: k_reduce writes Dinv in the wave-fragment-permuted layout
// dinvP[a][w][kp][i][j][h][q16][r] so k_attn's per-(kp,i) dinv loads are
// lane-contiguous (1 segment/wave-load instead of 16). k_attn reads dp4[l].
// Everything else unchanged from round 5.
// ---------------------------------------------------------------------------

typedef __attribute__((ext_vector_type(4))) float f32x4;
typedef __attribute__((ext_vector_type(8))) short bf16x8;

#define LOG2E 1.4426950408889634f
#define SM_SCALE (1.4426950408889634f / 5.656854249492381f)  // log2(e)/sqrt(32)

#define CVT_PK(d, lo, hi) \
    asm("v_cvt_pk_bf16_f32 %0, %1, %2" : "=v"(d) : "v"(lo), "v"(hi))
#define SWAP32(x, y) \
    asm("v_permlane32_swap_b32 %0, %1" : "+v"(x), "+v"(y))
#define SWAP16(x, y) \
    asm("v_permlane16_swap_b32 %0, %1" : "+v"(x), "+v"(y))

__device__ __forceinline__ unsigned short f2bf(float x) {
    union { float f; unsigned u; } v; v.f = x;
    unsigned r = v.u + 0x7FFFu + ((v.u >> 16) & 1u);   // RNE
    return (unsigned short)(r >> 16);
}

__device__ __forceinline__ float fast_tanh(float x) {
    float e = __builtin_amdgcn_exp2f(x * (2.0f * LOG2E));   // exp(2x)
    return 1.0f - 2.0f * __builtin_amdgcn_rcpf(e + 1.0f);
}

__device__ __forceinline__ f32x4 mfma_bf16(bf16x8 a, bf16x8 b, f32x4 c) {
    return __builtin_amdgcn_mfma_f32_16x16x32_bf16(a, b, c, 0, 0, 0);
}

// ---------------------------------------------------------------------------
// Weight conversion: 7 x (256x256) + W5 (256x1024) fp32 -> bf16, concatenated.
// Order: WQ(0) WV(1) WQ3(2) WK3(3) WV3(4) WQ4(5) WV4(6) W5(@458752)
// ---------------------------------------------------------------------------
__global__ __launch_bounds__(256) void k_convert_w(
    const float* w0, const float* w1, const float* w2, const float* w3,
    const float* w4, const float* w5, const float* w6, const float* w7,
    unsigned short* out)
{
    int i = blockIdx.x * 256 + threadIdx.x;
    if (i >= 720896) return;
    float v;
    if (i < 458752) {
        int r = i >> 16, j = i & 65535;
        const float* s =
            (r == 0) ? w0 : (r == 1) ? w1 : (r == 2) ? w2 :
            (r == 3) ? w3 : (r == 4) ? w4 : (r == 5) ? w5 : w6;
        v = s[j];
    } else {
        v = w7[i - 458752];
    }
    out[i] = (short)f2bf(v);
}

// ---------------------------------------------------------------------------
// Linear + tanh, grouped by input:  Y(bf16) = tanh(X(f32) @ W^T + bias)
// grid = (2, 256, 5), block = 256.  BM=128, BN=128, BK=64 (4 K-steps).
// ---------------------------------------------------------------------------
__global__ __launch_bounds__(256, 2) void k_linear(
    const float* __restrict__ q1, const float* __restrict__ q2,
    const float* __restrict__ q3, const int* __restrict__ adj,
    const unsigned short* __restrict__ wb,
    const float* __restrict__ bQ, const float* __restrict__ bV,
    const float* __restrict__ bQ3, const float* __restrict__ bK3,
    const float* __restrict__ bV3, const float* __restrict__ bQ4,
    const float* __restrict__ bV4,
    unsigned short* __restrict__ lin)
{
    __shared__ __align__(16) short lds[27648];   // As(9216) + Bs0(9216) + Bs1(9216)
    const int var = blockIdx.z;
    const float* X = (var == 0) ? q1 : (var == 1) ? q2 : q3;
    const bool gather = (var == 4);
    const int nout = (var == 3) ? 1 : 2;

    int widx[2] = {0, 0}, zidx[2] = {0, 0};
    const float* bptr[2] = {bQ, bQ};
    if (var == 0)      { widx[0]=0; widx[1]=1; zidx[0]=0; zidx[1]=5; bptr[0]=bQ;  bptr[1]=bV;  }
    else if (var == 1) { widx[0]=0; widx[1]=1; zidx[0]=1; zidx[1]=6; bptr[0]=bQ;  bptr[1]=bV;  }
    else if (var == 2) { widx[0]=2; widx[1]=3; zidx[0]=2; zidx[1]=4; bptr[0]=bQ3; bptr[1]=bK3; }
    else if (var == 3) { widx[0]=4;            zidx[0]=7;            bptr[0]=bV3;              }
    else               { widx[0]=5; widx[1]=6; zidx[0]=3; zidx[1]=8; bptr[0]=bQ4; bptr[1]=bV4; }

    const int tid = threadIdx.x;
    const int w = tid >> 6, l = tid & 63;
    const int n0 = blockIdx.x * 128, m0 = blockIdx.y * 128;
    const int lr = l & 15, lk = (l >> 4) * 8, lq = (l >> 4) * 4;
    const int wr = (w >> 1) * 64, wc = (w & 1) * 64;
    const int srow = tid >> 3, schunk = tid & 7;   // staging: 32 rows x 8 chunks

    f32x4 acc[2][4][4] = {};
    for (int step = 0; step < 4; ++step) {
        const int k0 = step * 64;
        __syncthreads();
        #pragma unroll
        for (int it = 0; it < 4; ++it) {
            const int row = srow + it * 32;
            const int gm = m0 + row;
            const int sm = gather ? (adj[gm >> 8] * 256 + (gm & 255)) : gm;
            const float* src = X + (size_t)sm * 256 + k0 + schunk * 8;
            float4 f0 = *(const float4*)src;
            float4 f1 = *(const float4*)(src + 4);
            unsigned a0, a1, a2, a3;
            CVT_PK(a0, f0.x, f0.y);
            CVT_PK(a1, f0.z, f0.w);
            CVT_PK(a2, f1.x, f1.y);
            CVT_PK(a3, f1.z, f1.w);
            uint4 pk; pk.x = a0; pk.y = a1; pk.z = a2; pk.w = a3;
            *(uint4*)&lds[row * 72 + schunk * 8] = pk;
            #pragma unroll
            for (int t = 0; t < 2; ++t)
                if (t < nout)
                    *(bf16x8*)&lds[9216 * (1 + t) + row * 72 + schunk * 8] =
                        *(const bf16x8*)(wb + (size_t)widx[t] * 65536 +
                                         (size_t)(n0 + row) * 256 + k0 + schunk * 8);
        }
        __syncthreads();
        #pragma unroll
        for (int kk = 0; kk < 2; ++kk) {
            bf16x8 af[4];
            #pragma unroll
            for (int i = 0; i < 4; ++i)
                af[i] = *(const bf16x8*)&lds[(wr + i * 16 + lr) * 72 + kk * 32 + lk];
            #pragma unroll
            for (int t = 0; t < 2; ++t)
                if (t < nout) {
                    bf16x8 bfr[4];
                    #pragma unroll
                    for (int j = 0; j < 4; ++j)
                        bfr[j] = *(const bf16x8*)&lds[9216 * (1 + t) +
                                                      (wc + j * 16 + lr) * 72 + kk * 32 + lk];
                    #pragma unroll
                    for (int i = 0; i < 4; ++i)
                        #pragma unroll
                        for (int j = 0; j < 4; ++j)
                            acc[t][i][j] = mfma_bf16(af[i], bfr[j], acc[t][i][j]);
                }
        }
    }

    // Epilogue: tanh -> bf16 -> LDS bounce -> coalesced 16B row stores.
    #pragma unroll
    for (int t = 0; t < 2; ++t)
        if (t < nout) {
            float bv[4];
            #pragma unroll
            for (int j = 0; j < 4; ++j)
                bv[j] = bptr[t][n0 + wc + j * 16 + lr];
            __syncthreads();
            #pragma unroll
            for (int i = 0; i < 4; ++i)
                #pragma unroll
                for (int j = 0; j < 4; ++j)
                    #pragma unroll
                    for (int r = 0; r < 4; ++r)
                        lds[(wr + i * 16 + lq + r) * 136 + wc + j * 16 + lr] =
                            (short)f2bf(fast_tanh(acc[t][i][j][r] + bv[j]));
            __syncthreads();
            unsigned short* Y = lin + (size_t)zidx[t] * 8388608;
            const int row0 = tid >> 4, chunk = tid & 15;
            #pragma unroll
            for (int it2 = 0; it2 < 8; ++it2) {
                int row = row0 + it2 * 16;
                *(bf16x8*)(Y + (size_t)(m0 + row) * 256 + n0 + chunk * 8) =
                    *(const bf16x8*)&lds[row * 136 + chunk * 8];
            }
        }
}

// ---------------------------------------------------------------------------
// Denominator partials: partial[a][g][q][k] = sum_{n in g} exp(QK^T/sqrt32).
// grid = (4 tiles, 32 groups, 4 attn), block = 256.
// ---------------------------------------------------------------------------
__global__ __launch_bounds__(256) void k_denom(
    const unsigned short* __restrict__ Qa, const unsigned short* __restrict__ Qb2,
    const unsigned short* __restrict__ Qc, const unsigned short* __restrict__ Qd,
    const unsigned short* __restrict__ Kb, float* __restrict__ partialBase)
{
    __shared__ __align__(16) short Qs[128 * 40];
    __shared__ __align__(16) short Ks[128 * 40];
    const int tid = threadIdx.x, w = tid >> 6, l = tid & 63;
    const int q0 = (blockIdx.x >> 1) * 128, k0 = (blockIdx.x & 1) * 128;
    const int g = blockIdx.y, a = blockIdx.z;
    const unsigned short* Qb = (a == 0) ? Qa : (a == 1) ? Qb2 : (a == 2) ? Qc : Qd;
    float* partial = partialBase + ((size_t)a * 32 + g) * 65536;
    const int lr = l & 15, lk = (l >> 4) * 8, lq = (l >> 4) * 4;

    f32x4 eacc[2][8] = {};
    for (int n = g * 32; n < g * 32 + 32; ++n) {
        const int c = n >> 7, b = n & 127;
        const size_t base = (size_t)b * 65536 + (size_t)c * 32;
        __syncthreads();
        for (int ci = tid; ci < 512; ci += 256) {
            int r = ci >> 2, ch = ci & 3;
            *(bf16x8*)&Qs[r * 40 + ch * 8] =
                *(const bf16x8*)(Qb + base + (size_t)(q0 + r) * 256 + ch * 8);
            *(bf16x8*)&Ks[r * 40 + ch * 8] =
                *(const bf16x8*)(Kb + base + (size_t)(k0 + r) * 256 + ch * 8);
        }
        __syncthreads();
        bf16x8 aq[2], bk[8];
        #pragma unroll
        for (int i = 0; i < 2; ++i)
            aq[i] = *(const bf16x8*)&Qs[(w * 32 + i * 16 + lr) * 40 + lk];
        #pragma unroll
        for (int j = 0; j < 8; ++j)
            bk[j] = *(const bf16x8*)&Ks[(j * 16 + lr) * 40 + lk];
        #pragma unroll
        for (int i = 0; i < 2; ++i)
            #pragma unroll
            for (int j = 0; j < 8; ++j) {
                f32x4 s = mfma_bf16(aq[i], bk[j], (f32x4){0.f, 0.f, 0.f, 0.f});
                #pragma unroll
                for (int r = 0; r < 4; ++r)
                    eacc[i][j][r] += __builtin_amdgcn_exp2f(s[r] * SM_SCALE);
            }
    }
    #pragma unroll
    for (int i = 0; i < 2; ++i)
        #pragma unroll
        for (int j = 0; j < 8; ++j)
            #pragma unroll
            for (int r = 0; r < 4; ++r) {
                int q = q0 + w * 32 + i * 16 + lq + r;
                int k = k0 + j * 16 + lr;
                partial[(size_t)q * 256 + k] = eacc[i][j][r];
            }
}

// ---------------------------------------------------------------------------
// Reduce 32 partials -> Dinv = 1/sum, written in the wave-fragment-permuted
// layout consumed by k_attn:
//   dinvP[a][w][kp][i][j][h][q16][r],  q = w*64+i*16+q16, k = kp*32+j*16+h*4+r
// grid = (256, 4)
// ---------------------------------------------------------------------------
__global__ __launch_bounds__(256) void k_reduce(
    const float* __restrict__ partial, float* __restrict__ dinvP)
{
    int a = blockIdx.y;
    int i = blockIdx.x * 256 + threadIdx.x;
    const float* p = partial + (size_t)a * 32 * 65536 + i;
    float s = 0.f;
    #pragma unroll
    for (int g = 0; g < 32; ++g) s += p[(size_t)g * 65536];
    const int q = i >> 8, k = i & 255;
    const int w_ = q >> 6, iq = (q >> 4) & 3, q16 = q & 15;
    const int kp = k >> 5, j = (k >> 4) & 1, h = (k >> 2) & 3, r = k & 3;
    const int off = (((((((w_ * 8 + kp) * 4 + iq) * 2 + j) * 4 + h) * 16) + q16) * 4) + r;
    dinvP[((size_t)a << 16) + off] = 1.0f / s;
}

// ---------------------------------------------------------------------------
// Attention: o = (exp(QK^T/sqrt32) * Dinv) @ V.  grid = 4096 (XCD-swizzled
// over (head n, attn a)), block = 256 (4 waves x 64 q-rows).
// P never touches LDS (cvt_pk + permlane transpose); dinv loads are
// lane-contiguous from the permuted dinvP (1 segment per wave-load).
// ---------------------------------------------------------------------------
__global__ __launch_bounds__(256) void k_attn(
    const unsigned short* __restrict__ Q1, const unsigned short* __restrict__ Q2,
    const unsigned short* __restrict__ Q3, const unsigned short* __restrict__ Q4,
    const unsigned short* __restrict__ Kb,
    const unsigned short* __restrict__ V1, const unsigned short* __restrict__ V2,
    const unsigned short* __restrict__ V3, const unsigned short* __restrict__ V4,
    const float* __restrict__ dinvP,
    float* __restrict__ outBase, unsigned short* __restrict__ ob4)
{
    __shared__ __align__(16) short Vt[32 * 264];      // V^T: [d=32][k=256] pad 264
    const int tid = threadIdx.x, w = tid >> 6, l = tid & 63;
    const int bid = blockIdx.x;
    const int swz = (bid & 7) * 512 + (bid >> 3);
    const int a = swz & 3, n = swz >> 2;
    const int c = n >> 7, b = n & 127;
    const int q16 = l & 15, h = l >> 4;
    const size_t base = (size_t)b * 65536 + (size_t)c * 32;

    const unsigned short* Qb = (a == 0) ? Q1 : (a == 1) ? Q2 : (a == 2) ? Q3 : Q4;
    const unsigned short* Vb = (a == 0) ? V1 : (a == 1) ? V2 : (a == 2) ? V3 : V4;
    const f32x4* dpa = (const f32x4*)(dinvP + ((size_t)a << 16)) + l;
    float* outp = outBase + (size_t)((a == 2) ? 3 : a) * 8388608;

    {
        const unsigned short* vp = Vb + base + (size_t)tid * 256;
        bf16x8 v0 = *(const bf16x8*)(vp);
        bf16x8 v1 = *(const bf16x8*)(vp + 8);
        bf16x8 v2 = *(const bf16x8*)(vp + 16);
        bf16x8 v3 = *(const bf16x8*)(vp + 24);
        #pragma unroll
        for (int e = 0; e < 8; ++e) {
            Vt[(0  + e) * 264 + tid] = v0[e];
            Vt[(8  + e) * 264 + tid] = v1[e];
            Vt[(16 + e) * 264 + tid] = v2[e];
            Vt[(24 + e) * 264 + tid] = v3[e];
        }
    }
    __syncthreads();

    const int q0 = w * 64;
    bf16x8 bq[4];
    #pragma unroll
    for (int i = 0; i < 4; ++i)
        bq[i] = *(const bf16x8*)(Qb + base + (size_t)(q0 + i * 16 + q16) * 256 + h * 8);

    f32x4 oacc[4][2] = {};
    #pragma unroll 2
    for (int kp = 0; kp < 8; ++kp) {
        const int kk0 = kp * 32;
        bf16x8 ak0 = *(const bf16x8*)(Kb + base + (size_t)(kk0 + q16) * 256 + h * 8);
        bf16x8 ak1 = *(const bf16x8*)(Kb + base + (size_t)(kk0 + 16 + q16) * 256 + h * 8);
        bf16x8 vb0 = *(const bf16x8*)&Vt[(0  + q16) * 264 + kk0 + h * 8];
        bf16x8 vb1 = *(const bf16x8*)&Vt[(16 + q16) * 264 + kk0 + h * 8];
        #pragma unroll
        for (int i = 0; i < 4; ++i) {
            f32x4 s0 = mfma_bf16(ak0, bq[i], (f32x4){0.f, 0.f, 0.f, 0.f});
            f32x4 s1 = mfma_bf16(ak1, bq[i], (f32x4){0.f, 0.f, 0.f, 0.f});
            // dinvP block index X = ((w*8+kp)*4+i)*2 + j; lane-contiguous.
            const int X = ((w * 8 + kp) * 4 + i) * 2;
            f32x4 d0 = dpa[(size_t)X * 64];
            f32x4 d1 = dpa[(size_t)(X + 1) * 64];
            float p0 = __builtin_amdgcn_exp2f(s0[0] * SM_SCALE) * d0[0];
            float p1 = __builtin_amdgcn_exp2f(s0[1] * SM_SCALE) * d0[1];
            float p2 = __builtin_amdgcn_exp2f(s0[2] * SM_SCALE) * d0[2];
            float p3 = __builtin_amdgcn_exp2f(s0[3] * SM_SCALE) * d0[3];
            float p4 = __builtin_amdgcn_exp2f(s1[0] * SM_SCALE) * d1[0];
            float p5 = __builtin_amdgcn_exp2f(s1[1] * SM_SCALE) * d1[1];
            float p6 = __builtin_amdgcn_exp2f(s1[2] * SM_SCALE) * d1[2];
            float p7 = __builtin_amdgcn_exp2f(s1[3] * SM_SCALE) * d1[3];
            unsigned r0, r1, r2, r3;
            CVT_PK(r0, p0, p1);
            CVT_PK(r1, p2, p3);
            CVT_PK(r2, p4, p5);
            CVT_PK(r3, p6, p7);
            SWAP32(r0, r2); SWAP16(r0, r2);
            SWAP32(r1, r3); SWAP16(r1, r3);
            union { unsigned u[4]; bf16x8 v; } F;
            F.u[0] = r0; F.u[1] = r1; F.u[2] = r2; F.u[3] = r3;
            oacc[i][0] = mfma_bf16(F.v, vb0, oacc[i][0]);
            oacc[i][1] = mfma_bf16(F.v, vb1, oacc[i][1]);
        }
    }
    if (a == 3) {
        #pragma unroll
        for (int i = 0; i < 4; ++i)
            #pragma unroll
            for (int d = 0; d < 2; ++d)
                #pragma unroll
                for (int r = 0; r < 4; ++r) {
                    int q = q0 + i * 16 + h * 4 + r;
                    int dc = d * 16 + q16;
                    ob4[(size_t)b * 65536 + (size_t)q * 256 + c * 32 + dc] =
                        f2bf(oacc[i][d][r]);
                }
    } else {
        #pragma unroll
        for (int i = 0; i < 4; ++i)
            #pragma unroll
            for (int d = 0; d < 2; ++d)
                #pragma unroll
                for (int r = 0; r < 4; ++r) {
                    int q = q0 + i * 16 + h * 4 + r;
                    int dc = d * 16 + q16;
                    outp[(size_t)b * 65536 + (size_t)q * 256 + c * 32 + dc] =
                        oacc[i][d][r];
                }
    }
}

// ---------------------------------------------------------------------------
// Final: o5 = tanh(concat(o1..o4) @ W5^T + b5).  M=32768, N=256, K=1024.
// o1..o3 fp32 (d_out planes), o4 bf16 (ws).  BM=128, BN=128, BK=64.
// ---------------------------------------------------------------------------
__global__ __launch_bounds__(256) void k_final(
    const float* __restrict__ p0, const float* __restrict__ p1,
    const float* __restrict__ p2, const unsigned short* __restrict__ p3,
    const unsigned short* __restrict__ W5b, const float* __restrict__ b5,
    float* __restrict__ out)
{
    __shared__ __align__(16) short As[128 * 72];
    __shared__ __align__(16) short Bs[128 * 72];
    const int tid = threadIdx.x, w = tid >> 6, l = tid & 63;
    const int n0 = blockIdx.x * 128, m0 = blockIdx.y * 128;
    const int lr = l & 15, lk = (l >> 4) * 8, lq = (l >> 4) * 4;
    const int wr = (w >> 1) * 64, wc = (w & 1) * 64;
    f32x4 acc[4][4] = {};
    for (int step = 0; step < 16; ++step) {
        const int k0 = step * 64;
        const int kc = k0 & 255;
        __syncthreads();
        if (step < 12) {
            const float* P = (step < 4) ? p0 : (step < 8) ? p1 : p2;
            for (int ci = tid; ci < 1024; ci += 256) {
                int r = ci >> 3, ch = ci & 7;
                const float* src = P + (size_t)(m0 + r) * 256 + kc + ch * 8;
                float4 f0 = *(const float4*)src;
                float4 f1 = *(const float4*)(src + 4);
                unsigned a0, a1, a2, a3;
                CVT_PK(a0, f0.x, f0.y);
                CVT_PK(a1, f0.z, f0.w);
                CVT_PK(a2, f1.x, f1.y);
                CVT_PK(a3, f1.z, f1.w);
                uint4 pk; pk.x = a0; pk.y = a1; pk.z = a2; pk.w = a3;
                *(uint4*)&As[r * 72 + ch * 8] = pk;
                *(bf16x8*)&Bs[r * 72 + ch * 8] =
                    *(const bf16x8*)(W5b + (size_t)(n0 + r) * 1024 + k0 + ch * 8);
            }
        } else {
            for (int ci = tid; ci < 1024; ci += 256) {
                int r = ci >> 3, ch = ci & 7;
                *(bf16x8*)&As[r * 72 + ch * 8] =
                    *(const bf16x8*)(p3 + (size_t)(m0 + r) * 256 + kc + ch * 8);
                *(bf16x8*)&Bs[r * 72 + ch * 8] =
                    *(const bf16x8*)(W5b + (size_t)(n0 + r) * 1024 + k0 + ch * 8);
            }
        }
        __syncthreads();
        #pragma unroll
        for (int kk = 0; kk < 2; ++kk) {
            bf16x8 af[4], bfr[4];
            #pragma unroll
            for (int i = 0; i < 4; ++i)
                af[i] = *(const bf16x8*)&As[(wr + i * 16 + lr) * 72 + kk * 32 + lk];
            #pragma unroll
            for (int j = 0; j < 4; ++j)
                bfr[j] = *(const bf16x8*)&Bs[(wc + j * 16 + lr) * 72 + kk * 32 + lk];
            #pragma unroll
            for (int i = 0; i < 4; ++i)
                #pragma unroll
                for (int j = 0; j < 4; ++j)
                    acc[i][j] = mfma_bf16(af[i], bfr[j], acc[i][j]);
        }
    }
    #pragma unroll
    for (int j = 0; j < 4; ++j) {
        int col = n0 + wc + j * 16 + lr;
        float bv = b5[col];
        #pragma unroll
        for (int i = 0; i < 4; ++i) {
            int rowb = m0 + wr + i * 16 + lq;
            #pragma unroll
            for (int r = 0; r < 4; ++r)
                out[(size_t)(rowb + r) * 256 + col] =
                    fast_tanh(acc[i][j][r] + bv);
        }
    }
}

// ---------------------------------------------------------------------------
extern "C" void kernel_launch(void* const* d_in, const int* in_sizes, int n_in,
                              void* d_out, int out_size, void* d_ws, size_t ws_size,
                              hipStream_t stream)
{
    const float* q1  = (const float*)d_in[0];
    const float* q2  = (const float*)d_in[1];
    const float* q3  = (const float*)d_in[2];
    const int*   adj = (const int*)d_in[3];
    const float* WQ  = (const float*)d_in[4];  const float* bQ  = (const float*)d_in[5];
    const float* WV  = (const float*)d_in[6];  const float* bV  = (const float*)d_in[7];
    const float* WQ3 = (const float*)d_in[8];  const float* bQ3 = (const float*)d_in[9];
    const float* WK3 = (const float*)d_in[10]; const float* bK3 = (const float*)d_in[11];
    const float* WV3 = (const float*)d_in[12]; const float* bV3 = (const float*)d_in[13];
    const float* WQ4 = (const float*)d_in[14]; const float* bQ4 = (const float*)d_in[15];
    const float* WV4 = (const float*)d_in[16]; const float* bV4 = (const float*)d_in[17];
    const float* W5  = (const float*)d_in[18]; const float* b5  = (const float*)d_in[19];

    char* ws = (char*)d_ws;
    unsigned short* wb  = (unsigned short*)ws;               // 720896 bf16 weights
    unsigned short* W5b = wb + 458752;
    unsigned short* lin = (unsigned short*)(ws + 1441792);   // 9 x 32768x256 bf16
    unsigned short* Q1 = lin + 0ull * 8388608;
    unsigned short* Q2 = lin + 1ull * 8388608;
    unsigned short* Q3 = lin + 2ull * 8388608;
    unsigned short* Q4 = lin + 3ull * 8388608;
    unsigned short* K3 = lin + 4ull * 8388608;
    unsigned short* V1 = lin + 5ull * 8388608;
    unsigned short* V2 = lin + 6ull * 8388608;
    unsigned short* V3 = lin + 7ull * 8388608;
    unsigned short* V4 = lin + 8ull * 8388608;
    float* partial = (float*)(ws + 152436736);               // 4*32*65536 f32
    float* dinvP   = (float*)(ws + 185991168);               // 4*65536 f32 (permuted)
    unsigned short* ob4 = (unsigned short*)(ws + 152436736); // o4 bf16, overlaps dead partial

    float* outf = (float*)d_out;   // planes: o1(0) o2(1) o5(2) o3(3)
    float* o5p = outf + 2ull * 8388608;

    dim3 blk(256);

    hipLaunchKernelGGL(k_convert_w, dim3(2816), blk, 0, stream,
                       WQ, WV, WQ3, WK3, WV3, WQ4, WV4, W5, wb);

    hipLaunchKernelGGL(k_linear, dim3(2, 256, 5), blk, 0, stream,
                       q1, q2, q3, adj, wb,
                       bQ, bV, bQ3, bK3, bV3, bQ4, bV4, lin);

    hipLaunchKernelGGL(k_denom, dim3(4, 32, 4), blk, 0, stream,
                       Q1, Q2, Q3, Q4, K3, partial);
    hipLaunchKernelGGL(k_reduce, dim3(256, 4), blk, 0, stream, partial, dinvP);

    hipLaunchKernelGGL(k_attn, dim3(4096), blk, 0, stream,
                       Q1, Q2, Q3, Q4, K3, V1, V2, V3, V4, dinvP,
                       outf, ob4);

    hipLaunchKernelGGL(k_final, dim3(2, 256), blk, 0, stream,
                       outf, outf + 8388608ull, outf + 3ull * 8388608, ob4,
                       W5b, b5, o5p);
}

// Round 7
// 343.214 us; speedup vs baseline: 2.3421x; 1.1324x over previous
//
#include <hip/hip_runtime.h>

// ---------------------------------------------------------------------------
// multihead_attention_87454124081549 — round 7
// Round-7: (1) q1/q2/q3 pre-converted to bf16 once (k_convert_x) into d_out
// scratch (o1/o2 planes are dead until k_attn); (2) k_linear rewritten:
// 512-thread blocks (wave tile 64x32, acc=64 regs -> 4 waves/SIMD),
// BK=32 double-buffered LDS (61 KB), reg-staged pipeline with 2-step
// load lookahead, one barrier per K-step. Everything else = round 6.
// ---------------------------------------------------------------------------

typedef __attribute__((ext_vector_type(4))) float f32x4;
typedef __attribute__((ext_vector_type(8))) short bf16x8;

#define LOG2E 1.4426950408889634f
#define SM_SCALE (1.4426950408889634f / 5.656854249492381f)  // log2(e)/sqrt(32)

#define CVT_PK(d, lo, hi) \
    asm("v_cvt_pk_bf16_f32 %0, %1, %2" : "=v"(d) : "v"(lo), "v"(hi))
#define SWAP32(x, y) \
    asm("v_permlane32_swap_b32 %0, %1" : "+v"(x), "+v"(y))
#define SWAP16(x, y) \
    asm("v_permlane16_swap_b32 %0, %1" : "+v"(x), "+v"(y))

__device__ __forceinline__ unsigned short f2bf(float x) {
    union { float f; unsigned u; } v; v.f = x;
    unsigned r = v.u + 0x7FFFu + ((v.u >> 16) & 1u);   // RNE
    return (unsigned short)(r >> 16);
}

__device__ __forceinline__ float fast_tanh(float x) {
    float e = __builtin_amdgcn_exp2f(x * (2.0f * LOG2E));   // exp(2x)
    return 1.0f - 2.0f * __builtin_amdgcn_rcpf(e + 1.0f);
}

__device__ __forceinline__ f32x4 mfma_bf16(bf16x8 a, bf16x8 b, f32x4 c) {
    return __builtin_amdgcn_mfma_f32_16x16x32_bf16(a, b, c, 0, 0, 0);
}

// ---------------------------------------------------------------------------
// Weight conversion: 7 x (256x256) + W5 (256x1024) fp32 -> bf16, concatenated.
// Order: WQ(0) WV(1) WQ3(2) WK3(3) WV3(4) WQ4(5) WV4(6) W5(@458752)
// ---------------------------------------------------------------------------
__global__ __launch_bounds__(256) void k_convert_w(
    const float* w0, const float* w1, const float* w2, const float* w3,
    const float* w4, const float* w5, const float* w6, const float* w7,
    unsigned short* out)
{
    int i = blockIdx.x * 256 + threadIdx.x;
    if (i >= 720896) return;
    float v;
    if (i < 458752) {
        int r = i >> 16, j = i & 65535;
        const float* s =
            (r == 0) ? w0 : (r == 1) ? w1 : (r == 2) ? w2 :
            (r == 3) ? w3 : (r == 4) ? w4 : (r == 5) ? w5 : w6;
        v = s[j];
    } else {
        v = w7[i - 458752];
    }
    out[i] = (short)f2bf(v);
}

// ---------------------------------------------------------------------------
// X conversion: q1,q2,q3 (each 8388608 fp32) -> bf16, concatenated in Xb.
// grid = 12288 x 256, 8 elems/thread.
// ---------------------------------------------------------------------------
__global__ __launch_bounds__(256) void k_convert_x(
    const float* __restrict__ q1, const float* __restrict__ q2,
    const float* __restrict__ q3, unsigned short* __restrict__ Xb)
{
    const int gi = (blockIdx.x * 256 + threadIdx.x) * 8;
    const float* s = (gi < 8388608) ? q1 : (gi < 16777216) ? q2 : q3;
    const int off = gi & 8388607;
    float4 f0 = *(const float4*)(s + off);
    float4 f1 = *(const float4*)(s + off + 4);
    unsigned a0, a1, a2, a3;
    CVT_PK(a0, f0.x, f0.y);
    CVT_PK(a1, f0.z, f0.w);
    CVT_PK(a2, f1.x, f1.y);
    CVT_PK(a3, f1.z, f1.w);
    uint4 pk; pk.x = a0; pk.y = a1; pk.z = a2; pk.w = a3;
    *(uint4*)(Xb + gi) = pk;
}

// ---------------------------------------------------------------------------
// Linear + tanh, grouped by input:  Y(bf16) = tanh(Xb(bf16) @ W^T + bias)
// grid = 2560 (XCD-swizzled), block = 512 (8 waves: 2m x 4n, tile 64x32/out).
// BM=128, BN=128, BK=32 (8 K-steps), double-buffered LDS (2x15360 shorts),
// reg-staged loads with 2-step lookahead, 1 barrier per step.
// Variant -> (X, gather, outputs):
//  v0: q1      -> z0 (WQ,bQ),  z5 (WV,bV)
//  v1: q2      -> z1 (WQ,bQ),  z6 (WV,bV)
//  v2: q3      -> z2 (WQ3,bQ3), z4 (WK3,bK3)
//  v3: q3      -> z7 (WV3,bV3)
//  v4: q3[adj] -> z3 (WQ4,bQ4), z8 (WV4,bV4)
// ---------------------------------------------------------------------------
__global__ __launch_bounds__(512, 4) void k_linear(
    const unsigned short* __restrict__ Xb, const int* __restrict__ adj,
    const unsigned short* __restrict__ wb,
    const float* __restrict__ bQ, const float* __restrict__ bV,
    const float* __restrict__ bQ3, const float* __restrict__ bK3,
    const float* __restrict__ bV3, const float* __restrict__ bQ4,
    const float* __restrict__ bV4,
    unsigned short* __restrict__ lin)
{
    __shared__ __align__(16) short lds[30720];   // 2 x (A 5120 + B0 5120 + B1 5120)
    const int bid0 = blockIdx.x;                 // 2560 = 8 XCD x 320
    const int swz = (bid0 & 7) * 320 + (bid0 >> 3);
    const int var = swz >> 9;
    const int rem = swz & 511;
    const int m0 = (rem >> 1) * 128, n0 = (rem & 1) * 128;

    const unsigned short* X = Xb + (size_t)((var == 0) ? 0 : (var == 1) ? 1 : 2) * 8388608;
    const bool gather = (var == 4);
    const int nout = (var == 3) ? 1 : 2;

    int widx0, widx1 = 0, zidx0, zidx1 = 0;
    const float* bp0;
    const float* bp1 = bQ;
    if (var == 0)      { widx0=0; widx1=1; zidx0=0; zidx1=5; bp0=bQ;  bp1=bV;  }
    else if (var == 1) { widx0=0; widx1=1; zidx0=1; zidx1=6; bp0=bQ;  bp1=bV;  }
    else if (var == 2) { widx0=2; widx1=3; zidx0=2; zidx1=4; bp0=bQ3; bp1=bK3; }
    else if (var == 3) { widx0=4;          zidx0=7;          bp0=bV3;          }
    else               { widx0=5; widx1=6; zidx0=3; zidx1=8; bp0=bQ4; bp1=bV4; }

    const int tid = threadIdx.x;
    const int w = tid >> 6, l = tid & 63;
    const int wm = w >> 2, wn = w & 3;           // 2 x 4 wave grid
    const int lr = l & 15, lk = (l >> 4) * 8, lq = (l >> 4) * 4;

    // staging: 512 threads cover one 128x32 bf16 tile (1 bf16x8 chunk each)
    const int srow = tid >> 2, scol = (tid & 3) * 8;
    const int gm = m0 + srow;
    const int sm = gather ? (adj[gm >> 8] * 256 + (gm & 255)) : gm;
    const unsigned short* aSrc = X + (size_t)sm * 256 + scol;
    const unsigned short* b0Src = wb + (size_t)widx0 * 65536 + (size_t)(n0 + srow) * 256 + scol;
    const unsigned short* b1Src = wb + (size_t)widx1 * 65536 + (size_t)(n0 + srow) * 256 + scol;

    bf16x8 ar, b0r, b1r;
    f32x4 acc[2][4][2] = {};

    // prologue
    ar = *(const bf16x8*)(aSrc);
    b0r = *(const bf16x8*)(b0Src);
    if (nout == 2) b1r = *(const bf16x8*)(b1Src);
    *(bf16x8*)&lds[srow * 40 + scol] = ar;
    *(bf16x8*)&lds[5120 + srow * 40 + scol] = b0r;
    if (nout == 2) *(bf16x8*)&lds[10240 + srow * 40 + scol] = b1r;
    ar = *(const bf16x8*)(aSrc + 32);
    b0r = *(const bf16x8*)(b0Src + 32);
    if (nout == 2) b1r = *(const bf16x8*)(b1Src + 32);
    __syncthreads();

    for (int st = 0; st < 8; ++st) {
        const int p = st & 1;
        const short* base = lds + p * 15360;
        bf16x8 af[4], bf0[2], bf1[2];
        #pragma unroll
        for (int i = 0; i < 4; ++i)
            af[i] = *(const bf16x8*)&base[(wm * 64 + i * 16 + lr) * 40 + lk];
        #pragma unroll
        for (int j = 0; j < 2; ++j)
            bf0[j] = *(const bf16x8*)&base[5120 + (wn * 32 + j * 16 + lr) * 40 + lk];
        if (nout == 2)
            #pragma unroll
            for (int j = 0; j < 2; ++j)
                bf1[j] = *(const bf16x8*)&base[10240 + (wn * 32 + j * 16 + lr) * 40 + lk];
        #pragma unroll
        for (int i = 0; i < 4; ++i)
            #pragma unroll
            for (int j = 0; j < 2; ++j)
                acc[0][i][j] = mfma_bf16(af[i], bf0[j], acc[0][i][j]);
        if (nout == 2)
            #pragma unroll
            for (int i = 0; i < 4; ++i)
                #pragma unroll
                for (int j = 0; j < 2; ++j)
                    acc[1][i][j] = mfma_bf16(af[i], bf1[j], acc[1][i][j]);
        if (st < 7) {
            short* nbase = lds + (p ^ 1) * 15360;
            *(bf16x8*)&nbase[srow * 40 + scol] = ar;
            *(bf16x8*)&nbase[5120 + srow * 40 + scol] = b0r;
            if (nout == 2) *(bf16x8*)&nbase[10240 + srow * 40 + scol] = b1r;
            if (st < 6) {
                const int ko = (st + 2) * 32;
                ar = *(const bf16x8*)(aSrc + ko);
                b0r = *(const bf16x8*)(b0Src + ko);
                if (nout == 2) b1r = *(const bf16x8*)(b1Src + ko);
            }
        }
        __syncthreads();
    }

    // Epilogue: tanh -> bf16 -> LDS bounce -> coalesced 16B row stores.
    const int erow = tid >> 4? 0 : 0;  (void)erow;
    #pragma unroll
    for (int t = 0; t < 2; ++t)
        if (t < nout) {
            const float* bp = t ? bp1 : bp0;
            float bv[2];
            #pragma unroll
            for (int j = 0; j < 2; ++j)
                bv[j] = bp[n0 + wn * 32 + j * 16 + lr];
            #pragma unroll
            for (int i = 0; i < 4; ++i)
                #pragma unroll
                for (int j = 0; j < 2; ++j)
                    #pragma unroll
                    for (int r = 0; r < 4; ++r)
                        lds[(wm * 64 + i * 16 + lq + r) * 136 + wn * 32 + j * 16 + lr] =
                            (short)f2bf(fast_tanh(acc[t][i][j][r] + bv[j]));
            __syncthreads();
            unsigned short* Y = lin + (size_t)(t ? zidx1 : zidx0) * 8388608;
            #pragma unroll
            for (int it2 = 0; it2 < 4; ++it2) {
                const int c = tid + it2 * 512;
                const int row = c >> 4, col8 = (c & 15) * 8;
                *(bf16x8*)(Y + (size_t)(m0 + row) * 256 + n0 + col8) =
                    *(const bf16x8*)&lds[row * 136 + col8];
            }
            __syncthreads();
        }
}

// ---------------------------------------------------------------------------
// Denominator partials: partial[a][g][q][k] = sum_{n in g} exp(QK^T/sqrt32).
// grid = (4 tiles, 32 groups, 4 attn), block = 256.
// ---------------------------------------------------------------------------
__global__ __launch_bounds__(256) void k_denom(
    const unsigned short* __restrict__ Qa, const unsigned short* __restrict__ Qb2,
    const unsigned short* __restrict__ Qc, const unsigned short* __restrict__ Qd,
    const unsigned short* __restrict__ Kb, float* __restrict__ partialBase)
{
    __shared__ __align__(16) short Qs[128 * 40];
    __shared__ __align__(16) short Ks[128 * 40];
    const int tid = threadIdx.x, w = tid >> 6, l = tid & 63;
    const int q0 = (blockIdx.x >> 1) * 128, k0 = (blockIdx.x & 1) * 128;
    const int g = blockIdx.y, a = blockIdx.z;
    const unsigned short* Qb = (a == 0) ? Qa : (a == 1) ? Qb2 : (a == 2) ? Qc : Qd;
    float* partial = partialBase + ((size_t)a * 32 + g) * 65536;
    const int lr = l & 15, lk = (l >> 4) * 8, lq = (l >> 4) * 4;

    f32x4 eacc[2][8] = {};
    for (int n = g * 32; n < g * 32 + 32; ++n) {
        const int c = n >> 7, b = n & 127;
        const size_t base = (size_t)b * 65536 + (size_t)c * 32;
        __syncthreads();
        for (int ci = tid; ci < 512; ci += 256) {
            int r = ci >> 2, ch = ci & 3;
            *(bf16x8*)&Qs[r * 40 + ch * 8] =
                *(const bf16x8*)(Qb + base + (size_t)(q0 + r) * 256 + ch * 8);
            *(bf16x8*)&Ks[r * 40 + ch * 8] =
                *(const bf16x8*)(Kb + base + (size_t)(k0 + r) * 256 + ch * 8);
        }
        __syncthreads();
        bf16x8 aq[2], bk[8];
        #pragma unroll
        for (int i = 0; i < 2; ++i)
            aq[i] = *(const bf16x8*)&Qs[(w * 32 + i * 16 + lr) * 40 + lk];
        #pragma unroll
        for (int j = 0; j < 8; ++j)
            bk[j] = *(const bf16x8*)&Ks[(j * 16 + lr) * 40 + lk];
        #pragma unroll
        for (int i = 0; i < 2; ++i)
            #pragma unroll
            for (int j = 0; j < 8; ++j) {
                f32x4 s = mfma_bf16(aq[i], bk[j], (f32x4){0.f, 0.f, 0.f, 0.f});
                #pragma unroll
                for (int r = 0; r < 4; ++r)
                    eacc[i][j][r] += __builtin_amdgcn_exp2f(s[r] * SM_SCALE);
            }
    }
    #pragma unroll
    for (int i = 0; i < 2; ++i)
        #pragma unroll
        for (int j = 0; j < 8; ++j)
            #pragma unroll
            for (int r = 0; r < 4; ++r) {
                int q = q0 + w * 32 + i * 16 + lq + r;
                int k = k0 + j * 16 + lr;
                partial[(size_t)q * 256 + k] = eacc[i][j][r];
            }
}

// ---------------------------------------------------------------------------
// Reduce 32 partials -> Dinv = 1/sum, written in the wave-fragment-permuted
// layout consumed by k_attn:
//   dinvP[a][w][kp][i][j][h][q16][r],  q = w*64+i*16+q16, k = kp*32+j*16+h*4+r
// grid = (256, 4)
// ---------------------------------------------------------------------------
__global__ __launch_bounds__(256) void k_reduce(
    const float* __restrict__ partial, float* __restrict__ dinvP)
{
    int a = blockIdx.y;
    int i = blockIdx.x * 256 + threadIdx.x;
    const float* p = partial + (size_t)a * 32 * 65536 + i;
    float s = 0.f;
    #pragma unroll
    for (int g = 0; g < 32; ++g) s += p[(size_t)g * 65536];
    const int q = i >> 8, k = i & 255;
    const int w_ = q >> 6, iq = (q >> 4) & 3, q16 = q & 15;
    const int kp = k >> 5, j = (k >> 4) & 1, h = (k >> 2) & 3, r = k & 3;
    const int off = (((((((w_ * 8 + kp) * 4 + iq) * 2 + j) * 4 + h) * 16) + q16) * 4) + r;
    dinvP[((size_t)a << 16) + off] = 1.0f / s;
}

// ---------------------------------------------------------------------------
// Attention: o = (exp(QK^T/sqrt32) * Dinv) @ V.  grid = 4096 (XCD-swizzled
// over (head n, attn a)), block = 256 (4 waves x 64 q-rows).
// ---------------------------------------------------------------------------
__global__ __launch_bounds__(256) void k_attn(
    const unsigned short* __restrict__ Q1, const unsigned short* __restrict__ Q2,
    const unsigned short* __restrict__ Q3, const unsigned short* __restrict__ Q4,
    const unsigned short* __restrict__ Kb,
    const unsigned short* __restrict__ V1, const unsigned short* __restrict__ V2,
    const unsigned short* __restrict__ V3, const unsigned short* __restrict__ V4,
    const float* __restrict__ dinvP,
    float* __restrict__ outBase, unsigned short* __restrict__ ob4)
{
    __shared__ __align__(16) short Vt[32 * 264];      // V^T: [d=32][k=256] pad 264
    const int tid = threadIdx.x, w = tid >> 6, l = tid & 63;
    const int bid = blockIdx.x;
    const int swz = (bid & 7) * 512 + (bid >> 3);
    const int a = swz & 3, n = swz >> 2;
    const int c = n >> 7, b = n & 127;
    const int q16 = l & 15, h = l >> 4;
    const size_t base = (size_t)b * 65536 + (size_t)c * 32;

    const unsigned short* Qb = (a == 0) ? Q1 : (a == 1) ? Q2 : (a == 2) ? Q3 : Q4;
    const unsigned short* Vb = (a == 0) ? V1 : (a == 1) ? V2 : (a == 2) ? V3 : V4;
    const f32x4* dpa = (const f32x4*)(dinvP + ((size_t)a << 16)) + l;
    float* outp = outBase + (size_t)((a == 2) ? 3 : a) * 8388608;

    {
        const unsigned short* vp = Vb + base + (size_t)tid * 256;
        bf16x8 v0 = *(const bf16x8*)(vp);
        bf16x8 v1 = *(const bf16x8*)(vp + 8);
        bf16x8 v2 = *(const bf16x8*)(vp + 16);
        bf16x8 v3 = *(const bf16x8*)(vp + 24);
        #pragma unroll
        for (int e = 0; e < 8; ++e) {
            Vt[(0  + e) * 264 + tid] = v0[e];
            Vt[(8  + e) * 264 + tid] = v1[e];
            Vt[(16 + e) * 264 + tid] = v2[e];
            Vt[(24 + e) * 264 + tid] = v3[e];
        }
    }
    __syncthreads();

    const int q0 = w * 64;
    bf16x8 bq[4];
    #pragma unroll
    for (int i = 0; i < 4; ++i)
        bq[i] = *(const bf16x8*)(Qb + base + (size_t)(q0 + i * 16 + q16) * 256 + h * 8);

    f32x4 oacc[4][2] = {};
    #pragma unroll 2
    for (int kp = 0; kp < 8; ++kp) {
        const int kk0 = kp * 32;
        bf16x8 ak0 = *(const bf16x8*)(Kb + base + (size_t)(kk0 + q16) * 256 + h * 8);
        bf16x8 ak1 = *(const bf16x8*)(Kb + base + (size_t)(kk0 + 16 + q16) * 256 + h * 8);
        bf16x8 vb0 = *(const bf16x8*)&Vt[(0  + q16) * 264 + kk0 + h * 8];
        bf16x8 vb1 = *(const bf16x8*)&Vt[(16 + q16) * 264 + kk0 + h * 8];
        #pragma unroll
        for (int i = 0; i < 4; ++i) {
            f32x4 s0 = mfma_bf16(ak0, bq[i], (f32x4){0.f, 0.f, 0.f, 0.f});
            f32x4 s1 = mfma_bf16(ak1, bq[i], (f32x4){0.f, 0.f, 0.f, 0.f});
            const int X = ((w * 8 + kp) * 4 + i) * 2;
            f32x4 d0 = dpa[(size_t)X * 64];
            f32x4 d1 = dpa[(size_t)(X + 1) * 64];
            float p0 = __builtin_amdgcn_exp2f(s0[0] * SM_SCALE) * d0[0];
            float p1 = __builtin_amdgcn_exp2f(s0[1] * SM_SCALE) * d0[1];
            float p2 = __builtin_amdgcn_exp2f(s0[2] * SM_SCALE) * d0[2];
            float p3 = __builtin_amdgcn_exp2f(s0[3] * SM_SCALE) * d0[3];
            float p4 = __builtin_amdgcn_exp2f(s1[0] * SM_SCALE) * d1[0];
            float p5 = __builtin_amdgcn_exp2f(s1[1] * SM_SCALE) * d1[1];
            float p6 = __builtin_amdgcn_exp2f(s1[2] * SM_SCALE) * d1[2];
            float p7 = __builtin_amdgcn_exp2f(s1[3] * SM_SCALE) * d1[3];
            unsigned r0, r1, r2, r3;
            CVT_PK(r0, p0, p1);
            CVT_PK(r1, p2, p3);
            CVT_PK(r2, p4, p5);
            CVT_PK(r3, p6, p7);
            SWAP32(r0, r2); SWAP16(r0, r2);
            SWAP32(r1, r3); SWAP16(r1, r3);
            union { unsigned u[4]; bf16x8 v; } F;
            F.u[0] = r0; F.u[1] = r1; F.u[2] = r2; F.u[3] = r3;
            oacc[i][0] = mfma_bf16(F.v, vb0, oacc[i][0]);
            oacc[i][1] = mfma_bf16(F.v, vb1, oacc[i][1]);
        }
    }
    if (a == 3) {
        #pragma unroll
        for (int i = 0; i < 4; ++i)
            #pragma unroll
            for (int d = 0; d < 2; ++d)
                #pragma unroll
                for (int r = 0; r < 4; ++r) {
                    int q = q0 + i * 16 + h * 4 + r;
                    int dc = d * 16 + q16;
                    ob4[(size_t)b * 65536 + (size_t)q * 256 + c * 32 + dc] =
                        f2bf(oacc[i][d][r]);
                }
    } else {
        #pragma unroll
        for (int i = 0; i < 4; ++i)
            #pragma unroll
            for (int d = 0; d < 2; ++d)
                #pragma unroll
                for (int r = 0; r < 4; ++r) {
                    int q = q0 + i * 16 + h * 4 + r;
                    int dc = d * 16 + q16;
                    outp[(size_t)b * 65536 + (size_t)q * 256 + c * 32 + dc] =
                        oacc[i][d][r];
                }
    }
}

// ---------------------------------------------------------------------------
// Final: o5 = tanh(concat(o1..o4) @ W5^T + b5).  M=32768, N=256, K=1024.
// o1..o3 fp32 (d_out planes), o4 bf16 (ws).  BM=128, BN=128, BK=64.
// ---------------------------------------------------------------------------
__global__ __launch_bounds__(256) void k_final(
    const float* __restrict__ p0, const float* __restrict__ p1,
    const float* __restrict__ p2, const unsigned short* __restrict__ p3,
    const unsigned short* __restrict__ W5b, const float* __restrict__ b5,
    float* __restrict__ out)
{
    __shared__ __align__(16) short As[128 * 72];
    __shared__ __align__(16) short Bs[128 * 72];
    const int tid = threadIdx.x, w = tid >> 6, l = tid & 63;
    const int n0 = blockIdx.x * 128, m0 = blockIdx.y * 128;
    const int lr = l & 15, lk = (l >> 4) * 8, lq = (l >> 4) * 4;
    const int wr = (w >> 1) * 64, wc = (w & 1) * 64;
    f32x4 acc[4][4] = {};
    for (int step = 0; step < 16; ++step) {
        const int k0 = step * 64;
        const int kc = k0 & 255;
        __syncthreads();
        if (step < 12) {
            const float* P = (step < 4) ? p0 : (step < 8) ? p1 : p2;
            for (int ci = tid; ci < 1024; ci += 256) {
                int r = ci >> 3, ch = ci & 7;
                const float* src = P + (size_t)(m0 + r) * 256 + kc + ch * 8;
                float4 f0 = *(const float4*)src;
                float4 f1 = *(const float4*)(src + 4);
                unsigned a0, a1, a2, a3;
                CVT_PK(a0, f0.x, f0.y);
                CVT_PK(a1, f0.z, f0.w);
                CVT_PK(a2, f1.x, f1.y);
                CVT_PK(a3, f1.z, f1.w);
                uint4 pk; pk.x = a0; pk.y = a1; pk.z = a2; pk.w = a3;
                *(uint4*)&As[r * 72 + ch * 8] = pk;
                *(bf16x8*)&Bs[r * 72 + ch * 8] =
                    *(const bf16x8*)(W5b + (size_t)(n0 + r) * 1024 + k0 + ch * 8);
            }
        } else {
            for (int ci = tid; ci < 1024; ci += 256) {
                int r = ci >> 3, ch = ci & 7;
                *(bf16x8*)&As[r * 72 + ch * 8] =
                    *(const bf16x8*)(p3 + (size_t)(m0 + r) * 256 + kc + ch * 8);
                *(bf16x8*)&Bs[r * 72 + ch * 8] =
                    *(const bf16x8*)(W5b + (size_t)(n0 + r) * 1024 + k0 + ch * 8);
            }
        }
        __syncthreads();
        #pragma unroll
        for (int kk = 0; kk < 2; ++kk) {
            bf16x8 af[4], bfr[4];
            #pragma unroll
            for (int i = 0; i < 4; ++i)
                af[i] = *(const bf16x8*)&As[(wr + i * 16 + lr) * 72 + kk * 32 + lk];
            #pragma unroll
            for (int j = 0; j < 4; ++j)
                bfr[j] = *(const bf16x8*)&Bs[(wc + j * 16 + lr) * 72 + kk * 32 + lk];
            #pragma unroll
            for (int i = 0; i < 4; ++i)
                #pragma unroll
                for (int j = 0; j < 4; ++j)
                    acc[i][j] = mfma_bf16(af[i], bfr[j], acc[i][j]);
        }
    }
    #pragma unroll
    for (int j = 0; j < 4; ++j) {
        int col = n0 + wc + j * 16 + lr;
        float bv = b5[col];
        #pragma unroll
        for (int i = 0; i < 4; ++i) {
            int rowb = m0 + wr + i * 16 + lq;
            #pragma unroll
            for (int r = 0; r < 4; ++r)
                out[(size_t)(rowb + r) * 256 + col] =
                    fast_tanh(acc[i][j][r] + bv);
        }
    }
}

// ---------------------------------------------------------------------------
extern "C" void kernel_launch(void* const* d_in, const int* in_sizes, int n_in,
                              void* d_out, int out_size, void* d_ws, size_t ws_size,
                              hipStream_t stream)
{
    const float* q1  = (const float*)d_in[0];
    const float* q2  = (const float*)d_in[1];
    const float* q3  = (const float*)d_in[2];
    const int*   adj = (const int*)d_in[3];
    const float* WQ  = (const float*)d_in[4];  const float* bQ  = (const float*)d_in[5];
    const float* WV  = (const float*)d_in[6];  const float* bV  = (const float*)d_in[7];
    const float* WQ3 = (const float*)d_in[8];  const float* bQ3 = (const float*)d_in[9];
    const float* WK3 = (const float*)d_in[10]; const float* bK3 = (const float*)d_in[11];
    const float* WV3 = (const float*)d_in[12]; const float* bV3 = (const float*)d_in[13];
    const float* WQ4 = (const float*)d_in[14]; const float* bQ4 = (const float*)d_in[15];
    const float* WV4 = (const float*)d_in[16]; const float* bV4 = (const float*)d_in[17];
    const float* W5  = (const float*)d_in[18]; const float* b5  = (const float*)d_in[19];

    char* ws = (char*)d_ws;
    unsigned short* wb  = (unsigned short*)ws;               // 720896 bf16 weights
    unsigned short* W5b = wb + 458752;
    unsigned short* lin = (unsigned short*)(ws + 1441792);   // 9 x 32768x256 bf16
    unsigned short* Q1 = lin + 0ull * 8388608;
    unsigned short* Q2 = lin + 1ull * 8388608;
    unsigned short* Q3 = lin + 2ull * 8388608;
    unsigned short* Q4 = lin + 3ull * 8388608;
    unsigned short* K3 = lin + 4ull * 8388608;
    unsigned short* V1 = lin + 5ull * 8388608;
    unsigned short* V2 = lin + 6ull * 8388608;
    unsigned short* V3 = lin + 7ull * 8388608;
    unsigned short* V4 = lin + 8ull * 8388608;
    float* partial = (float*)(ws + 152436736);               // 4*32*65536 f32
    float* dinvP   = (float*)(ws + 185991168);               // 4*65536 f32 (permuted)
    unsigned short* ob4 = (unsigned short*)(ws + 152436736); // o4 bf16, overlaps dead partial

    float* outf = (float*)d_out;   // planes: o1(0) o2(1) o5(2) o3(3)
    float* o5p = outf + 2ull * 8388608;
    // Xb (q1/q2/q3 bf16, 48 MB) lives in d_out's o1+o2 planes — dead until k_attn.
    unsigned short* Xb = (unsigned short*)d_out;

    dim3 blk(256);

    hipLaunchKernelGGL(k_convert_w, dim3(2816), blk, 0, stream,
                       WQ, WV, WQ3, WK3, WV3, WQ4, WV4, W5, wb);
    hipLaunchKernelGGL(k_convert_x, dim3(12288), blk, 0, stream,
                       q1, q2, q3, Xb);

    hipLaunchKernelGGL(k_linear, dim3(2560), dim3(512), 0, stream,
                       Xb, adj, wb,
                       bQ, bV, bQ3, bK3, bV3, bQ4, bV4, lin);

    hipLaunchKernelGGL(k_denom, dim3(4, 32, 4), blk, 0, stream,
                       Q1, Q2, Q3, Q4, K3, partial);
    hipLaunchKernelGGL(k_reduce, dim3(256, 4), blk, 0, stream, partial, dinvP);

    hipLaunchKernelGGL(k_attn, dim3(4096), blk, 0, stream,
                       Q1, Q2, Q3, Q4, K3, V1, V2, V3, V4, dinvP,
                       outf, ob4);

    hipLaunchKernelGGL(k_final, dim3(2, 256), blk, 0, stream,
                       outf, outf + 8388608ull, outf + 3ull * 8388608, ob4,
                       W5b, b5, o5p);
}

// Round 10
// 335.074 us; speedup vs baseline: 2.3990x; 1.0243x over previous
//
#include <hip/hip_runtime.h>

// ---------------------------------------------------------------------------
// multihead_attention_87454124081549 — round 10
// Round-10 (bisect): exponent-fold fully reverted (k_reduce stores 1/s,
// k_attn multiplies by dinv — round-7 verified numerics). K-prefetch kept as
// the SINGLE remaining suspect from rounds 8/9. k_denom gets a safe 2x unroll
// (two heads staged per barrier pair, 64 -> 32 barriers).
// ---------------------------------------------------------------------------

typedef __attribute__((ext_vector_type(4))) float f32x4;
typedef __attribute__((ext_vector_type(8))) short bf16x8;

#define LOG2E 1.4426950408889634f
#define SM_SCALE (1.4426950408889634f / 5.656854249492381f)  // log2(e)/sqrt(32)

#define CVT_PK(d, lo, hi) \
    asm("v_cvt_pk_bf16_f32 %0, %1, %2" : "=v"(d) : "v"(lo), "v"(hi))
#define SWAP32(x, y) \
    asm("v_permlane32_swap_b32 %0, %1" : "+v"(x), "+v"(y))
#define SWAP16(x, y) \
    asm("v_permlane16_swap_b32 %0, %1" : "+v"(x), "+v"(y))

__device__ __forceinline__ unsigned short f2bf(float x) {
    union { float f; unsigned u; } v; v.f = x;
    unsigned r = v.u + 0x7FFFu + ((v.u >> 16) & 1u);   // RNE
    return (unsigned short)(r >> 16);
}

__device__ __forceinline__ float fast_tanh(float x) {
    float e = __builtin_amdgcn_exp2f(x * (2.0f * LOG2E));   // exp(2x)
    return 1.0f - 2.0f * __builtin_amdgcn_rcpf(e + 1.0f);
}

__device__ __forceinline__ f32x4 mfma_bf16(bf16x8 a, bf16x8 b, f32x4 c) {
    return __builtin_amdgcn_mfma_f32_16x16x32_bf16(a, b, c, 0, 0, 0);
}

// ---------------------------------------------------------------------------
// Weight conversion: 7 x (256x256) + W5 (256x1024) fp32 -> bf16, concatenated.
// Order: WQ(0) WV(1) WQ3(2) WK3(3) WV3(4) WQ4(5) WV4(6) W5(@458752)
// ---------------------------------------------------------------------------
__global__ __launch_bounds__(256) void k_convert_w(
    const float* w0, const float* w1, const float* w2, const float* w3,
    const float* w4, const float* w5, const float* w6, const float* w7,
    unsigned short* out)
{
    int i = blockIdx.x * 256 + threadIdx.x;
    if (i >= 720896) return;
    float v;
    if (i < 458752) {
        int r = i >> 16, j = i & 65535;
        const float* s =
            (r == 0) ? w0 : (r == 1) ? w1 : (r == 2) ? w2 :
            (r == 3) ? w3 : (r == 4) ? w4 : (r == 5) ? w5 : w6;
        v = s[j];
    } else {
        v = w7[i - 458752];
    }
    out[i] = (short)f2bf(v);
}

// ---------------------------------------------------------------------------
// X conversion: q1,q2,q3 (each 8388608 fp32) -> bf16, concatenated in Xb.
// ---------------------------------------------------------------------------
__global__ __launch_bounds__(256) void k_convert_x(
    const float* __restrict__ q1, const float* __restrict__ q2,
    const float* __restrict__ q3, unsigned short* __restrict__ Xb)
{
    const int gi = (blockIdx.x * 256 + threadIdx.x) * 8;
    const float* s = (gi < 8388608) ? q1 : (gi < 16777216) ? q2 : q3;
    const int off = gi & 8388607;
    float4 f0 = *(const float4*)(s + off);
    float4 f1 = *(const float4*)(s + off + 4);
    unsigned a0, a1, a2, a3;
    CVT_PK(a0, f0.x, f0.y);
    CVT_PK(a1, f0.z, f0.w);
    CVT_PK(a2, f1.x, f1.y);
    CVT_PK(a3, f1.z, f1.w);
    uint4 pk; pk.x = a0; pk.y = a1; pk.z = a2; pk.w = a3;
    *(uint4*)(Xb + gi) = pk;
}

// ---------------------------------------------------------------------------
// Linear + tanh, grouped by input:  Y(bf16) = tanh(Xb(bf16) @ W^T + bias)
// grid = 2560 (XCD-swizzled), block = 512 (8 waves: 2m x 4n, tile 64x32/out).
// ---------------------------------------------------------------------------
__global__ __launch_bounds__(512, 4) void k_linear(
    const unsigned short* __restrict__ Xb, const int* __restrict__ adj,
    const unsigned short* __restrict__ wb,
    const float* __restrict__ bQ, const float* __restrict__ bV,
    const float* __restrict__ bQ3, const float* __restrict__ bK3,
    const float* __restrict__ bV3, const float* __restrict__ bQ4,
    const float* __restrict__ bV4,
    unsigned short* __restrict__ lin)
{
    __shared__ __align__(16) short lds[30720];   // 2 x (A 5120 + B0 5120 + B1 5120)
    const int bid0 = blockIdx.x;                 // 2560 = 8 XCD x 320
    const int swz = (bid0 & 7) * 320 + (bid0 >> 3);
    const int var = swz >> 9;
    const int rem = swz & 511;
    const int m0 = (rem >> 1) * 128, n0 = (rem & 1) * 128;

    const unsigned short* X = Xb + (size_t)((var == 0) ? 0 : (var == 1) ? 1 : 2) * 8388608;
    const bool gather = (var == 4);
    const int nout = (var == 3) ? 1 : 2;

    int widx0, widx1 = 0, zidx0, zidx1 = 0;
    const float* bp0;
    const float* bp1 = bQ;
    if (var == 0)      { widx0=0; widx1=1; zidx0=0; zidx1=5; bp0=bQ;  bp1=bV;  }
    else if (var == 1) { widx0=0; widx1=1; zidx0=1; zidx1=6; bp0=bQ;  bp1=bV;  }
    else if (var == 2) { widx0=2; widx1=3; zidx0=2; zidx1=4; bp0=bQ3; bp1=bK3; }
    else if (var == 3) { widx0=4;          zidx0=7;          bp0=bV3;          }
    else               { widx0=5; widx1=6; zidx0=3; zidx1=8; bp0=bQ4; bp1=bV4; }

    const int tid = threadIdx.x;
    const int w = tid >> 6, l = tid & 63;
    const int wm = w >> 2, wn = w & 3;           // 2 x 4 wave grid
    const int lr = l & 15, lk = (l >> 4) * 8, lq = (l >> 4) * 4;

    const int srow = tid >> 2, scol = (tid & 3) * 8;
    const int gm = m0 + srow;
    const int sm = gather ? (adj[gm >> 8] * 256 + (gm & 255)) : gm;
    const unsigned short* aSrc = X + (size_t)sm * 256 + scol;
    const unsigned short* b0Src = wb + (size_t)widx0 * 65536 + (size_t)(n0 + srow) * 256 + scol;
    const unsigned short* b1Src = wb + (size_t)widx1 * 65536 + (size_t)(n0 + srow) * 256 + scol;

    bf16x8 ar, b0r, b1r;
    f32x4 acc[2][4][2] = {};

    ar = *(const bf16x8*)(aSrc);
    b0r = *(const bf16x8*)(b0Src);
    if (nout == 2) b1r = *(const bf16x8*)(b1Src);
    *(bf16x8*)&lds[srow * 40 + scol] = ar;
    *(bf16x8*)&lds[5120 + srow * 40 + scol] = b0r;
    if (nout == 2) *(bf16x8*)&lds[10240 + srow * 40 + scol] = b1r;
    ar = *(const bf16x8*)(aSrc + 32);
    b0r = *(const bf16x8*)(b0Src + 32);
    if (nout == 2) b1r = *(const bf16x8*)(b1Src + 32);
    __syncthreads();

    for (int st = 0; st < 8; ++st) {
        const int p = st & 1;
        const short* base = lds + p * 15360;
        bf16x8 af[4], bf0[2], bf1[2];
        #pragma unroll
        for (int i = 0; i < 4; ++i)
            af[i] = *(const bf16x8*)&base[(wm * 64 + i * 16 + lr) * 40 + lk];
        #pragma unroll
        for (int j = 0; j < 2; ++j)
            bf0[j] = *(const bf16x8*)&base[5120 + (wn * 32 + j * 16 + lr) * 40 + lk];
        if (nout == 2)
            #pragma unroll
            for (int j = 0; j < 2; ++j)
                bf1[j] = *(const bf16x8*)&base[10240 + (wn * 32 + j * 16 + lr) * 40 + lk];
        #pragma unroll
        for (int i = 0; i < 4; ++i)
            #pragma unroll
            for (int j = 0; j < 2; ++j)
                acc[0][i][j] = mfma_bf16(af[i], bf0[j], acc[0][i][j]);
        if (nout == 2)
            #pragma unroll
            for (int i = 0; i < 4; ++i)
                #pragma unroll
                for (int j = 0; j < 2; ++j)
                    acc[1][i][j] = mfma_bf16(af[i], bf1[j], acc[1][i][j]);
        if (st < 7) {
            short* nbase = lds + (p ^ 1) * 15360;
            *(bf16x8*)&nbase[srow * 40 + scol] = ar;
            *(bf16x8*)&nbase[5120 + srow * 40 + scol] = b0r;
            if (nout == 2) *(bf16x8*)&nbase[10240 + srow * 40 + scol] = b1r;
            if (st < 6) {
                const int ko = (st + 2) * 32;
                ar = *(const bf16x8*)(aSrc + ko);
                b0r = *(const bf16x8*)(b0Src + ko);
                if (nout == 2) b1r = *(const bf16x8*)(b1Src + ko);
            }
        }
        __syncthreads();
    }

    #pragma unroll
    for (int t = 0; t < 2; ++t)
        if (t < nout) {
            const float* bp = t ? bp1 : bp0;
            float bv[2];
            #pragma unroll
            for (int j = 0; j < 2; ++j)
                bv[j] = bp[n0 + wn * 32 + j * 16 + lr];
            #pragma unroll
            for (int i = 0; i < 4; ++i)
                #pragma unroll
                for (int j = 0; j < 2; ++j)
                    #pragma unroll
                    for (int r = 0; r < 4; ++r)
                        lds[(wm * 64 + i * 16 + lq + r) * 136 + wn * 32 + j * 16 + lr] =
                            (short)f2bf(fast_tanh(acc[t][i][j][r] + bv[j]));
            __syncthreads();
            unsigned short* Y = lin + (size_t)(t ? zidx1 : zidx0) * 8388608;
            #pragma unroll
            for (int it2 = 0; it2 < 4; ++it2) {
                const int c = tid + it2 * 512;
                const int row = c >> 4, col8 = (c & 15) * 8;
                *(bf16x8*)(Y + (size_t)(m0 + row) * 256 + n0 + col8) =
                    *(const bf16x8*)&lds[row * 136 + col8];
            }
            __syncthreads();
        }
}

// ---------------------------------------------------------------------------
// Denominator partials: partial[a][g][q][k] = sum_{n in g} exp(QK^T/sqrt32).
// grid = (4 tiles, 32 groups, 4 attn), block = 256.
// Round-10: 2 heads staged per barrier pair (Qs[2]/Ks[2], 40 KB) — halves the
// barrier count vs round-7; compute section is round-7 verbatim per head.
// ---------------------------------------------------------------------------
__global__ __launch_bounds__(256) void k_denom(
    const unsigned short* __restrict__ Qa, const unsigned short* __restrict__ Qb2,
    const unsigned short* __restrict__ Qc, const unsigned short* __restrict__ Qd,
    const unsigned short* __restrict__ Kb, float* __restrict__ partialBase)
{
    __shared__ __align__(16) short Qs[2][128 * 40];
    __shared__ __align__(16) short Ks[2][128 * 40];
    const int tid = threadIdx.x, w = tid >> 6, l = tid & 63;
    const int q0 = (blockIdx.x >> 1) * 128, k0 = (blockIdx.x & 1) * 128;
    const int g = blockIdx.y, a = blockIdx.z;
    const unsigned short* Qb = (a == 0) ? Qa : (a == 1) ? Qb2 : (a == 2) ? Qc : Qd;
    float* partial = partialBase + ((size_t)a * 32 + g) * 65536;
    const int lr = l & 15, lk = (l >> 4) * 8, lq = (l >> 4) * 4;

    f32x4 eacc[2][8] = {};
    for (int it = 0; it < 32; it += 2) {
        __syncthreads();
        #pragma unroll
        for (int u = 0; u < 2; ++u) {
            const int n = g * 32 + it + u;
            const int c = n >> 7, b = n & 127;
            const size_t base = (size_t)b * 65536 + (size_t)c * 32;
            for (int ci = tid; ci < 512; ci += 256) {
                int r = ci >> 2, ch = ci & 3;
                *(bf16x8*)&Qs[u][r * 40 + ch * 8] =
                    *(const bf16x8*)(Qb + base + (size_t)(q0 + r) * 256 + ch * 8);
                *(bf16x8*)&Ks[u][r * 40 + ch * 8] =
                    *(const bf16x8*)(Kb + base + (size_t)(k0 + r) * 256 + ch * 8);
            }
        }
        __syncthreads();
        #pragma unroll
        for (int u = 0; u < 2; ++u) {
            bf16x8 aq[2], bk[8];
            #pragma unroll
            for (int i = 0; i < 2; ++i)
                aq[i] = *(const bf16x8*)&Qs[u][(w * 32 + i * 16 + lr) * 40 + lk];
            #pragma unroll
            for (int j = 0; j < 8; ++j)
                bk[j] = *(const bf16x8*)&Ks[u][(j * 16 + lr) * 40 + lk];
            #pragma unroll
            for (int i = 0; i < 2; ++i)
                #pragma unroll
                for (int j = 0; j < 8; ++j) {
                    f32x4 s = mfma_bf16(aq[i], bk[j], (f32x4){0.f, 0.f, 0.f, 0.f});
                    #pragma unroll
                    for (int r = 0; r < 4; ++r)
                        eacc[i][j][r] += __builtin_amdgcn_exp2f(s[r] * SM_SCALE);
                }
        }
    }
    #pragma unroll
    for (int i = 0; i < 2; ++i)
        #pragma unroll
        for (int j = 0; j < 8; ++j)
            #pragma unroll
            for (int r = 0; r < 4; ++r) {
                int q = q0 + w * 32 + i * 16 + lq + r;
                int k = k0 + j * 16 + lr;
                partial[(size_t)q * 256 + k] = eacc[i][j][r];
            }
}

// ---------------------------------------------------------------------------
// Reduce 32 partials -> Dinv = 1/sum, written in the wave-fragment-permuted
// layout consumed by k_attn (round-7 verbatim):
//   dinvP[a][w][kp][i][j][h][q16][r],  q = w*64+i*16+q16, k = kp*32+j*16+h*4+r
// grid = (256, 4)
// ---------------------------------------------------------------------------
__global__ __launch_bounds__(256) void k_reduce(
    const float* __restrict__ partial, float* __restrict__ dinvP)
{
    int a = blockIdx.y;
    int i = blockIdx.x * 256 + threadIdx.x;
    const float* p = partial + (size_t)a * 32 * 65536 + i;
    float s = 0.f;
    #pragma unroll
    for (int g = 0; g < 32; ++g) s += p[(size_t)g * 65536];
    const int q = i >> 8, k = i & 255;
    const int w_ = q >> 6, iq = (q >> 4) & 3, q16 = q & 15;
    const int kp = k >> 5, j = (k >> 4) & 1, h = (k >> 2) & 3, r = k & 3;
    const int off = (((((((w_ * 8 + kp) * 4 + iq) * 2 + j) * 4 + h) * 16) + q16) * 4) + r;
    dinvP[((size_t)a << 16) + off] = 1.0f / s;
}

// ---------------------------------------------------------------------------
// Attention: o = (exp(QK^T/sqrt32) * Dinv) @ V.  grid = 4096 (XCD-swizzled
// over (head n, attn a)), block = 256 (4 waves x 64 q-rows).
// Round-7 numerics (dinv multiply); K prefetched one kp ahead (the single
// round-8/9 element under bisection).
// ---------------------------------------------------------------------------
__global__ __launch_bounds__(256) void k_attn(
    const unsigned short* __restrict__ Q1, const unsigned short* __restrict__ Q2,
    const unsigned short* __restrict__ Q3, const unsigned short* __restrict__ Q4,
    const unsigned short* __restrict__ Kb,
    const unsigned short* __restrict__ V1, const unsigned short* __restrict__ V2,
    const unsigned short* __restrict__ V3, const unsigned short* __restrict__ V4,
    const float* __restrict__ dinvP,
    float* __restrict__ outBase, unsigned short* __restrict__ ob4)
{
    __shared__ __align__(16) short Vt[32 * 264];      // V^T: [d=32][k=256] pad 264
    const int tid = threadIdx.x, w = tid >> 6, l = tid & 63;
    const int bid = blockIdx.x;
    const int swz = (bid & 7) * 512 + (bid >> 3);
    const int a = swz & 3, n = swz >> 2;
    const int c = n >> 7, b = n & 127;
    const int q16 = l & 15, h = l >> 4;
    const size_t base = (size_t)b * 65536 + (size_t)c * 32;

    const unsigned short* Qb = (a == 0) ? Q1 : (a == 1) ? Q2 : (a == 2) ? Q3 : Q4;
    const unsigned short* Vb = (a == 0) ? V1 : (a == 1) ? V2 : (a == 2) ? V3 : V4;
    const f32x4* dpa = (const f32x4*)(dinvP + ((size_t)a << 16)) + l;
    float* outp = outBase + (size_t)((a == 2) ? 3 : a) * 8388608;

    {
        const unsigned short* vp = Vb + base + (size_t)tid * 256;
        bf16x8 v0 = *(const bf16x8*)(vp);
        bf16x8 v1 = *(const bf16x8*)(vp + 8);
        bf16x8 v2 = *(const bf16x8*)(vp + 16);
        bf16x8 v3 = *(const bf16x8*)(vp + 24);
        #pragma unroll
        for (int e = 0; e < 8; ++e) {
            Vt[(0  + e) * 264 + tid] = v0[e];
            Vt[(8  + e) * 264 + tid] = v1[e];
            Vt[(16 + e) * 264 + tid] = v2[e];
            Vt[(24 + e) * 264 + tid] = v3[e];
        }
    }
    __syncthreads();

    const int q0 = w * 64;
    bf16x8 bq[4];
    #pragma unroll
    for (int i = 0; i < 4; ++i)
        bq[i] = *(const bf16x8*)(Qb + base + (size_t)(q0 + i * 16 + q16) * 256 + h * 8);

    const unsigned short* kSrc = Kb + base + (size_t)q16 * 256 + h * 8;
    bf16x8 akA = *(const bf16x8*)(kSrc);
    bf16x8 akB = *(const bf16x8*)(kSrc + 16 * 256);

    f32x4 oacc[4][2] = {};
    for (int kp = 0; kp < 8; ++kp) {
        const int kk0 = kp * 32;
        bf16x8 nA = akA, nB = akB;
        if (kp < 7) {
            nA = *(const bf16x8*)(kSrc + (size_t)(kk0 + 32) * 256);
            nB = *(const bf16x8*)(kSrc + (size_t)(kk0 + 48) * 256);
        }
        bf16x8 vb0 = *(const bf16x8*)&Vt[(0  + q16) * 264 + kk0 + h * 8];
        bf16x8 vb1 = *(const bf16x8*)&Vt[(16 + q16) * 264 + kk0 + h * 8];
        #pragma unroll
        for (int i = 0; i < 4; ++i) {
            f32x4 s0 = mfma_bf16(akA, bq[i], (f32x4){0.f, 0.f, 0.f, 0.f});
            f32x4 s1 = mfma_bf16(akB, bq[i], (f32x4){0.f, 0.f, 0.f, 0.f});
            const int X = ((w * 8 + kp) * 4 + i) * 2;
            f32x4 d0 = dpa[(size_t)X * 64];
            f32x4 d1 = dpa[(size_t)(X + 1) * 64];
            float p0 = __builtin_amdgcn_exp2f(s0[0] * SM_SCALE) * d0[0];
            float p1 = __builtin_amdgcn_exp2f(s0[1] * SM_SCALE) * d0[1];
            float p2 = __builtin_amdgcn_exp2f(s0[2] * SM_SCALE) * d0[2];
            float p3 = __builtin_amdgcn_exp2f(s0[3] * SM_SCALE) * d0[3];
            float p4 = __builtin_amdgcn_exp2f(s1[0] * SM_SCALE) * d1[0];
            float p5 = __builtin_amdgcn_exp2f(s1[1] * SM_SCALE) * d1[1];
            float p6 = __builtin_amdgcn_exp2f(s1[2] * SM_SCALE) * d1[2];
            float p7 = __builtin_amdgcn_exp2f(s1[3] * SM_SCALE) * d1[3];
            unsigned r0, r1, r2, r3;
            CVT_PK(r0, p0, p1);
            CVT_PK(r1, p2, p3);
            CVT_PK(r2, p4, p5);
            CVT_PK(r3, p6, p7);
            SWAP32(r0, r2); SWAP16(r0, r2);
            SWAP32(r1, r3); SWAP16(r1, r3);
            union { unsigned u[4]; bf16x8 v; } F;
            F.u[0] = r0; F.u[1] = r1; F.u[2] = r2; F.u[3] = r3;
            oacc[i][0] = mfma_bf16(F.v, vb0, oacc[i][0]);
            oacc[i][1] = mfma_bf16(F.v, vb1, oacc[i][1]);
        }
        akA = nA; akB = nB;
    }
    if (a == 3) {
        #pragma unroll
        for (int i = 0; i < 4; ++i)
            #pragma unroll
            for (int d = 0; d < 2; ++d)
                #pragma unroll
                for (int r = 0; r < 4; ++r) {
                    int q = q0 + i * 16 + h * 4 + r;
                    int dc = d * 16 + q16;
                    ob4[(size_t)b * 65536 + (size_t)q * 256 + c * 32 + dc] =
                        f2bf(oacc[i][d][r]);
                }
    } else {
        #pragma unroll
        for (int i = 0; i < 4; ++i)
            #pragma unroll
            for (int d = 0; d < 2; ++d)
                #pragma unroll
                for (int r = 0; r < 4; ++r) {
                    int q = q0 + i * 16 + h * 4 + r;
                    int dc = d * 16 + q16;
                    outp[(size_t)b * 65536 + (size_t)q * 256 + c * 32 + dc] =
                        oacc[i][d][r];
                }
    }
}

// ---------------------------------------------------------------------------
// Final: o5 = tanh(concat(o1..o4) @ W5^T + b5).  M=32768, N=256, K=1024.
// o1..o3 fp32 (d_out planes), o4 bf16 (ws).  BM=128, BN=128, BK=64.
// ---------------------------------------------------------------------------
__global__ __launch_bounds__(256) void k_final(
    const float* __restrict__ p0, const float* __restrict__ p1,
    const float* __restrict__ p2, const unsigned short* __restrict__ p3,
    const unsigned short* __restrict__ W5b, const float* __restrict__ b5,
    float* __restrict__ out)
{
    __shared__ __align__(16) short As[128 * 72];
    __shared__ __align__(16) short Bs[128 * 72];
    const int tid = threadIdx.x, w = tid >> 6, l = tid & 63;
    const int n0 = blockIdx.x * 128, m0 = blockIdx.y * 128;
    const int lr = l & 15, lk = (l >> 4) * 8, lq = (l >> 4) * 4;
    const int wr = (w >> 1) * 64, wc = (w & 1) * 64;
    f32x4 acc[4][4] = {};
    for (int step = 0; step < 16; ++step) {
        const int k0 = step * 64;
        const int kc = k0 & 255;
        __syncthreads();
        if (step < 12) {
            const float* P = (step < 4) ? p0 : (step < 8) ? p1 : p2;
            for (int ci = tid; ci < 1024; ci += 256) {
                int r = ci >> 3, ch = ci & 7;
                const float* src = P + (size_t)(m0 + r) * 256 + kc + ch * 8;
                float4 f0 = *(const float4*)src;
                float4 f1 = *(const float4*)(src + 4);
                unsigned a0, a1, a2, a3;
                CVT_PK(a0, f0.x, f0.y);
                CVT_PK(a1, f0.z, f0.w);
                CVT_PK(a2, f1.x, f1.y);
                CVT_PK(a3, f1.z, f1.w);
                uint4 pk; pk.x = a0; pk.y = a1; pk.z = a2; pk.w = a3;
                *(uint4*)&As[r * 72 + ch * 8] = pk;
                *(bf16x8*)&Bs[r * 72 + ch * 8] =
                    *(const bf16x8*)(W5b + (size_t)(n0 + r) * 1024 + k0 + ch * 8);
            }
        } else {
            for (int ci = tid; ci < 1024; ci += 256) {
                int r = ci >> 3, ch = ci & 7;
                *(bf16x8*)&As[r * 72 + ch * 8] =
                    *(const bf16x8*)(p3 + (size_t)(m0 + r) * 256 + kc + ch * 8);
                *(bf16x8*)&Bs[r * 72 + ch * 8] =
                    *(const bf16x8*)(W5b + (size_t)(n0 + r) * 1024 + k0 + ch * 8);
            }
        }
        __syncthreads();
        #pragma unroll
        for (int kk = 0; kk < 2; ++kk) {
            bf16x8 af[4], bfr[4];
            #pragma unroll
            for (int i = 0; i < 4; ++i)
                af[i] = *(const bf16x8*)&As[(wr + i * 16 + lr) * 72 + kk * 32 + lk];
            #pragma unroll
            for (int j = 0; j < 4; ++j)
                bfr[j] = *(const bf16x8*)&Bs[(wc + j * 16 + lr) * 72 + kk * 32 + lk];
            #pragma unroll
            for (int i = 0; i < 4; ++i)
                #pragma unroll
                for (int j = 0; j < 4; ++j)
                    acc[i][j] = mfma_bf16(af[i], bfr[j], acc[i][j]);
        }
    }
    #pragma unroll
    for (int j = 0; j < 4; ++j) {
        int col = n0 + wc + j * 16 + lr;
        float bv = b5[col];
        #pragma unroll
        for (int i = 0; i < 4; ++i) {
            int rowb = m0 + wr + i * 16 + lq;
            #pragma unroll
            for (int r = 0; r < 4; ++r)
                out[(size_t)(rowb + r) * 256 + col] =
                    fast_tanh(acc[i][j][r] + bv);
        }
    }
}

// ---------------------------------------------------------------------------
extern "C" void kernel_launch(void* const* d_in, const int* in_sizes, int n_in,
                              void* d_out, int out_size, void* d_ws, size_t ws_size,
                              hipStream_t stream)
{
    const float* q1  = (const float*)d_in[0];
    const float* q2  = (const float*)d_in[1];
    const float* q3  = (const float*)d_in[2];
    const int*   adj = (const int*)d_in[3];
    const float* WQ  = (const float*)d_in[4];  const float* bQ  = (const float*)d_in[5];
    const float* WV  = (const float*)d_in[6];  const float* bV  = (const float*)d_in[7];
    const float* WQ3 = (const float*)d_in[8];  const float* bQ3 = (const float*)d_in[9];
    const float* WK3 = (const float*)d_in[10]; const float* bK3 = (const float*)d_in[11];
    const float* WV3 = (const float*)d_in[12]; const float* bV3 = (const float*)d_in[13];
    const float* WQ4 = (const float*)d_in[14]; const float* bQ4 = (const float*)d_in[15];
    const float* WV4 = (const float*)d_in[16]; const float* bV4 = (const float*)d_in[17];
    const float* W5  = (const float*)d_in[18]; const float* b5  = (const float*)d_in[19];

    char* ws = (char*)d_ws;
    unsigned short* wb  = (unsigned short*)ws;               // 720896 bf16 weights
    unsigned short* W5b = wb + 458752;
    unsigned short* lin = (unsigned short*)(ws + 1441792);   // 9 x 32768x256 bf16
    unsigned short* Q1 = lin + 0ull * 8388608;
    unsigned short* Q2 = lin + 1ull * 8388608;
    unsigned short* Q3 = lin + 2ull * 8388608;
    unsigned short* Q4 = lin + 3ull * 8388608;
    unsigned short* K3 = lin + 4ull * 8388608;
    unsigned short* V1 = lin + 5ull * 8388608;
    unsigned short* V2 = lin + 6ull * 8388608;
    unsigned short* V3 = lin + 7ull * 8388608;
    unsigned short* V4 = lin + 8ull * 8388608;
    float* partial = (float*)(ws + 152436736);               // 4*32*65536 f32
    float* dinvP   = (float*)(ws + 185991168);               // 4*65536 f32 (permuted)
    unsigned short* ob4 = (unsigned short*)(ws + 152436736); // o4 bf16, overlaps dead partial

    float* outf = (float*)d_out;   // planes: o1(0) o2(1) o5(2) o3(3)
    float* o5p = outf + 2ull * 8388608;
    unsigned short* Xb = (unsigned short*)d_out;  // q1..q3 bf16 scratch in o1/o2 planes

    dim3 blk(256);

    hipLaunchKernelGGL(k_convert_w, dim3(2816), blk, 0, stream,
                       WQ, WV, WQ3, WK3, WV3, WQ4, WV4, W5, wb);
    hipLaunchKernelGGL(k_convert_x, dim3(12288), blk, 0, stream,
                       q1, q2, q3, Xb);

    hipLaunchKernelGGL(k_linear, dim3(2560), dim3(512), 0, stream,
                       Xb, adj, wb,
                       bQ, bV, bQ3, bK3, bV3, bQ4, bV4, lin);

    hipLaunchKernelGGL(k_denom, dim3(4, 32, 4), blk, 0, stream,
                       Q1, Q2, Q3, Q4, K3, partial);
    hipLaunchKernelGGL(k_reduce, dim3(256, 4), blk, 0, stream, partial, dinvP);

    hipLaunchKernelGGL(k_attn, dim3(4096), blk, 0, stream,
                       Q1, Q2, Q3, Q4, K3, V1, V2, V3, V4, dinvP,
                       outf, ob4);

    hipLaunchKernelGGL(k_final, dim3(2, 256), blk, 0, stream,
                       outf, outf + 8388608ull, outf + 3ull * 8388608, ob4,
                       W5b, b5, o5p);
}

// Round 11
// 329.535 us; speedup vs baseline: 2.4393x; 1.0168x over previous
//
#include <hip/hip_runtime.h>

// ---------------------------------------------------------------------------
// multihead_attention_87454124081549 — round 11
// Round-11: k_attn dinv loads rotate-prefetched one (kp,i) iteration ahead
// (same register-rotation pattern as the K prefetch; the 64 per-wave L2
// dinv loads were the exposed-latency chain). Everything else identical to
// round 10 (passed, 335 us). NOTE (journal): exponent-fold of dinv into
// exp2 FAILED twice (rounds 8/9, unnormalized-softmax signature, mechanism
// unidentified) — keep the multiply form.
// ---------------------------------------------------------------------------

typedef __attribute__((ext_vector_type(4))) float f32x4;
typedef __attribute__((ext_vector_type(8))) short bf16x8;

#define LOG2E 1.4426950408889634f
#define SM_SCALE (1.4426950408889634f / 5.656854249492381f)  // log2(e)/sqrt(32)

#define CVT_PK(d, lo, hi) \
    asm("v_cvt_pk_bf16_f32 %0, %1, %2" : "=v"(d) : "v"(lo), "v"(hi))
#define SWAP32(x, y) \
    asm("v_permlane32_swap_b32 %0, %1" : "+v"(x), "+v"(y))
#define SWAP16(x, y) \
    asm("v_permlane16_swap_b32 %0, %1" : "+v"(x), "+v"(y))

__device__ __forceinline__ unsigned short f2bf(float x) {
    union { float f; unsigned u; } v; v.f = x;
    unsigned r = v.u + 0x7FFFu + ((v.u >> 16) & 1u);   // RNE
    return (unsigned short)(r >> 16);
}

__device__ __forceinline__ float fast_tanh(float x) {
    float e = __builtin_amdgcn_exp2f(x * (2.0f * LOG2E));   // exp(2x)
    return 1.0f - 2.0f * __builtin_amdgcn_rcpf(e + 1.0f);
}

__device__ __forceinline__ f32x4 mfma_bf16(bf16x8 a, bf16x8 b, f32x4 c) {
    return __builtin_amdgcn_mfma_f32_16x16x32_bf16(a, b, c, 0, 0, 0);
}

// ---------------------------------------------------------------------------
// Weight conversion: 7 x (256x256) + W5 (256x1024) fp32 -> bf16, concatenated.
// Order: WQ(0) WV(1) WQ3(2) WK3(3) WV3(4) WQ4(5) WV4(6) W5(@458752)
// ---------------------------------------------------------------------------
__global__ __launch_bounds__(256) void k_convert_w(
    const float* w0, const float* w1, const float* w2, const float* w3,
    const float* w4, const float* w5, const float* w6, const float* w7,
    unsigned short* out)
{
    int i = blockIdx.x * 256 + threadIdx.x;
    if (i >= 720896) return;
    float v;
    if (i < 458752) {
        int r = i >> 16, j = i & 65535;
        const float* s =
            (r == 0) ? w0 : (r == 1) ? w1 : (r == 2) ? w2 :
            (r == 3) ? w3 : (r == 4) ? w4 : (r == 5) ? w5 : w6;
        v = s[j];
    } else {
        v = w7[i - 458752];
    }
    out[i] = (short)f2bf(v);
}

// ---------------------------------------------------------------------------
// X conversion: q1,q2,q3 (each 8388608 fp32) -> bf16, concatenated in Xb.
// ---------------------------------------------------------------------------
__global__ __launch_bounds__(256) void k_convert_x(
    const float* __restrict__ q1, const float* __restrict__ q2,
    const float* __restrict__ q3, unsigned short* __restrict__ Xb)
{
    const int gi = (blockIdx.x * 256 + threadIdx.x) * 8;
    const float* s = (gi < 8388608) ? q1 : (gi < 16777216) ? q2 : q3;
    const int off = gi & 8388607;
    float4 f0 = *(const float4*)(s + off);
    float4 f1 = *(const float4*)(s + off + 4);
    unsigned a0, a1, a2, a3;
    CVT_PK(a0, f0.x, f0.y);
    CVT_PK(a1, f0.z, f0.w);
    CVT_PK(a2, f1.x, f1.y);
    CVT_PK(a3, f1.z, f1.w);
    uint4 pk; pk.x = a0; pk.y = a1; pk.z = a2; pk.w = a3;
    *(uint4*)(Xb + gi) = pk;
}

// ---------------------------------------------------------------------------
// Linear + tanh, grouped by input:  Y(bf16) = tanh(Xb(bf16) @ W^T + bias)
// grid = 2560 (XCD-swizzled), block = 512 (8 waves: 2m x 4n, tile 64x32/out).
// ---------------------------------------------------------------------------
__global__ __launch_bounds__(512, 4) void k_linear(
    const unsigned short* __restrict__ Xb, const int* __restrict__ adj,
    const unsigned short* __restrict__ wb,
    const float* __restrict__ bQ, const float* __restrict__ bV,
    const float* __restrict__ bQ3, const float* __restrict__ bK3,
    const float* __restrict__ bV3, const float* __restrict__ bQ4,
    const float* __restrict__ bV4,
    unsigned short* __restrict__ lin)
{
    __shared__ __align__(16) short lds[30720];   // 2 x (A 5120 + B0 5120 + B1 5120)
    const int bid0 = blockIdx.x;                 // 2560 = 8 XCD x 320
    const int swz = (bid0 & 7) * 320 + (bid0 >> 3);
    const int var = swz >> 9;
    const int rem = swz & 511;
    const int m0 = (rem >> 1) * 128, n0 = (rem & 1) * 128;

    const unsigned short* X = Xb + (size_t)((var == 0) ? 0 : (var == 1) ? 1 : 2) * 8388608;
    const bool gather = (var == 4);
    const int nout = (var == 3) ? 1 : 2;

    int widx0, widx1 = 0, zidx0, zidx1 = 0;
    const float* bp0;
    const float* bp1 = bQ;
    if (var == 0)      { widx0=0; widx1=1; zidx0=0; zidx1=5; bp0=bQ;  bp1=bV;  }
    else if (var == 1) { widx0=0; widx1=1; zidx0=1; zidx1=6; bp0=bQ;  bp1=bV;  }
    else if (var == 2) { widx0=2; widx1=3; zidx0=2; zidx1=4; bp0=bQ3; bp1=bK3; }
    else if (var == 3) { widx0=4;          zidx0=7;          bp0=bV3;          }
    else               { widx0=5; widx1=6; zidx0=3; zidx1=8; bp0=bQ4; bp1=bV4; }

    const int tid = threadIdx.x;
    const int w = tid >> 6, l = tid & 63;
    const int wm = w >> 2, wn = w & 3;           // 2 x 4 wave grid
    const int lr = l & 15, lk = (l >> 4) * 8, lq = (l >> 4) * 4;

    const int srow = tid >> 2, scol = (tid & 3) * 8;
    const int gm = m0 + srow;
    const int sm = gather ? (adj[gm >> 8] * 256 + (gm & 255)) : gm;
    const unsigned short* aSrc = X + (size_t)sm * 256 + scol;
    const unsigned short* b0Src = wb + (size_t)widx0 * 65536 + (size_t)(n0 + srow) * 256 + scol;
    const unsigned short* b1Src = wb + (size_t)widx1 * 65536 + (size_t)(n0 + srow) * 256 + scol;

    bf16x8 ar, b0r, b1r;
    f32x4 acc[2][4][2] = {};

    ar = *(const bf16x8*)(aSrc);
    b0r = *(const bf16x8*)(b0Src);
    if (nout == 2) b1r = *(const bf16x8*)(b1Src);
    *(bf16x8*)&lds[srow * 40 + scol] = ar;
    *(bf16x8*)&lds[5120 + srow * 40 + scol] = b0r;
    if (nout == 2) *(bf16x8*)&lds[10240 + srow * 40 + scol] = b1r;
    ar = *(const bf16x8*)(aSrc + 32);
    b0r = *(const bf16x8*)(b0Src + 32);
    if (nout == 2) b1r = *(const bf16x8*)(b1Src + 32);
    __syncthreads();

    for (int st = 0; st < 8; ++st) {
        const int p = st & 1;
        const short* base = lds + p * 15360;
        bf16x8 af[4], bf0[2], bf1[2];
        #pragma unroll
        for (int i = 0; i < 4; ++i)
            af[i] = *(const bf16x8*)&base[(wm * 64 + i * 16 + lr) * 40 + lk];
        #pragma unroll
        for (int j = 0; j < 2; ++j)
            bf0[j] = *(const bf16x8*)&base[5120 + (wn * 32 + j * 16 + lr) * 40 + lk];
        if (nout == 2)
            #pragma unroll
            for (int j = 0; j < 2; ++j)
                bf1[j] = *(const bf16x8*)&base[10240 + (wn * 32 + j * 16 + lr) * 40 + lk];
        #pragma unroll
        for (int i = 0; i < 4; ++i)
            #pragma unroll
            for (int j = 0; j < 2; ++j)
                acc[0][i][j] = mfma_bf16(af[i], bf0[j], acc[0][i][j]);
        if (nout == 2)
            #pragma unroll
            for (int i = 0; i < 4; ++i)
                #pragma unroll
                for (int j = 0; j < 2; ++j)
                    acc[1][i][j] = mfma_bf16(af[i], bf1[j], acc[1][i][j]);
        if (st < 7) {
            short* nbase = lds + (p ^ 1) * 15360;
            *(bf16x8*)&nbase[srow * 40 + scol] = ar;
            *(bf16x8*)&nbase[5120 + srow * 40 + scol] = b0r;
            if (nout == 2) *(bf16x8*)&nbase[10240 + srow * 40 + scol] = b1r;
            if (st < 6) {
                const int ko = (st + 2) * 32;
                ar = *(const bf16x8*)(aSrc + ko);
                b0r = *(const bf16x8*)(b0Src + ko);
                if (nout == 2) b1r = *(const bf16x8*)(b1Src + ko);
            }
        }
        __syncthreads();
    }

    #pragma unroll
    for (int t = 0; t < 2; ++t)
        if (t < nout) {
            const float* bp = t ? bp1 : bp0;
            float bv[2];
            #pragma unroll
            for (int j = 0; j < 2; ++j)
                bv[j] = bp[n0 + wn * 32 + j * 16 + lr];
            #pragma unroll
            for (int i = 0; i < 4; ++i)
                #pragma unroll
                for (int j = 0; j < 2; ++j)
                    #pragma unroll
                    for (int r = 0; r < 4; ++r)
                        lds[(wm * 64 + i * 16 + lq + r) * 136 + wn * 32 + j * 16 + lr] =
                            (short)f2bf(fast_tanh(acc[t][i][j][r] + bv[j]));
            __syncthreads();
            unsigned short* Y = lin + (size_t)(t ? zidx1 : zidx0) * 8388608;
            #pragma unroll
            for (int it2 = 0; it2 < 4; ++it2) {
                const int c = tid + it2 * 512;
                const int row = c >> 4, col8 = (c & 15) * 8;
                *(bf16x8*)(Y + (size_t)(m0 + row) * 256 + n0 + col8) =
                    *(const bf16x8*)&lds[row * 136 + col8];
            }
            __syncthreads();
        }
}

// ---------------------------------------------------------------------------
// Denominator partials: partial[a][g][q][k] = sum_{n in g} exp(QK^T/sqrt32).
// grid = (4 tiles, 32 groups, 4 attn), block = 256.  2 heads per barrier pair.
// ---------------------------------------------------------------------------
__global__ __launch_bounds__(256) void k_denom(
    const unsigned short* __restrict__ Qa, const unsigned short* __restrict__ Qb2,
    const unsigned short* __restrict__ Qc, const unsigned short* __restrict__ Qd,
    const unsigned short* __restrict__ Kb, float* __restrict__ partialBase)
{
    __shared__ __align__(16) short Qs[2][128 * 40];
    __shared__ __align__(16) short Ks[2][128 * 40];
    const int tid = threadIdx.x, w = tid >> 6, l = tid & 63;
    const int q0 = (blockIdx.x >> 1) * 128, k0 = (blockIdx.x & 1) * 128;
    const int g = blockIdx.y, a = blockIdx.z;
    const unsigned short* Qb = (a == 0) ? Qa : (a == 1) ? Qb2 : (a == 2) ? Qc : Qd;
    float* partial = partialBase + ((size_t)a * 32 + g) * 65536;
    const int lr = l & 15, lk = (l >> 4) * 8, lq = (l >> 4) * 4;

    f32x4 eacc[2][8] = {};
    for (int it = 0; it < 32; it += 2) {
        __syncthreads();
        #pragma unroll
        for (int u = 0; u < 2; ++u) {
            const int n = g * 32 + it + u;
            const int c = n >> 7, b = n & 127;
            const size_t base = (size_t)b * 65536 + (size_t)c * 32;
            for (int ci = tid; ci < 512; ci += 256) {
                int r = ci >> 2, ch = ci & 3;
                *(bf16x8*)&Qs[u][r * 40 + ch * 8] =
                    *(const bf16x8*)(Qb + base + (size_t)(q0 + r) * 256 + ch * 8);
                *(bf16x8*)&Ks[u][r * 40 + ch * 8] =
                    *(const bf16x8*)(Kb + base + (size_t)(k0 + r) * 256 + ch * 8);
            }
        }
        __syncthreads();
        #pragma unroll
        for (int u = 0; u < 2; ++u) {
            bf16x8 aq[2], bk[8];
            #pragma unroll
            for (int i = 0; i < 2; ++i)
                aq[i] = *(const bf16x8*)&Qs[u][(w * 32 + i * 16 + lr) * 40 + lk];
            #pragma unroll
            for (int j = 0; j < 8; ++j)
                bk[j] = *(const bf16x8*)&Ks[u][(j * 16 + lr) * 40 + lk];
            #pragma unroll
            for (int i = 0; i < 2; ++i)
                #pragma unroll
                for (int j = 0; j < 8; ++j) {
                    f32x4 s = mfma_bf16(aq[i], bk[j], (f32x4){0.f, 0.f, 0.f, 0.f});
                    #pragma unroll
                    for (int r = 0; r < 4; ++r)
                        eacc[i][j][r] += __builtin_amdgcn_exp2f(s[r] * SM_SCALE);
                }
        }
    }
    #pragma unroll
    for (int i = 0; i < 2; ++i)
        #pragma unroll
        for (int j = 0; j < 8; ++j)
            #pragma unroll
            for (int r = 0; r < 4; ++r) {
                int q = q0 + w * 32 + i * 16 + lq + r;
                int k = k0 + j * 16 + lr;
                partial[(size_t)q * 256 + k] = eacc[i][j][r];
            }
}

// ---------------------------------------------------------------------------
// Reduce 32 partials -> Dinv = 1/sum, wave-fragment-permuted layout:
//   dinvP[a][w][kp][i][j][h][q16][r],  q = w*64+i*16+q16, k = kp*32+j*16+h*4+r
// grid = (256, 4)
// ---------------------------------------------------------------------------
__global__ __launch_bounds__(256) void k_reduce(
    const float* __restrict__ partial, float* __restrict__ dinvP)
{
    int a = blockIdx.y;
    int i = blockIdx.x * 256 + threadIdx.x;
    const float* p = partial + (size_t)a * 32 * 65536 + i;
    float s = 0.f;
    #pragma unroll
    for (int g = 0; g < 32; ++g) s += p[(size_t)g * 65536];
    const int q = i >> 8, k = i & 255;
    const int w_ = q >> 6, iq = (q >> 4) & 3, q16 = q & 15;
    const int kp = k >> 5, j = (k >> 4) & 1, h = (k >> 2) & 3, r = k & 3;
    const int off = (((((((w_ * 8 + kp) * 4 + iq) * 2 + j) * 4 + h) * 16) + q16) * 4) + r;
    dinvP[((size_t)a << 16) + off] = 1.0f / s;
}

// ---------------------------------------------------------------------------
// Attention: o = (exp(QK^T/sqrt32) * Dinv) @ V.  grid = 4096 (XCD-swizzled
// over (head n, attn a)), block = 256 (4 waves x 64 q-rows).
// K prefetched one kp ahead; dinv pair rotate-prefetched one (kp,i) ahead.
// ---------------------------------------------------------------------------
__global__ __launch_bounds__(256) void k_attn(
    const unsigned short* __restrict__ Q1, const unsigned short* __restrict__ Q2,
    const unsigned short* __restrict__ Q3, const unsigned short* __restrict__ Q4,
    const unsigned short* __restrict__ Kb,
    const unsigned short* __restrict__ V1, const unsigned short* __restrict__ V2,
    const unsigned short* __restrict__ V3, const unsigned short* __restrict__ V4,
    const float* __restrict__ dinvP,
    float* __restrict__ outBase, unsigned short* __restrict__ ob4)
{
    __shared__ __align__(16) short Vt[32 * 264];      // V^T: [d=32][k=256] pad 264
    const int tid = threadIdx.x, w = tid >> 6, l = tid & 63;
    const int bid = blockIdx.x;
    const int swz = (bid & 7) * 512 + (bid >> 3);
    const int a = swz & 3, n = swz >> 2;
    const int c = n >> 7, b = n & 127;
    const int q16 = l & 15, h = l >> 4;
    const size_t base = (size_t)b * 65536 + (size_t)c * 32;

    const unsigned short* Qb = (a == 0) ? Q1 : (a == 1) ? Q2 : (a == 2) ? Q3 : Q4;
    const unsigned short* Vb = (a == 0) ? V1 : (a == 1) ? V2 : (a == 2) ? V3 : V4;
    // dinv fragment stream for this wave: dw[t*128], dw[t*128+64], t = kp*4+i
    const f32x4* dw = (const f32x4*)(dinvP + ((size_t)a << 16)) + l + (size_t)w * 4096;
    float* outp = outBase + (size_t)((a == 2) ? 3 : a) * 8388608;

    {
        const unsigned short* vp = Vb + base + (size_t)tid * 256;
        bf16x8 v0 = *(const bf16x8*)(vp);
        bf16x8 v1 = *(const bf16x8*)(vp + 8);
        bf16x8 v2 = *(const bf16x8*)(vp + 16);
        bf16x8 v3 = *(const bf16x8*)(vp + 24);
        #pragma unroll
        for (int e = 0; e < 8; ++e) {
            Vt[(0  + e) * 264 + tid] = v0[e];
            Vt[(8  + e) * 264 + tid] = v1[e];
            Vt[(16 + e) * 264 + tid] = v2[e];
            Vt[(24 + e) * 264 + tid] = v3[e];
        }
    }
    __syncthreads();

    const int q0 = w * 64;
    bf16x8 bq[4];
    #pragma unroll
    for (int i = 0; i < 4; ++i)
        bq[i] = *(const bf16x8*)(Qb + base + (size_t)(q0 + i * 16 + q16) * 256 + h * 8);

    const unsigned short* kSrc = Kb + base + (size_t)q16 * 256 + h * 8;
    bf16x8 akA = *(const bf16x8*)(kSrc);
    bf16x8 akB = *(const bf16x8*)(kSrc + 16 * 256);
    f32x4 dc0 = dw[0];
    f32x4 dc1 = dw[64];

    f32x4 oacc[4][2] = {};
    for (int kp = 0; kp < 8; ++kp) {
        const int kk0 = kp * 32;
        bf16x8 nA = akA, nB = akB;
        if (kp < 7) {
            nA = *(const bf16x8*)(kSrc + (size_t)(kk0 + 32) * 256);
            nB = *(const bf16x8*)(kSrc + (size_t)(kk0 + 48) * 256);
        }
        bf16x8 vb0 = *(const bf16x8*)&Vt[(0  + q16) * 264 + kk0 + h * 8];
        bf16x8 vb1 = *(const bf16x8*)&Vt[(16 + q16) * 264 + kk0 + h * 8];
        #pragma unroll
        for (int i = 0; i < 4; ++i) {
            const int t = kp * 4 + i;
            // prefetch next iteration's dinv pair (register rotation)
            f32x4 dn0 = dc0, dn1 = dc1;
            if (t < 31) {
                dn0 = dw[(size_t)(t + 1) * 128];
                dn1 = dw[(size_t)(t + 1) * 128 + 64];
            }
            f32x4 s0 = mfma_bf16(akA, bq[i], (f32x4){0.f, 0.f, 0.f, 0.f});
            f32x4 s1 = mfma_bf16(akB, bq[i], (f32x4){0.f, 0.f, 0.f, 0.f});
            float p0 = __builtin_amdgcn_exp2f(s0[0] * SM_SCALE) * dc0[0];
            float p1 = __builtin_amdgcn_exp2f(s0[1] * SM_SCALE) * dc0[1];
            float p2 = __builtin_amdgcn_exp2f(s0[2] * SM_SCALE) * dc0[2];
            float p3 = __builtin_amdgcn_exp2f(s0[3] * SM_SCALE) * dc0[3];
            float p4 = __builtin_amdgcn_exp2f(s1[0] * SM_SCALE) * dc1[0];
            float p5 = __builtin_amdgcn_exp2f(s1[1] * SM_SCALE) * dc1[1];
            float p6 = __builtin_amdgcn_exp2f(s1[2] * SM_SCALE) * dc1[2];
            float p7 = __builtin_amdgcn_exp2f(s1[3] * SM_SCALE) * dc1[3];
            unsigned r0, r1, r2, r3;
            CVT_PK(r0, p0, p1);
            CVT_PK(r1, p2, p3);
            CVT_PK(r2, p4, p5);
            CVT_PK(r3, p6, p7);
            SWAP32(r0, r2); SWAP16(r0, r2);
            SWAP32(r1, r3); SWAP16(r1, r3);
            union { unsigned u[4]; bf16x8 v; } F;
            F.u[0] = r0; F.u[1] = r1; F.u[2] = r2; F.u[3] = r3;
            oacc[i][0] = mfma_bf16(F.v, vb0, oacc[i][0]);
            oacc[i][1] = mfma_bf16(F.v, vb1, oacc[i][1]);
            dc0 = dn0; dc1 = dn1;
        }
        akA = nA; akB = nB;
    }
    if (a == 3) {
        #pragma unroll
        for (int i = 0; i < 4; ++i)
            #pragma unroll
            for (int d = 0; d < 2; ++d)
                #pragma unroll
                for (int r = 0; r < 4; ++r) {
                    int q = q0 + i * 16 + h * 4 + r;
                    int dc = d * 16 + q16;
                    ob4[(size_t)b * 65536 + (size_t)q * 256 + c * 32 + dc] =
                        f2bf(oacc[i][d][r]);
                }
    } else {
        #pragma unroll
        for (int i = 0; i < 4; ++i)
            #pragma unroll
            for (int d = 0; d < 2; ++d)
                #pragma unroll
                for (int r = 0; r < 4; ++r) {
                    int q = q0 + i * 16 + h * 4 + r;
                    int dc = d * 16 + q16;
                    outp[(size_t)b * 65536 + (size_t)q * 256 + c * 32 + dc] =
                        oacc[i][d][r];
                }
    }
}

// ---------------------------------------------------------------------------
// Final: o5 = tanh(concat(o1..o4) @ W5^T + b5).  M=32768, N=256, K=1024.
// o1..o3 fp32 (d_out planes), o4 bf16 (ws).  BM=128, BN=128, BK=64.
// ---------------------------------------------------------------------------
__global__ __launch_bounds__(256) void k_final(
    const float* __restrict__ p0, const float* __restrict__ p1,
    const float* __restrict__ p2, const unsigned short* __restrict__ p3,
    const unsigned short* __restrict__ W5b, const float* __restrict__ b5,
    float* __restrict__ out)
{
    __shared__ __align__(16) short As[128 * 72];
    __shared__ __align__(16) short Bs[128 * 72];
    const int tid = threadIdx.x, w = tid >> 6, l = tid & 63;
    const int n0 = blockIdx.x * 128, m0 = blockIdx.y * 128;
    const int lr = l & 15, lk = (l >> 4) * 8, lq = (l >> 4) * 4;
    const int wr = (w >> 1) * 64, wc = (w & 1) * 64;
    f32x4 acc[4][4] = {};
    for (int step = 0; step < 16; ++step) {
        const int k0 = step * 64;
        const int kc = k0 & 255;
        __syncthreads();
        if (step < 12) {
            const float* P = (step < 4) ? p0 : (step < 8) ? p1 : p2;
            for (int ci = tid; ci < 1024; ci += 256) {
                int r = ci >> 3, ch = ci & 7;
                const float* src = P + (size_t)(m0 + r) * 256 + kc + ch * 8;
                float4 f0 = *(const float4*)src;
                float4 f1 = *(const float4*)(src + 4);
                unsigned a0, a1, a2, a3;
                CVT_PK(a0, f0.x, f0.y);
                CVT_PK(a1, f0.z, f0.w);
                CVT_PK(a2, f1.x, f1.y);
                CVT_PK(a3, f1.z, f1.w);
                uint4 pk; pk.x = a0; pk.y = a1; pk.z = a2; pk.w = a3;
                *(uint4*)&As[r * 72 + ch * 8] = pk;
                *(bf16x8*)&Bs[r * 72 + ch * 8] =
                    *(const bf16x8*)(W5b + (size_t)(n0 + r) * 1024 + k0 + ch * 8);
            }
        } else {
            for (int ci = tid; ci < 1024; ci += 256) {
                int r = ci >> 3, ch = ci & 7;
                *(bf16x8*)&As[r * 72 + ch * 8] =
                    *(const bf16x8*)(p3 + (size_t)(m0 + r) * 256 + kc + ch * 8);
                *(bf16x8*)&Bs[r * 72 + ch * 8] =
                    *(const bf16x8*)(W5b + (size_t)(n0 + r) * 1024 + k0 + ch * 8);
            }
        }
        __syncthreads();
        #pragma unroll
        for (int kk = 0; kk < 2; ++kk) {
            bf16x8 af[4], bfr[4];
            #pragma unroll
            for (int i = 0; i < 4; ++i)
                af[i] = *(const bf16x8*)&As[(wr + i * 16 + lr) * 72 + kk * 32 + lk];
            #pragma unroll
            for (int j = 0; j < 4; ++j)
                bfr[j] = *(const bf16x8*)&Bs[(wc + j * 16 + lr) * 72 + kk * 32 + lk];
            #pragma unroll
            for (int i = 0; i < 4; ++i)
                #pragma unroll
                for (int j = 0; j < 4; ++j)
                    acc[i][j] = mfma_bf16(af[i], bfr[j], acc[i][j]);
        }
    }
    #pragma unroll
    for (int j = 0; j < 4; ++j) {
        int col = n0 + wc + j * 16 + lr;
        float bv = b5[col];
        #pragma unroll
        for (int i = 0; i < 4; ++i) {
            int rowb = m0 + wr + i * 16 + lq;
            #pragma unroll
            for (int r = 0; r < 4; ++r)
                out[(size_t)(rowb + r) * 256 + col] =
                    fast_tanh(acc[i][j][r] + bv);
        }
    }
}

// ---------------------------------------------------------------------------
extern "C" void kernel_launch(void* const* d_in, const int* in_sizes, int n_in,
                              void* d_out, int out_size, void* d_ws, size_t ws_size,
                              hipStream_t stream)
{
    const float* q1  = (const float*)d_in[0];
    const float* q2  = (const float*)d_in[1];
    const float* q3  = (const float*)d_in[2];
    const int*   adj = (const int*)d_in[3];
    const float* WQ  = (const float*)d_in[4];  const float* bQ  = (const float*)d_in[5];
    const float* WV  = (const float*)d_in[6];  const float* bV  = (const float*)d_in[7];
    const float* WQ3 = (const float*)d_in[8];  const float* bQ3 = (const float*)d_in[9];
    const float* WK3 = (const float*)d_in[10]; const float* bK3 = (const float*)d_in[11];
    const float* WV3 = (const float*)d_in[12]; const float* bV3 = (const float*)d_in[13];
    const float* WQ4 = (const float*)d_in[14]; const float* bQ4 = (const float*)d_in[15];
    const float* WV4 = (const float*)d_in[16]; const float* bV4 = (const float*)d_in[17];
    const float* W5  = (const float*)d_in[18]; const float* b5  = (const float*)d_in[19];

    char* ws = (char*)d_ws;
    unsigned short* wb  = (unsigned short*)ws;               // 720896 bf16 weights
    unsigned short* W5b = wb + 458752;
    unsigned short* lin = (unsigned short*)(ws + 1441792);   // 9 x 32768x256 bf16
    unsigned short* Q1 = lin + 0ull * 8388608;
    unsigned short* Q2 = lin + 1ull * 8388608;
    unsigned short* Q3 = lin + 2ull * 8388608;
    unsigned short* Q4 = lin + 3ull * 8388608;
    unsigned short* K3 = lin + 4ull * 8388608;
    unsigned short* V1 = lin + 5ull * 8388608;
    unsigned short* V2 = lin + 6ull * 8388608;
    unsigned short* V3 = lin + 7ull * 8388608;
    unsigned short* V4 = lin + 8ull * 8388608;
    float* partial = (float*)(ws + 152436736);               // 4*32*65536 f32
    float* dinvP   = (float*)(ws + 185991168);               // 4*65536 f32 (permuted)
    unsigned short* ob4 = (unsigned short*)(ws + 152436736); // o4 bf16, overlaps dead partial

    float* outf = (float*)d_out;   // planes: o1(0) o2(1) o5(2) o3(3)
    float* o5p = outf + 2ull * 8388608;
    unsigned short* Xb = (unsigned short*)d_out;  // q1..q3 bf16 scratch in o1/o2 planes

    dim3 blk(256);

    hipLaunchKernelGGL(k_convert_w, dim3(2816), blk, 0, stream,
                       WQ, WV, WQ3, WK3, WV3, WQ4, WV4, W5, wb);
    hipLaunchKernelGGL(k_convert_x, dim3(12288), blk, 0, stream,
                       q1, q2, q3, Xb);

    hipLaunchKernelGGL(k_linear, dim3(2560), dim3(512), 0, stream,
                       Xb, adj, wb,
                       bQ, bV, bQ3, bK3, bV3, bQ4, bV4, lin);

    hipLaunchKernelGGL(k_denom, dim3(4, 32, 4), blk, 0, stream,
                       Q1, Q2, Q3, Q4, K3, partial);
    hipLaunchKernelGGL(k_reduce, dim3(256, 4), blk, 0, stream, partial, dinvP);

    hipLaunchKernelGGL(k_attn, dim3(4096), blk, 0, stream,
                       Q1, Q2, Q3, Q4, K3, V1, V2, V3, V4, dinvP,
                       outf, ob4);

    hipLaunchKernelGGL(k_final, dim3(2, 256), blk, 0, stream,
                       outf, outf + 8388608ull, outf + 3ull * 8388608, ob4,
                       W5b, b5, o5p);
}